// Round 16
// baseline (4619.405 us; speedup 1.0000x reference)
//
#include <hip/hip_runtime.h>
#include <math.h>

typedef float4 f4;
typedef __attribute__((ext_vector_type(8))) short bf8v;
typedef __attribute__((ext_vector_type(4))) float f4v;

#define T_SEQ 2048
#define D_MOD 1024

__device__ __forceinline__ float gelu_f(float x){
    float u = 0.7978845608028654f*(x + 0.044715f*x*x*x);
    return 0.5f*x*(1.0f + tanhf(u));
}

// pack f32 -> (hi bf16 rounded, lo bf16) ; x ~= hi + lo
__device__ __forceinline__ unsigned f32_to_pair(float x){
    unsigned u = __float_as_uint(x);
    unsigned hi = (u + 0x7FFFu + ((u >> 16) & 1u)) >> 16;
    float hif = __uint_as_float(hi << 16);
    float lof = x - hif;
    unsigned v = __float_as_uint(lof);
    unsigned lo = (v + 0x7FFFu + ((v >> 16) & 1u)) >> 16;
    return hi | (lo << 16);
}

// truncating split: hi = trunc-bf16(x), lo = trunc-bf16(x-hi)
__device__ __forceinline__ void split2(float x, short& hi, short& lo){
    unsigned u = __float_as_uint(x);
    hi = (short)(u >> 16);
    float rem = x - __uint_as_float(u & 0xFFFF0000u);
    lo = (short)(__float_as_uint(rem) >> 16);
}

__global__ __launch_bounds__(256) void convert1(
    const float* __restrict__ s, unsigned* __restrict__ d, int n4)
{
    const int i = blockIdx.x*256 + threadIdx.x;
    if (i < n4){
        f4 v = ((const f4*)s)[i];
        uint4 o;
        o.x = f32_to_pair(v.x); o.y = f32_to_pair(v.y);
        o.z = f32_to_pair(v.z); o.w = f32_to_pair(v.w);
        ((uint4*)d)[i] = o;
    }
}

__global__ __launch_bounds__(256) void convert6(
    const float* __restrict__ s0, const float* __restrict__ s1,
    const float* __restrict__ s2, const float* __restrict__ s3,
    const float* __restrict__ s4, const float* __restrict__ s5,
    unsigned* __restrict__ d0, unsigned* __restrict__ d1,
    unsigned* __restrict__ d2, unsigned* __restrict__ d3,
    unsigned* __restrict__ d4, unsigned* __restrict__ d5)
{
    const int stride = gridDim.x * 256;
    for (int idx = blockIdx.x*256 + threadIdx.x; idx < 3145728; idx += stride){
        const float* s; unsigned* d; int off;
        if (idx < 1048576){
            const int r = idx >> 18; off = idx & 262143;
            s = (r==0)?s0:(r==1)?s1:(r==2)?s2:s3;
            d = (r==0)?d0:(r==1)?d1:(r==2)?d2:d3;
        } else if (idx < 2097152){ s = s4; d = d4; off = idx - 1048576; }
        else                     { s = s5; d = d5; off = idx - 2097152; }
        f4 v = ((const f4*)s)[off];
        uint4 o;
        o.x = f32_to_pair(v.x); o.y = f32_to_pair(v.y);
        o.z = f32_to_pair(v.z); o.w = f32_to_pair(v.w);
        ((uint4*)d)[off] = o;
    }
}

// bf16x2 MFMA GEMM, 512 threads: intra-block split-K x2 + depth-1 register
// prefetch (R13-proven structure; depth-2 gets unwound by the compiler).
// Used for ALL matmuls on the pair path (QKVO, mW1, mW2).
__global__ __launch_bounds__(512) void gemm_mfma2(
    const unsigned* __restrict__ Apr, const unsigned* __restrict__ Wpr,
    const float* __restrict__ bias, const float* __restrict__ res,
    float* __restrict__ Cf, unsigned* __restrict__ Cp,
    int M, int N, int K, int act, int hasres, int outpair)
{
    __shared__ short Ah[2][2][4][64][8];   // [kh][ks][mf][lane][e]  16KB
    __shared__ short Al[2][2][4][64][8];   // 16KB
    __shared__ short Bh[2][2][8][64][8];   // 32KB
    __shared__ short Bl[2][2][8][64][8];   // 32KB
    const int tid = threadIdx.x;
    const int kh = tid >> 8;               // K-half
    const int t  = tid & 255;
    const int w = t >> 6, l = t & 63;
    const int row0 = blockIdx.y * 64, col0 = blockIdx.x * 128;
    const int mb = (w >> 1) * 2;
    const int nb = (w & 1) * 4;
    const int K2 = K >> 1;
    const int kbase = kh * K2;
    const int b_c4 = (t & 31) * 4;
    const int b_kg = t >> 5;
    const int a_r0 = t >> 3,       a_kg0 = t & 7;
    const int a_r1 = (t+256) >> 3, a_kg1 = (t+256) & 7;

    f4v acc[2][4];
    #pragma unroll
    for (int i=0;i<2;i++)
        #pragma unroll
        for (int j=0;j<4;j++) acc[i][j] = (f4v){0.f,0.f,0.f,0.f};

    uint4 pa0[2], pa1[2], pb[8];

    // load tile 0 into regs
    {
        const unsigned* s0 = Apr + (size_t)(row0 + a_r0)*K + kbase + a_kg0*8;
        const unsigned* s1 = Apr + (size_t)(row0 + a_r1)*K + kbase + a_kg1*8;
        pa0[0] = *(const uint4*)s0; pa0[1] = *(const uint4*)(s0+4);
        pa1[0] = *(const uint4*)s1; pa1[1] = *(const uint4*)(s1+4);
        #pragma unroll
        for (int j=0;j<8;j++)
            pb[j] = *(const uint4*)(Wpr + (size_t)(kbase + b_kg*8 + j)*N + col0 + b_c4);
    }

    #define STAGE_A(pr, ar, kg) { \
        bf8v hv, lv; \
        hv[0]=(short)(pr[0].x); lv[0]=(short)(pr[0].x>>16); \
        hv[1]=(short)(pr[0].y); lv[1]=(short)(pr[0].y>>16); \
        hv[2]=(short)(pr[0].z); lv[2]=(short)(pr[0].z>>16); \
        hv[3]=(short)(pr[0].w); lv[3]=(short)(pr[0].w>>16); \
        hv[4]=(short)(pr[1].x); lv[4]=(short)(pr[1].x>>16); \
        hv[5]=(short)(pr[1].y); lv[5]=(short)(pr[1].y>>16); \
        hv[6]=(short)(pr[1].z); lv[6]=(short)(pr[1].z>>16); \
        hv[7]=(short)(pr[1].w); lv[7]=(short)(pr[1].w>>16); \
        const int lane_ = ((ar) & 15) | (((kg) & 3) << 4); \
        *(bf8v*)&Ah[kh][(kg)>>2][(ar)>>4][lane_][0] = hv; \
        *(bf8v*)&Al[kh][(kg)>>2][(ar)>>4][lane_][0] = lv; }

    #define STAGE_B() { \
        _Pragma("unroll") \
        for (int c=0;c<4;c++){ \
            bf8v hv, lv; \
            _Pragma("unroll") \
            for (int j=0;j<8;j++){ \
                const unsigned e = ((const unsigned*)&pb[j])[c]; \
                hv[j] = (short)e; lv[j] = (short)(e >> 16); \
            } \
            const int col_ = b_c4 + c; \
            const int lane_ = (col_ & 15) | ((b_kg & 3) << 4); \
            *(bf8v*)&Bh[kh][b_kg>>2][col_>>4][lane_][0] = hv; \
            *(bf8v*)&Bl[kh][b_kg>>2][col_>>4][lane_][0] = lv; } }

    // stage tile 0
    STAGE_A(pa0, a_r0, a_kg0)
    STAGE_A(pa1, a_r1, a_kg1)
    STAGE_B()
    __syncthreads();

    int k0 = 0;
    while (true){
        const int kn = k0 + 64;
        const bool more = kn < K2;
        if (more){
            const unsigned* s0 = Apr + (size_t)(row0 + a_r0)*K + kbase + kn + a_kg0*8;
            const unsigned* s1 = Apr + (size_t)(row0 + a_r1)*K + kbase + kn + a_kg1*8;
            pa0[0] = *(const uint4*)s0; pa0[1] = *(const uint4*)(s0+4);
            pa1[0] = *(const uint4*)s1; pa1[1] = *(const uint4*)(s1+4);
            #pragma unroll
            for (int j=0;j<8;j++)
                pb[j] = *(const uint4*)(Wpr + (size_t)(kbase + kn + b_kg*8 + j)*N + col0 + b_c4);
        }
        #pragma unroll
        for (int ks=0; ks<2; ks++){
            const bf8v ah0 = *(const bf8v*)&Ah[kh][ks][mb+0][l][0];
            const bf8v ah1 = *(const bf8v*)&Ah[kh][ks][mb+1][l][0];
            const bf8v al0 = *(const bf8v*)&Al[kh][ks][mb+0][l][0];
            const bf8v al1 = *(const bf8v*)&Al[kh][ks][mb+1][l][0];
            #pragma unroll
            for (int nf=0; nf<4; nf++){
                const bf8v bh = *(const bf8v*)&Bh[kh][ks][nb+nf][l][0];
                const bf8v bl = *(const bf8v*)&Bl[kh][ks][nb+nf][l][0];
                acc[0][nf] = __builtin_amdgcn_mfma_f32_16x16x32_bf16(ah0, bh, acc[0][nf], 0,0,0);
                acc[0][nf] = __builtin_amdgcn_mfma_f32_16x16x32_bf16(ah0, bl, acc[0][nf], 0,0,0);
                acc[0][nf] = __builtin_amdgcn_mfma_f32_16x16x32_bf16(al0, bh, acc[0][nf], 0,0,0);
                acc[1][nf] = __builtin_amdgcn_mfma_f32_16x16x32_bf16(ah1, bh, acc[1][nf], 0,0,0);
                acc[1][nf] = __builtin_amdgcn_mfma_f32_16x16x32_bf16(ah1, bl, acc[1][nf], 0,0,0);
                acc[1][nf] = __builtin_amdgcn_mfma_f32_16x16x32_bf16(al1, bh, acc[1][nf], 0,0,0);
            }
        }
        __syncthreads();        // both halves done reading this tile
        if (!more) break;
        STAGE_A(pa0, a_r0, a_kg0)
        STAGE_A(pa1, a_r1, a_kg1)
        STAGE_B()
        __syncthreads();        // next tile staged
        k0 = kn;
    }

    // deterministic half-combine via LDS (kh1 -> kh0)
    float* cs = (float*)&Ah[0][0][0][0][0];
    if (kh == 1){
        #pragma unroll
        for (int mf=0; mf<2; mf++)
            #pragma unroll
            for (int nf=0; nf<4; nf++){
                f4 p;
                p.x=acc[mf][nf][0]; p.y=acc[mf][nf][1];
                p.z=acc[mf][nf][2]; p.w=acc[mf][nf][3];
                *(f4*)(cs + 4*(((mf*4+nf))*256 + t)) = p;
            }
    }
    __syncthreads();
    if (kh == 0){
        #pragma unroll
        for (int mf=0; mf<2; mf++)
            #pragma unroll
            for (int nf=0; nf<4; nf++){
                const f4 p = *(const f4*)(cs + 4*(((mf*4+nf))*256 + t));
                acc[mf][nf][0]+=p.x; acc[mf][nf][1]+=p.y;
                acc[mf][nf][2]+=p.z; acc[mf][nf][3]+=p.w;
            }
        const int ecol = l & 15, erow = (l >> 4) * 4;
        #pragma unroll
        for (int mf=0; mf<2; mf++){
            #pragma unroll
            for (int nf=0; nf<4; nf++){
                const int col = col0 + (w&1)*64 + nf*16 + ecol;
                const float bv = bias[col];
                #pragma unroll
                for (int j=0; j<4; j++){
                    const int row = row0 + (w>>1)*32 + mf*16 + erow + j;
                    float v = acc[mf][nf][j] + bv;
                    if (act==1) v = fmaxf(v, 0.f);
                    else if (act==2) v = gelu_f(v);
                    if (hasres) v += res[(size_t)row*N + col];
                    if (outpair) Cp[(size_t)row*N + col] = f32_to_pair(v);
                    else         Cf[(size_t)row*N + col] = v;
                }
            }
        }
    }
    #undef STAGE_A
    #undef STAGE_B
}

// f32 GEMM kept for projectors + locate head
__global__ __launch_bounds__(512) void gemm128k2(
    const float* __restrict__ A, const float* __restrict__ W,
    const float* __restrict__ bias, const float* __restrict__ res,
    float* __restrict__ C, int M, int N, int K, int act, int hasres)
{
    __shared__ float As[2][32][68];
    __shared__ float Ws[2][32][132];
    const int tid = threadIdx.x;
    const int kh = tid >> 8;
    const int t  = tid & 255;
    const int row0 = blockIdx.y*64, col0 = blockIdx.x*128;
    const int ty = t>>4, tx = t&15;
    const int am = t>>2, ak = (t&3)*8;
    const int wk = t>>3, u  = t&7;
    const int K2 = K >> 1;
    const float* Ap = A + (size_t)(row0+am)*K + kh*K2 + ak;
    const float* Wp = W + (size_t)(kh*K2 + wk)*N + col0 + u*16;
    float* Wrow = &Ws[kh][wk][0];

    f4 a0,a1,w0,w1,w2,w3;
    a0 = *(const f4*)(Ap);
    a1 = *(const f4*)(Ap + 4);
    w0 = *(const f4*)(Wp);
    w1 = *(const f4*)(Wp + 4);
    w2 = *(const f4*)(Wp + 8);
    w3 = *(const f4*)(Wp + 12);
    As[kh][ak+0][am]=a0.x; As[kh][ak+1][am]=a0.y; As[kh][ak+2][am]=a0.z; As[kh][ak+3][am]=a0.w;
    As[kh][ak+4][am]=a1.x; As[kh][ak+5][am]=a1.y; As[kh][ak+6][am]=a1.z; As[kh][ak+7][am]=a1.w;
    *(f4*)(Wrow + 8*u)      = w0;
    *(f4*)(Wrow + 8*u + 4)  = w2;
    *(f4*)(Wrow + 64 + 8*u)     = w1;
    *(f4*)(Wrow + 64 + 8*u + 4) = w3;
    __syncthreads();

    float acc[4][8];
    #pragma unroll
    for (int i=0;i<4;i++){
        #pragma unroll
        for (int j=0;j<8;j++) acc[i][j]=0.f;
    }

    int k0 = 0;
    while (true){
        const int kn = k0 + 32;
        const bool more = kn < K2;
        if (more){
            a0 = *(const f4*)(Ap + kn);
            a1 = *(const f4*)(Ap + kn + 4);
            w0 = *(const f4*)(Wp + (size_t)kn*N);
            w1 = *(const f4*)(Wp + (size_t)kn*N + 4);
            w2 = *(const f4*)(Wp + (size_t)kn*N + 8);
            w3 = *(const f4*)(Wp + (size_t)kn*N + 12);
        }
        #pragma unroll
        for (int kk=0;kk<32;kk++){
            f4 a  = *(const f4*)&As[kh][kk][ty*4];
            f4 wA = *(const f4*)&Ws[kh][kk][tx*4];
            f4 wB = *(const f4*)&Ws[kh][kk][64 + tx*4];
            float ar[4] = {a.x,a.y,a.z,a.w};
            #pragma unroll
            for (int i=0;i<4;i++){
                acc[i][0] += ar[i]*wA.x;
                acc[i][1] += ar[i]*wA.y;
                acc[i][2] += ar[i]*wA.z;
                acc[i][3] += ar[i]*wA.w;
                acc[i][4] += ar[i]*wB.x;
                acc[i][5] += ar[i]*wB.y;
                acc[i][6] += ar[i]*wB.z;
                acc[i][7] += ar[i]*wB.w;
            }
        }
        __syncthreads();
        if (!more) break;
        As[kh][ak+0][am]=a0.x; As[kh][ak+1][am]=a0.y; As[kh][ak+2][am]=a0.z; As[kh][ak+3][am]=a0.w;
        As[kh][ak+4][am]=a1.x; As[kh][ak+5][am]=a1.y; As[kh][ak+6][am]=a1.z; As[kh][ak+7][am]=a1.w;
        *(f4*)(Wrow + 8*u)      = w0;
        *(f4*)(Wrow + 8*u + 4)  = w2;
        *(f4*)(Wrow + 64 + 8*u)     = w1;
        *(f4*)(Wrow + 64 + 8*u + 4) = w3;
        __syncthreads();
        k0 = kn;
    }

    float* cs = &Ws[0][0][0];
    if (kh == 1){
        #pragma unroll
        for (int i=0;i<4;i++){
            #pragma unroll
            for (int b=0;b<2;b++){
                f4 p;
                p.x=acc[i][b*4+0]; p.y=acc[i][b*4+1]; p.z=acc[i][b*4+2]; p.w=acc[i][b*4+3];
                *(f4*)(cs + 4*(((i<<1)|b)*256 + t)) = p;
            }
        }
    }
    __syncthreads();
    if (kh == 0){
        #pragma unroll
        for (int i=0;i<4;i++){
            #pragma unroll
            for (int b=0;b<2;b++){
                const f4 p = *(const f4*)(cs + 4*(((i<<1)|b)*256 + t));
                acc[i][b*4+0]+=p.x; acc[i][b*4+1]+=p.y; acc[i][b*4+2]+=p.z; acc[i][b*4+3]+=p.w;
            }
        }
        #pragma unroll
        for (int i=0;i<4;i++){
            const int r = row0 + ty*4 + i;
            #pragma unroll
            for (int half=0; half<2; ++half){
                const int cb = col0 + tx*8 + half*4;
                f4 bv = *(const f4*)(bias + cb);
                float t0 = acc[i][half*4+0] + bv.x;
                float t1 = acc[i][half*4+1] + bv.y;
                float t2 = acc[i][half*4+2] + bv.z;
                float t3 = acc[i][half*4+3] + bv.w;
                if (act==1){ t0=fmaxf(t0,0.f); t1=fmaxf(t1,0.f); t2=fmaxf(t2,0.f); t3=fmaxf(t3,0.f); }
                else if (act==2){ t0=gelu_f(t0); t1=gelu_f(t1); t2=gelu_f(t2); t3=gelu_f(t3); }
                if (hasres){
                    f4 rv = *(const f4*)(res + (size_t)r*N + cb);
                    t0+=rv.x; t1+=rv.y; t2+=rv.z; t3+=rv.w;
                }
                f4 o; o.x=t0; o.y=t1; o.z=t2; o.w=t3;
                *(f4*)(C + (size_t)r*N + cb) = o;
            }
        }
    }
}

__global__ __launch_bounds__(256) void lnrow(
    const float* __restrict__ X, const float* __restrict__ g,
    const float* __restrict__ b, float* __restrict__ out, float eps)
{
    __shared__ float red[4];
    const int row = blockIdx.x, tid = threadIdx.x;
    const float* xp = X + (size_t)row*D_MOD;
    f4 xv = *(const f4*)(xp + tid*4);
    float s = xv.x+xv.y+xv.z+xv.w;
    #pragma unroll
    for (int m=1;m<64;m<<=1) s += __shfl_xor(s, m);
    const int wid = tid>>6, lane = tid&63;
    if (lane==0) red[wid]=s;
    __syncthreads();
    float mean = (red[0]+red[1]+red[2]+red[3]) * (1.0f/1024.0f);
    __syncthreads();
    float d0=xv.x-mean, d1=xv.y-mean, d2=xv.z-mean, d3=xv.w-mean;
    float q = d0*d0+d1*d1+d2*d2+d3*d3;
    #pragma unroll
    for (int m=1;m<64;m<<=1) q += __shfl_xor(q, m);
    if (lane==0) red[wid]=q;
    __syncthreads();
    float var = (red[0]+red[1]+red[2]+red[3]) * (1.0f/1024.0f);
    float inv = rsqrtf(var + eps);
    f4 gv = *(const f4*)(g + tid*4);
    f4 bv = *(const f4*)(b + tid*4);
    f4 o;
    o.x = d0*inv*gv.x + bv.x;
    o.y = d1*inv*gv.y + bv.y;
    o.z = d2*inv*gv.z + bv.z;
    o.w = d3*inv*gv.w + bv.w;
    *(f4*)(out + (size_t)row*D_MOD + tid*4) = o;
}

__global__ __launch_bounds__(256) void lnrow_pair(
    const float* __restrict__ X, const float* __restrict__ g,
    const float* __restrict__ b, unsigned* __restrict__ outp, float eps)
{
    __shared__ float red[4];
    const int row = blockIdx.x, tid = threadIdx.x;
    const float* xp = X + (size_t)row*D_MOD;
    f4 xv = *(const f4*)(xp + tid*4);
    float s = xv.x+xv.y+xv.z+xv.w;
    #pragma unroll
    for (int m=1;m<64;m<<=1) s += __shfl_xor(s, m);
    const int wid = tid>>6, lane = tid&63;
    if (lane==0) red[wid]=s;
    __syncthreads();
    float mean = (red[0]+red[1]+red[2]+red[3]) * (1.0f/1024.0f);
    __syncthreads();
    float d0=xv.x-mean, d1=xv.y-mean, d2=xv.z-mean, d3=xv.w-mean;
    float q = d0*d0+d1*d1+d2*d2+d3*d3;
    #pragma unroll
    for (int m=1;m<64;m<<=1) q += __shfl_xor(q, m);
    if (lane==0) red[wid]=q;
    __syncthreads();
    float var = (red[0]+red[1]+red[2]+red[3]) * (1.0f/1024.0f);
    float inv = rsqrtf(var + eps);
    f4 gv = *(const f4*)(g + tid*4);
    f4 bv = *(const f4*)(b + tid*4);
    uint4 o;
    o.x = f32_to_pair(d0*inv*gv.x + bv.x);
    o.y = f32_to_pair(d1*inv*gv.y + bv.y);
    o.z = f32_to_pair(d2*inv*gv.z + bv.z);
    o.w = f32_to_pair(d3*inv*gv.w + bv.w);
    ((uint4*)(outp + (size_t)row*D_MOD))[tid] = o;
}

// MFMA flash attention, bf16x2 (R12, validated)
__global__ __launch_bounds__(256,1) void attn_mfma(
    const float* __restrict__ Q, const float* __restrict__ Kb,
    const float* __restrict__ Vb,
    float* __restrict__ OA0, float* __restrict__ OA1,
    float* __restrict__ ML0, float* __restrict__ ML1)
{
    __shared__ short QhS[4][8][64][8];
    __shared__ short QlS[4][8][64][8];
    __shared__ short KhS[4][4][64][8];
    __shared__ short KlS[4][4][64][8];
    __shared__ short VhS[2][8][64][8];
    __shared__ short VlS[2][8][64][8];
    short* Ph = &KhS[0][0][0][0];
    short* Pl = &KlS[0][0][0][0];

    const int tid = threadIdx.x;
    const int w = tid >> 6, l = tid & 63;
    const int h  = blockIdx.x & 7;
    const int sh = (blockIdx.x >> 3) & 1;
    const int q0 = (blockIdx.x >> 4) * 128;
    const int sbase = sh * 1024;
    const float qscale = 0.08838834764831845f;

    #pragma unroll
    for (int i=0;i<2;i++){
        const int u = tid + i*256;
        const int qr = u >> 2, dks = u & 3;
        const float* src = Q + (size_t)(q0+qr)*D_MOD + h*128 + dks*32;
        float a[32];
        #pragma unroll
        for (int j=0;j<8;j++) *(f4*)&a[j*4] = ((const f4*)src)[j];
        const int qmf = qr >> 4;
        #pragma unroll
        for (int kg=0;kg<4;kg++){
            bf8v hv, lv;
            #pragma unroll
            for (int e=0;e<8;e++){
                short hi, lo;
                split2(a[kg*8+e]*qscale, hi, lo);
                hv[e]=hi; lv[e]=lo;
            }
            const int lane = (qr & 15) | (kg << 4);
            *(bf8v*)&QhS[dks][qmf][lane][0] = hv;
            *(bf8v*)&QlS[dks][qmf][lane][0] = lv;
        }
    }
    {
        const int sr = tid >> 2, dks = tid & 3;
        const float* src = Kb + (size_t)(sbase+sr)*D_MOD + h*128 + dks*32;
        float a[32];
        #pragma unroll
        for (int j=0;j<8;j++) *(f4*)&a[j*4] = ((const f4*)src)[j];
        const int smf = sr >> 4;
        #pragma unroll
        for (int kg=0;kg<4;kg++){
            bf8v hv, lv;
            #pragma unroll
            for (int e=0;e<8;e++){ short hi,lo; split2(a[kg*8+e],hi,lo); hv[e]=hi; lv[e]=lo; }
            const int lane = (sr & 15) | (kg << 4);
            *(bf8v*)&KhS[dks][smf][lane][0] = hv;
            *(bf8v*)&KlS[dks][smf][lane][0] = lv;
        }
        const int s8 = tid >> 5, d4 = (tid & 31) * 4;
        float b[8][4];
        #pragma unroll
        for (int r=0;r<8;r++)
            *(f4*)&b[r][0] = *(const f4*)(Vb + (size_t)(sbase+s8*8+r)*D_MOD + h*128 + d4);
        const int sks = s8 >> 2, sg = s8 & 3;
        #pragma unroll
        for (int c=0;c<4;c++){
            bf8v hv, lv;
            #pragma unroll
            for (int r=0;r<8;r++){ short hi,lo; split2(b[r][c],hi,lo); hv[r]=hi; lv[r]=lo; }
            const int d = d4 + c;
            const int lane = (d & 15) | (sg << 4);
            *(bf8v*)&VhS[sks][d>>4][lane][0] = hv;
            *(bf8v*)&VlS[sks][d>>4][lane][0] = lv;
        }
    }
    __syncthreads();

    float mstat[8], lstat[8];
    f4v oacc[2][8];
    #pragma unroll
    for (int i=0;i<8;i++){ mstat[i] = -__builtin_inff(); lstat[i] = 0.f; }
    #pragma unroll
    for (int i=0;i<2;i++)
        #pragma unroll
        for (int j=0;j<8;j++) oacc[i][j] = (f4v){0.f,0.f,0.f,0.f};

    for (int t=0; t<16; ++t){
        f4v sacc[2][4];
        #pragma unroll
        for (int i=0;i<2;i++)
            #pragma unroll
            for (int j=0;j<4;j++) sacc[i][j] = (f4v){0.f,0.f,0.f,0.f};
        #pragma unroll
        for (int dks=0; dks<4; dks++){
            const bf8v qh0 = *(const bf8v*)&QhS[dks][2*w+0][l][0];
            const bf8v qh1 = *(const bf8v*)&QhS[dks][2*w+1][l][0];
            const bf8v ql0 = *(const bf8v*)&QlS[dks][2*w+0][l][0];
            const bf8v ql1 = *(const bf8v*)&QlS[dks][2*w+1][l][0];
            #pragma unroll
            for (int sf=0; sf<4; sf++){
                const bf8v kh = *(const bf8v*)&KhS[dks][sf][l][0];
                const bf8v kl = *(const bf8v*)&KlS[dks][sf][l][0];
                sacc[0][sf] = __builtin_amdgcn_mfma_f32_16x16x32_bf16(qh0, kh, sacc[0][sf], 0,0,0);
                sacc[0][sf] = __builtin_amdgcn_mfma_f32_16x16x32_bf16(qh0, kl, sacc[0][sf], 0,0,0);
                sacc[0][sf] = __builtin_amdgcn_mfma_f32_16x16x32_bf16(ql0, kh, sacc[0][sf], 0,0,0);
                sacc[1][sf] = __builtin_amdgcn_mfma_f32_16x16x32_bf16(qh1, kh, sacc[1][sf], 0,0,0);
                sacc[1][sf] = __builtin_amdgcn_mfma_f32_16x16x32_bf16(qh1, kl, sacc[1][sf], 0,0,0);
                sacc[1][sf] = __builtin_amdgcn_mfma_f32_16x16x32_bf16(ql1, kh, sacc[1][sf], 0,0,0);
            }
        }
        __syncthreads();

        float scr[8];
        #pragma unroll
        for (int mfi=0; mfi<2; mfi++){
            #pragma unroll
            for (int j=0; j<4; j++){
                const int si = mfi*4 + j;
                float tm = fmaxf(fmaxf(sacc[mfi][0][j], sacc[mfi][1][j]),
                                 fmaxf(sacc[mfi][2][j], sacc[mfi][3][j]));
                tm = fmaxf(tm, __shfl_xor(tm,1));
                tm = fmaxf(tm, __shfl_xor(tm,2));
                tm = fmaxf(tm, __shfl_xor(tm,4));
                tm = fmaxf(tm, __shfl_xor(tm,8));
                const float mn = fmaxf(mstat[si], tm);
                const float sc = __expf(mstat[si] - mn);
                float rs = 0.f;
                #pragma unroll
                for (int sf=0; sf<4; sf++){
                    const float p = __expf(sacc[mfi][sf][j] - mn);
                    sacc[mfi][sf][j] = p; rs += p;
                }
                rs += __shfl_xor(rs,1); rs += __shfl_xor(rs,2);
                rs += __shfl_xor(rs,4); rs += __shfl_xor(rs,8);
                lstat[si] = lstat[si]*sc + rs;
                mstat[si] = mn;
                scr[si] = sc;
            }
        }
        {
            const int pe = l & 7;
            const int rb4 = (l >> 4) * 4;
            const int sgb = (l & 15) >> 3;
            #pragma unroll
            for (int mfi=0; mfi<2; mfi++){
                const int qmf = 2*w + mfi;
                #pragma unroll
                for (int sf=0; sf<4; sf++){
                    const int sks = sf >> 1;
                    const int sg = (sf & 1)*2 + sgb;
                    #pragma unroll
                    for (int j=0; j<4; j++){
                        const int lane = (rb4 + j) | (sg << 4);
                        short hi, lo;
                        split2(sacc[mfi][sf][j], hi, lo);
                        const int off = ((sks*8 + qmf)*64 + lane)*8 + pe;
                        Ph[off] = hi;
                        Pl[off] = lo;
                    }
                }
            }
        }
        __syncthreads();

        #pragma unroll
        for (int mfi=0; mfi<2; mfi++){
            #pragma unroll
            for (int j=0; j<4; j++){
                const float sc = scr[mfi*4+j];
                #pragma unroll
                for (int dmf=0; dmf<8; dmf++) oacc[mfi][dmf][j] *= sc;
            }
        }
        #pragma unroll
        for (int sks=0; sks<2; sks++){
            const bf8v ph0 = *(const bf8v*)&Ph[((sks*8 + 2*w+0)*64 + l)*8];
            const bf8v ph1 = *(const bf8v*)&Ph[((sks*8 + 2*w+1)*64 + l)*8];
            const bf8v pl0 = *(const bf8v*)&Pl[((sks*8 + 2*w+0)*64 + l)*8];
            const bf8v pl1 = *(const bf8v*)&Pl[((sks*8 + 2*w+1)*64 + l)*8];
            #pragma unroll
            for (int dmf=0; dmf<8; dmf++){
                const bf8v vh = *(const bf8v*)&VhS[sks][dmf][l][0];
                const bf8v vl = *(const bf8v*)&VlS[sks][dmf][l][0];
                oacc[0][dmf] = __builtin_amdgcn_mfma_f32_16x16x32_bf16(ph0, vh, oacc[0][dmf], 0,0,0);
                oacc[0][dmf] = __builtin_amdgcn_mfma_f32_16x16x32_bf16(ph0, vl, oacc[0][dmf], 0,0,0);
                oacc[0][dmf] = __builtin_amdgcn_mfma_f32_16x16x32_bf16(pl0, vh, oacc[0][dmf], 0,0,0);
                oacc[1][dmf] = __builtin_amdgcn_mfma_f32_16x16x32_bf16(ph1, vh, oacc[1][dmf], 0,0,0);
                oacc[1][dmf] = __builtin_amdgcn_mfma_f32_16x16x32_bf16(ph1, vl, oacc[1][dmf], 0,0,0);
                oacc[1][dmf] = __builtin_amdgcn_mfma_f32_16x16x32_bf16(pl1, vh, oacc[1][dmf], 0,0,0);
            }
        }
        __syncthreads();

        if (t < 15){
            const int sb = sbase + (t+1)*64;
            const int sr = tid >> 2, dks = tid & 3;
            const float* src = Kb + (size_t)(sb+sr)*D_MOD + h*128 + dks*32;
            float a[32];
            #pragma unroll
            for (int j=0;j<8;j++) *(f4*)&a[j*4] = ((const f4*)src)[j];
            const int smf = sr >> 4;
            #pragma unroll
            for (int kg=0;kg<4;kg++){
                bf8v hv, lv;
                #pragma unroll
                for (int e=0;e<8;e++){ short hi,lo; split2(a[kg*8+e],hi,lo); hv[e]=hi; lv[e]=lo; }
                const int lane = (sr & 15) | (kg << 4);
                *(bf8v*)&KhS[dks][smf][lane][0] = hv;
                *(bf8v*)&KlS[dks][smf][lane][0] = lv;
            }
            const int s8 = tid >> 5, d4 = (tid & 31) * 4;
            float b[8][4];
            #pragma unroll
            for (int r=0;r<8;r++)
                *(f4*)&b[r][0] = *(const f4*)(Vb + (size_t)(sb+s8*8+r)*D_MOD + h*128 + d4);
            const int sks = s8 >> 2, sg = s8 & 3;
            #pragma unroll
            for (int c=0;c<4;c++){
                bf8v hv, lv;
                #pragma unroll
                for (int r=0;r<8;r++){ short hi,lo; split2(b[r][c],hi,lo); hv[r]=hi; lv[r]=lo; }
                const int d = d4 + c;
                const int lane = (d & 15) | (sg << 4);
                *(bf8v*)&VhS[sks][d>>4][lane][0] = hv;
                *(bf8v*)&VlS[sks][d>>4][lane][0] = lv;
            }
        }
        __syncthreads();
    }

    float* OAp = sh ? OA1 : OA0;
    float* MLp = sh ? ML1 : ML0;
    const int erow = (l >> 4) * 4, ecol = l & 15;
    #pragma unroll
    for (int mfi=0; mfi<2; mfi++){
        #pragma unroll
        for (int dmf=0; dmf<8; dmf++){
            const int col = h*128 + dmf*16 + ecol;
            #pragma unroll
            for (int j=0; j<4; j++){
                const int row = q0 + w*32 + mfi*16 + erow + j;
                OAp[(size_t)row*D_MOD + col] = oacc[mfi][dmf][j];
            }
        }
    }
    if (ecol == 0){
        #pragma unroll
        for (int mfi=0; mfi<2; mfi++){
            #pragma unroll
            for (int j=0; j<4; j++){
                const int row = q0 + w*32 + mfi*16 + erow + j;
                MLp[(size_t)row*16 + h*2 + 0] = mstat[mfi*4+j];
                MLp[(size_t)row*16 + h*2 + 1] = lstat[mfi*4+j];
            }
        }
    }
}

// flash-combine of the two s-halves + bias-KV token; writes bf16-pair output
__global__ __launch_bounds__(256) void attn_combine(
    const float* __restrict__ Q, const float* __restrict__ kbias,
    const float* __restrict__ vbias,
    const float* __restrict__ OA0, const float* __restrict__ OA1,
    const float* __restrict__ ML0, const float* __restrict__ ML1,
    unsigned* __restrict__ OP)
{
    const int row = blockIdx.x, t = threadIdx.x;
    const int h = t >> 5;
    const int cc = t & 31;
    const float qscale = 0.08838834764831845f;
    const f4 qv = *(const f4*)(Q + (size_t)row*D_MOD + h*128 + cc*4);
    const f4 kb = *(const f4*)(kbias + h*128 + cc*4);
    float part = qv.x*kb.x + qv.y*kb.y + qv.z*kb.z + qv.w*kb.w;
    part += __shfl_xor(part,1); part += __shfl_xor(part,2);
    part += __shfl_xor(part,4); part += __shfl_xor(part,8);
    part += __shfl_xor(part,16);
    const float sb = part * qscale;
    const float m0 = ML0[(size_t)row*16 + h*2], l0 = ML0[(size_t)row*16 + h*2 + 1];
    const float m1 = ML1[(size_t)row*16 + h*2], l1 = ML1[(size_t)row*16 + h*2 + 1];
    const float M  = fmaxf(fmaxf(m0, m1), sb);
    const float w0 = __expf(m0 - M), w1 = __expf(m1 - M), wb = __expf(sb - M);
    const float inv = 1.0f / (w0*l0 + w1*l1 + wb);
    const f4 o0 = *(const f4*)(OA0 + (size_t)row*D_MOD + t*4);
    const f4 o1 = *(const f4*)(OA1 + (size_t)row*D_MOD + t*4);
    const f4 vb = *(const f4*)(vbias + h*128 + cc*4);
    uint4 o;
    o.x = f32_to_pair((o0.x*w0 + o1.x*w1 + vb.x*wb) * inv);
    o.y = f32_to_pair((o0.y*w0 + o1.y*w1 + vb.y*wb) * inv);
    o.z = f32_to_pair((o0.z*w0 + o1.z*w1 + vb.z*wb) * inv);
    o.w = f32_to_pair((o0.w*w0 + o1.w*w1 + vb.w*wb) * inv);
    *(uint4*)(OP + (size_t)row*D_MOD + t*4) = o;
}

__global__ __launch_bounds__(64) void locate_head(
    const float* __restrict__ mid, const float* __restrict__ W2,
    const float* __restrict__ b2, float* __restrict__ loc_ws,
    float* __restrict__ loc_out)
{
    const int row = blockIdx.x, lane = threadIdx.x;
    const float* m = mid + (size_t)row*512;
    f4 v0 = *(const f4*)(m + lane*8);
    f4 v1 = *(const f4*)(m + lane*8 + 4);
    f4 w0 = *(const f4*)(W2 + lane*8);
    f4 w1 = *(const f4*)(W2 + lane*8 + 4);
    float s = v0.x*w0.x + v0.y*w0.y + v0.z*w0.z + v0.w*w0.w
            + v1.x*w1.x + v1.y*w1.y + v1.z*w1.z + v1.w*w1.w;
    #pragma unroll
    for (int mm=1; mm<64; mm<<=1) s += __shfl_xor(s, mm);
    if (lane==0){
        float z = s + b2[0];
        float l = 1.0f/(1.0f + expf(-z));
        loc_ws[row] = l;
        loc_out[row] = l;
    }
}

__global__ __launch_bounds__(1024) void segscan(
    const float* __restrict__ located, const float* __restrict__ thrp,
    float* __restrict__ out_segid, float* __restrict__ out_segtype,
    float* __restrict__ out_numseg, int* __restrict__ wsi)
{
    __shared__ int clips[2048];
    __shared__ int segid[2048];
    __shared__ int sstart[2049];
    __shared__ int wsum[16];
    const int tid = threadIdx.x;
    const float thr = *thrp;
    for (int t=tid; t<2048; t+=1024) clips[t] = (located[t] > thr) ? 1 : 0;
    __syncthreads();
    const int t0 = tid*2, t1 = t0+1;
    int f0 = (t0==0) ? 0 : (clips[t0]!=clips[t0-1] ? 1 : 0);
    int f1 = (clips[t1]!=clips[t1-1] ? 1 : 0);
    int e0 = f0, e1 = f0+f1;
    const int lane = tid&63, wid = tid>>6;
    int v = e1;
    #pragma unroll
    for (int off=1; off<64; off<<=1){
        int u = __shfl_up(v, off, 64);
        if (lane>=off) v += u;
    }
    if (lane==63) wsum[wid] = v;
    __syncthreads();
    if (tid < 16){
        int w = wsum[tid];
        #pragma unroll
        for (int off=1; off<16; off<<=1){
            int u = __shfl_up(w, off, 16);
            if (tid>=off) w += u;
        }
        wsum[tid] = w;
    }
    __syncthreads();
    int base = (wid>0 ? wsum[wid-1] : 0) + (v - e1);
    segid[t0] = base + e0;
    segid[t1] = base + e1;
    __syncthreads();
    const int ns = segid[2047] + 1;
    for (int t=tid; t<2048; t+=1024){
        if (t==0 || segid[t]!=segid[t-1]) sstart[segid[t]] = t;
    }
    if (tid==0) sstart[ns] = 2048;
    __syncthreads();
    for (int t=tid; t<2048; t+=1024) out_segid[t] = (float)segid[t];
    for (int s=tid; s<2048; s+=1024)
        out_segtype[s] = (s<ns) ? (float)clips[sstart[s]] : -2147483648.0f;
    if (tid==0){ out_numseg[0] = (float)ns; wsi[0] = ns; }
    for (int s=tid; s<=2048; s+=1024) wsi[2+s] = (s<=ns) ? sstart[s] : 0;
}

__global__ __launch_bounds__(256) void segpool(
    const float* __restrict__ V, const float* __restrict__ A,
    const int* __restrict__ wsi, float* __restrict__ out_vid,
    float* __restrict__ out_aud)
{
    const int s = blockIdx.x;
    const int c = threadIdx.x*4;
    const int ns = wsi[0];
    f4 vv; vv.x=0.f; vv.y=0.f; vv.z=0.f; vv.w=0.f;
    f4 av = vv;
    if (s < ns){
        const int st = wsi[2+s], en = wsi[2+s+1];
        for (int r=st; r<en; ++r){
            f4 x = *(const f4*)(V + (size_t)r*D_MOD + c);
            vv.x+=x.x; vv.y+=x.y; vv.z+=x.z; vv.w+=x.w;
            f4 y = *(const f4*)(A + (size_t)r*D_MOD + c);
            av.x+=y.x; av.y+=y.y; av.z+=y.z; av.w+=y.w;
        }
        const float inv = 1.0f/(float)(en-st);
        vv.x*=inv; vv.y*=inv; vv.z*=inv; vv.w*=inv;
        av.x*=inv; av.y*=inv; av.z*=inv; av.w*=inv;
    }
    *(f4*)(out_vid + (size_t)s*D_MOD + c) = vv;
    *(f4*)(out_aud + (size_t)s*D_MOD + c) = av;
}

extern "C" void kernel_launch(void* const* d_in, const int* in_sizes, int n_in,
                              void* d_out, int out_size, void* d_ws, size_t ws_size,
                              hipStream_t stream) {
    (void)in_sizes; (void)n_in; (void)out_size; (void)ws_size;
    const float* video = (const float*)d_in[0];
    const float* audio = (const float*)d_in[1];
    const float* apW1  = (const float*)d_in[2];
    const float* apb1  = (const float*)d_in[3];
    const float* apW2  = (const float*)d_in[4];
    const float* apb2  = (const float*)d_in[5];
    const float* vpW1  = (const float*)d_in[6];
    const float* vpb1  = (const float*)d_in[7];
    const float* vpW2  = (const float*)d_in[8];
    const float* vpb2  = (const float*)d_in[9];
    const float* preg  = (const float*)d_in[10];
    const float* preb  = (const float*)d_in[11];
    const float* bWq   = (const float*)d_in[12];
    const float* bbq   = (const float*)d_in[13];
    const float* bWk   = (const float*)d_in[14];
    const float* bbk   = (const float*)d_in[15];
    const float* bWv   = (const float*)d_in[16];
    const float* bbv   = (const float*)d_in[17];
    const float* bWo   = (const float*)d_in[18];
    const float* bbo   = (const float*)d_in[19];
    const float* bbiask= (const float*)d_in[20];
    const float* bbiasv= (const float*)d_in[21];
    const float* bg1   = (const float*)d_in[22];
    const float* bb1   = (const float*)d_in[23];
    const float* bg2   = (const float*)d_in[24];
    const float* bb2   = (const float*)d_in[25];
    const float* bmW1  = (const float*)d_in[26];
    const float* bmb1  = (const float*)d_in[27];
    const float* bmW2  = (const float*)d_in[28];
    const float* bmb2  = (const float*)d_in[29];
    const float* lhW1  = (const float*)d_in[30];
    const float* lhb1  = (const float*)d_in[31];
    const float* lhW2  = (const float*)d_in[32];
    const float* lhb2  = (const float*)d_in[33];
    const float* thrp  = (const float*)d_in[34];

    float* ws = (float*)d_ws;
    float* V    = ws + 0;
    float* Abuf = ws + 2097152;
    float* X    = ws + 4194304;
    float* H    = ws + 6291456;
    float* Q    = ws + 8388608;
    float* Kb   = ws + 10485760;
    float* Vb   = ws + 12582912;
    float* Obuf = ws + 14680064;
    unsigned* M4p = (unsigned*)(ws + 8388608);
    float* M512 = ws + 16777216;
    float* LOC  = ws + 17825792;
    int*   WSI  = (int*)(ws + 17827840);
    float* ML0  = ws + 17829952;
    float* ML1  = ws + 17862720;
    unsigned* Vp  = (unsigned*)(ws + 17895488);
    unsigned* OPp = (unsigned*)(ws + 19992640);
    unsigned* WQp = (unsigned*)(ws + 22089792);
    unsigned* WKp = (unsigned*)(ws + 23138368);
    unsigned* WVp = (unsigned*)(ws + 24186944);
    unsigned* WOp = (unsigned*)(ws + 25235520);
    unsigned* W1p = (unsigned*)(ws + 26284096);
    unsigned* W2p = (unsigned*)(ws + 30478400);
    unsigned* Hp  = (unsigned*)H;

    float* out = (float*)d_out;
    float* out_vid     = out + 0;
    float* out_aud     = out + 2097152;
    float* out_loc     = out + 4194304;
    float* out_segid   = out + 4196352;
    float* out_segtype = out + 4198400;
    float* out_numseg  = out + 4200448;

    const dim3 B512(512);
    const dim3 B256(256);
    #define GRID128(M,N) dim3((N)/128,(M)/64)
    #define GRIDM(M,N)   dim3((N)/128,(M)/64)

    // projectors (f32 path, exact for pools)
    gemm128k2<<<GRID128(2048,512), B512, 0, stream>>>(audio, apW1, apb1, nullptr, M512, 2048,512,128, 1,0);
    gemm128k2<<<GRID128(2048,1024),B512, 0, stream>>>(M512, apW2, apb2, nullptr, Abuf, 2048,1024,512, 0,0);
    gemm128k2<<<GRID128(2048,512), B512, 0, stream>>>(video, vpW1, vpb1, nullptr, M512, 2048,512,1024, 1,0);
    gemm128k2<<<GRID128(2048,1024),B512, 0, stream>>>(M512, vpW2, vpb2, nullptr, V,    2048,1024,512, 0,0);
    lnrow<<<2048, B256, 0, stream>>>(Abuf, preg, preb, X, 1e-6f);
    convert1<<<2048, B256, 0, stream>>>(V, Vp, 524288);

    for (int l=0; l<8; ++l){
        const size_t wo = (size_t)l*1024*1024;
        const size_t bo = (size_t)l*1024;
        const size_t mo1 = (size_t)l*1024*4096;
        convert6<<<1536, B256, 0, stream>>>(bWq+wo, bWk+wo, bWv+wo, bWo+wo,
                                            bmW1+mo1, bmW2+mo1,
                                            WQp, WKp, WVp, WOp, W1p, W2p);
        lnrow_pair<<<2048, B256, 0, stream>>>(X, bg1+bo, bb1+bo, Hp, 1e-5f);
        gemm_mfma2<<<GRIDM(2048,1024), B512, 0, stream>>>(Hp, WQp, bbq+bo, nullptr, Q,  nullptr, 2048,1024,1024, 0,0,0);
        gemm_mfma2<<<GRIDM(2048,1024), B512, 0, stream>>>(Vp, WKp, bbk+bo, nullptr, Kb, nullptr, 2048,1024,1024, 0,0,0);
        gemm_mfma2<<<GRIDM(2048,1024), B512, 0, stream>>>(Vp, WVp, bbv+bo, nullptr, Vb, nullptr, 2048,1024,1024, 0,0,0);
        attn_mfma<<<256, B256, 0, stream>>>(Q, Kb, Vb, Obuf, H, ML0, ML1);
        attn_combine<<<2048, B256, 0, stream>>>(Q, bbiask+bo, bbiasv+bo, Obuf, H, ML0, ML1, OPp);
        gemm_mfma2<<<GRIDM(2048,1024), B512, 0, stream>>>(OPp, WOp, bbo+bo, X, X, nullptr, 2048,1024,1024, 0,1,0);
        lnrow_pair<<<2048, B256, 0, stream>>>(X, bg2+bo, bb2+bo, Hp, 1e-5f);
        gemm_mfma2<<<GRIDM(2048,4096), B512, 0, stream>>>(Hp, W1p, bmb1+(size_t)l*4096, nullptr, nullptr, M4p, 2048,4096,1024, 2,0,1);
        gemm_mfma2<<<GRIDM(2048,1024), B512, 0, stream>>>(M4p, W2p, bmb2+bo, X, X, nullptr, 2048,1024,4096, 0,1,0);
    }

    gemm128k2<<<GRID128(2048,512), B512, 0, stream>>>(X, lhW1, lhb1, nullptr, M512, 2048,512,1024, 1,0);
    locate_head<<<2048, dim3(64), 0, stream>>>(M512, lhW2, lhb2, LOC, out_loc);
    segscan<<<1, dim3(1024), 0, stream>>>(LOC, thrp, out_segid, out_segtype, out_numseg, WSI);
    segpool<<<2048, B256, 0, stream>>>(V, Abuf, WSI, out_vid, out_aud);
}

// Round 17
// 4320.543 us; speedup vs baseline: 1.0692x; 1.0692x over previous
//
#include <hip/hip_runtime.h>
#include <math.h>

typedef float4 f4;
typedef __attribute__((ext_vector_type(8))) short bf8v;
typedef __attribute__((ext_vector_type(4))) float f4v;

#define T_SEQ 2048
#define D_MOD 1024

__device__ __forceinline__ float gelu_f(float x){
    float u = 0.7978845608028654f*(x + 0.044715f*x*x*x);
    return 0.5f*x*(1.0f + tanhf(u));
}

// pack f32 -> (hi bf16 rounded, lo bf16) ; x ~= hi + lo
__device__ __forceinline__ unsigned f32_to_pair(float x){
    unsigned u = __float_as_uint(x);
    unsigned hi = (u + 0x7FFFu + ((u >> 16) & 1u)) >> 16;
    float hif = __uint_as_float(hi << 16);
    float lof = x - hif;
    unsigned v = __float_as_uint(lof);
    unsigned lo = (v + 0x7FFFu + ((v >> 16) & 1u)) >> 16;
    return hi | (lo << 16);
}

// truncating split: hi = trunc-bf16(x), lo = trunc-bf16(x-hi)
__device__ __forceinline__ void split2(float x, short& hi, short& lo){
    unsigned u = __float_as_uint(x);
    hi = (short)(u >> 16);
    float rem = x - __uint_as_float(u & 0xFFFF0000u);
    lo = (short)(__float_as_uint(rem) >> 16);
}

__global__ __launch_bounds__(256) void convert1(
    const float* __restrict__ s, unsigned* __restrict__ d, int n4)
{
    const int i = blockIdx.x*256 + threadIdx.x;
    if (i < n4){
        f4 v = ((const f4*)s)[i];
        uint4 o;
        o.x = f32_to_pair(v.x); o.y = f32_to_pair(v.y);
        o.z = f32_to_pair(v.z); o.w = f32_to_pair(v.w);
        ((uint4*)d)[i] = o;
    }
}

// bf16x2 MFMA GEMM, 256 threads, 3 blocks/CU (48KB LDS) — for LARGE grids (mW1).
// A given as pairs; W read as raw f32 and split in staging (same bytes).
__global__ __launch_bounds__(256) void gemm_mfma(
    const unsigned* __restrict__ Apr, const float* __restrict__ Wf,
    const float* __restrict__ bias, const float* __restrict__ res,
    float* __restrict__ Cf, unsigned* __restrict__ Cp,
    int M, int N, int K, int act, int hasres, int outpair)
{
    __shared__ short Ah[2][4][64][8];
    __shared__ short Al[2][4][64][8];
    __shared__ short Bh[2][8][64][8];
    __shared__ short Bl[2][8][64][8];
    const int tid = threadIdx.x;
    const int w = tid >> 6, l = tid & 63;
    const int row0 = blockIdx.y * 64, col0 = blockIdx.x * 128;
    const int mb = (w >> 1) * 2;
    const int nb = (w & 1) * 4;

    f4v acc[2][4];
    #pragma unroll
    for (int i=0;i<2;i++)
        #pragma unroll
        for (int j=0;j<4;j++) acc[i][j] = (f4v){0.f,0.f,0.f,0.f};

    const int b_c4 = (tid & 31) * 4;
    const int b_kg = tid >> 5;

    for (int k0 = 0; k0 < K; k0 += 64){
        if (k0) __syncthreads();
        #pragma unroll
        for (int i=0;i<2;i++){
            const int u = tid + i*256;
            const int ar = u >> 3, kg = u & 7;
            const unsigned* src = Apr + (size_t)(row0 + ar)*K + k0 + kg*8;
            const uint4 p0 = *(const uint4*)src;
            const uint4 p1 = *(const uint4*)(src + 4);
            bf8v hv, lv;
            hv[0]=(short)(p0.x); lv[0]=(short)(p0.x>>16);
            hv[1]=(short)(p0.y); lv[1]=(short)(p0.y>>16);
            hv[2]=(short)(p0.z); lv[2]=(short)(p0.z>>16);
            hv[3]=(short)(p0.w); lv[3]=(short)(p0.w>>16);
            hv[4]=(short)(p1.x); lv[4]=(short)(p1.x>>16);
            hv[5]=(short)(p1.y); lv[5]=(short)(p1.y>>16);
            hv[6]=(short)(p1.z); lv[6]=(short)(p1.z>>16);
            hv[7]=(short)(p1.w); lv[7]=(short)(p1.w>>16);
            const int lane = (ar & 15) | ((kg & 3) << 4);
            const int ks = kg >> 2, mf = ar >> 4;
            *(bf8v*)&Ah[ks][mf][lane][0] = hv;
            *(bf8v*)&Al[ks][mf][lane][0] = lv;
        }
        {
            f4 r[8];
            #pragma unroll
            for (int j=0;j<8;j++)
                r[j] = *(const f4*)(Wf + (size_t)(k0 + b_kg*8 + j)*N + col0 + b_c4);
            #pragma unroll
            for (int c=0;c<4;c++){
                bf8v hv, lv;
                #pragma unroll
                for (int j=0;j<8;j++){
                    short hi, lo;
                    split2(((const float*)&r[j])[c], hi, lo);
                    hv[j] = hi; lv[j] = lo;
                }
                const int col = b_c4 + c;
                const int lane = (col & 15) | ((b_kg & 3) << 4);
                const int ks = b_kg >> 2, nf = col >> 4;
                *(bf8v*)&Bh[ks][nf][lane][0] = hv;
                *(bf8v*)&Bl[ks][nf][lane][0] = lv;
            }
        }
        __syncthreads();
        #pragma unroll
        for (int ks=0; ks<2; ks++){
            const bf8v ah0 = *(const bf8v*)&Ah[ks][mb+0][l][0];
            const bf8v ah1 = *(const bf8v*)&Ah[ks][mb+1][l][0];
            const bf8v al0 = *(const bf8v*)&Al[ks][mb+0][l][0];
            const bf8v al1 = *(const bf8v*)&Al[ks][mb+1][l][0];
            #pragma unroll
            for (int nf=0; nf<4; nf++){
                const bf8v bh = *(const bf8v*)&Bh[ks][nb+nf][l][0];
                const bf8v bl = *(const bf8v*)&Bl[ks][nb+nf][l][0];
                acc[0][nf] = __builtin_amdgcn_mfma_f32_16x16x32_bf16(ah0, bh, acc[0][nf], 0,0,0);
                acc[0][nf] = __builtin_amdgcn_mfma_f32_16x16x32_bf16(ah0, bl, acc[0][nf], 0,0,0);
                acc[0][nf] = __builtin_amdgcn_mfma_f32_16x16x32_bf16(al0, bh, acc[0][nf], 0,0,0);
                acc[1][nf] = __builtin_amdgcn_mfma_f32_16x16x32_bf16(ah1, bh, acc[1][nf], 0,0,0);
                acc[1][nf] = __builtin_amdgcn_mfma_f32_16x16x32_bf16(ah1, bl, acc[1][nf], 0,0,0);
                acc[1][nf] = __builtin_amdgcn_mfma_f32_16x16x32_bf16(al1, bh, acc[1][nf], 0,0,0);
            }
        }
    }

    const int ecol = l & 15, erow = (l >> 4) * 4;
    #pragma unroll
    for (int mf=0; mf<2; mf++){
        #pragma unroll
        for (int nf=0; nf<4; nf++){
            const int col = col0 + (w&1)*64 + nf*16 + ecol;
            const float bv = bias[col];
            #pragma unroll
            for (int j=0; j<4; j++){
                const int row = row0 + (w>>1)*32 + mf*16 + erow + j;
                float v = acc[mf][nf][j] + bv;
                if (act==1) v = fmaxf(v, 0.f);
                else if (act==2) v = gelu_f(v);
                if (hasres) v += res[(size_t)row*N + col];
                if (outpair) Cp[(size_t)row*N + col] = f32_to_pair(v);
                else         Cf[(size_t)row*N + col] = v;
            }
        }
    }
}

// bf16x2 MFMA GEMM, 512 threads: intra-block split-K x2 + depth-1 register
// prefetch — for 256-block grids (QKVO, mW2). W read as raw f32, split in staging.
__global__ __launch_bounds__(512) void gemm_mfma2(
    const unsigned* __restrict__ Apr, const float* __restrict__ Wf,
    const float* __restrict__ bias, const float* __restrict__ res,
    float* __restrict__ Cf, unsigned* __restrict__ Cp,
    int M, int N, int K, int act, int hasres, int outpair)
{
    __shared__ short Ah[2][2][4][64][8];   // [kh][ks][mf][lane][e]  16KB
    __shared__ short Al[2][2][4][64][8];   // 16KB
    __shared__ short Bh[2][2][8][64][8];   // 32KB
    __shared__ short Bl[2][2][8][64][8];   // 32KB
    const int tid = threadIdx.x;
    const int kh = tid >> 8;               // K-half
    const int t  = tid & 255;
    const int w = t >> 6, l = t & 63;
    const int row0 = blockIdx.y * 64, col0 = blockIdx.x * 128;
    const int mb = (w >> 1) * 2;
    const int nb = (w & 1) * 4;
    const int K2 = K >> 1;
    const int kbase = kh * K2;
    const int b_c4 = (t & 31) * 4;
    const int b_kg = t >> 5;
    const int a_r0 = t >> 3,       a_kg0 = t & 7;
    const int a_r1 = (t+256) >> 3, a_kg1 = (t+256) & 7;

    f4v acc[2][4];
    #pragma unroll
    for (int i=0;i<2;i++)
        #pragma unroll
        for (int j=0;j<4;j++) acc[i][j] = (f4v){0.f,0.f,0.f,0.f};

    uint4 pa0[2], pa1[2];
    f4 pb[8];

    // load tile 0 into regs
    {
        const unsigned* s0 = Apr + (size_t)(row0 + a_r0)*K + kbase + a_kg0*8;
        const unsigned* s1 = Apr + (size_t)(row0 + a_r1)*K + kbase + a_kg1*8;
        pa0[0] = *(const uint4*)s0; pa0[1] = *(const uint4*)(s0+4);
        pa1[0] = *(const uint4*)s1; pa1[1] = *(const uint4*)(s1+4);
        #pragma unroll
        for (int j=0;j<8;j++)
            pb[j] = *(const f4*)(Wf + (size_t)(kbase + b_kg*8 + j)*N + col0 + b_c4);
    }

    #define STAGE_A(pr, ar, kg) { \
        bf8v hv, lv; \
        hv[0]=(short)(pr[0].x); lv[0]=(short)(pr[0].x>>16); \
        hv[1]=(short)(pr[0].y); lv[1]=(short)(pr[0].y>>16); \
        hv[2]=(short)(pr[0].z); lv[2]=(short)(pr[0].z>>16); \
        hv[3]=(short)(pr[0].w); lv[3]=(short)(pr[0].w>>16); \
        hv[4]=(short)(pr[1].x); lv[4]=(short)(pr[1].x>>16); \
        hv[5]=(short)(pr[1].y); lv[5]=(short)(pr[1].y>>16); \
        hv[6]=(short)(pr[1].z); lv[6]=(short)(pr[1].z>>16); \
        hv[7]=(short)(pr[1].w); lv[7]=(short)(pr[1].w>>16); \
        const int lane_ = ((ar) & 15) | (((kg) & 3) << 4); \
        *(bf8v*)&Ah[kh][(kg)>>2][(ar)>>4][lane_][0] = hv; \
        *(bf8v*)&Al[kh][(kg)>>2][(ar)>>4][lane_][0] = lv; }

    #define STAGE_B() { \
        _Pragma("unroll") \
        for (int c=0;c<4;c++){ \
            bf8v hv, lv; \
            _Pragma("unroll") \
            for (int j=0;j<8;j++){ \
                short hi_, lo_; \
                split2(((const float*)&pb[j])[c], hi_, lo_); \
                hv[j] = hi_; lv[j] = lo_; \
            } \
            const int col_ = b_c4 + c; \
            const int lane_ = (col_ & 15) | ((b_kg & 3) << 4); \
            *(bf8v*)&Bh[kh][b_kg>>2][col_>>4][lane_][0] = hv; \
            *(bf8v*)&Bl[kh][b_kg>>2][col_>>4][lane_][0] = lv; } }

    // stage tile 0
    STAGE_A(pa0, a_r0, a_kg0)
    STAGE_A(pa1, a_r1, a_kg1)
    STAGE_B()
    __syncthreads();

    int k0 = 0;
    while (true){
        const int kn = k0 + 64;
        const bool more = kn < K2;
        if (more){
            const unsigned* s0 = Apr + (size_t)(row0 + a_r0)*K + kbase + kn + a_kg0*8;
            const unsigned* s1 = Apr + (size_t)(row0 + a_r1)*K + kbase + kn + a_kg1*8;
            pa0[0] = *(const uint4*)s0; pa0[1] = *(const uint4*)(s0+4);
            pa1[0] = *(const uint4*)s1; pa1[1] = *(const uint4*)(s1+4);
            #pragma unroll
            for (int j=0;j<8;j++)
                pb[j] = *(const f4*)(Wf + (size_t)(kbase + kn + b_kg*8 + j)*N + col0 + b_c4);
        }
        #pragma unroll
        for (int ks=0; ks<2; ks++){
            const bf8v ah0 = *(const bf8v*)&Ah[kh][ks][mb+0][l][0];
            const bf8v ah1 = *(const bf8v*)&Ah[kh][ks][mb+1][l][0];
            const bf8v al0 = *(const bf8v*)&Al[kh][ks][mb+0][l][0];
            const bf8v al1 = *(const bf8v*)&Al[kh][ks][mb+1][l][0];
            #pragma unroll
            for (int nf=0; nf<4; nf++){
                const bf8v bh = *(const bf8v*)&Bh[kh][ks][nb+nf][l][0];
                const bf8v bl = *(const bf8v*)&Bl[kh][ks][nb+nf][l][0];
                acc[0][nf] = __builtin_amdgcn_mfma_f32_16x16x32_bf16(ah0, bh, acc[0][nf], 0,0,0);
                acc[0][nf] = __builtin_amdgcn_mfma_f32_16x16x32_bf16(ah0, bl, acc[0][nf], 0,0,0);
                acc[0][nf] = __builtin_amdgcn_mfma_f32_16x16x32_bf16(al0, bh, acc[0][nf], 0,0,0);
                acc[1][nf] = __builtin_amdgcn_mfma_f32_16x16x32_bf16(ah1, bh, acc[1][nf], 0,0,0);
                acc[1][nf] = __builtin_amdgcn_mfma_f32_16x16x32_bf16(ah1, bl, acc[1][nf], 0,0,0);
                acc[1][nf] = __builtin_amdgcn_mfma_f32_16x16x32_bf16(al1, bh, acc[1][nf], 0,0,0);
            }
        }
        __syncthreads();        // both halves done reading this tile
        if (!more) break;
        STAGE_A(pa0, a_r0, a_kg0)
        STAGE_A(pa1, a_r1, a_kg1)
        STAGE_B()
        __syncthreads();        // next tile staged
        k0 = kn;
    }

    // deterministic half-combine via LDS (kh1 -> kh0)
    float* cs = (float*)&Ah[0][0][0][0][0];
    if (kh == 1){
        #pragma unroll
        for (int mf=0; mf<2; mf++)
            #pragma unroll
            for (int nf=0; nf<4; nf++){
                f4 p;
                p.x=acc[mf][nf][0]; p.y=acc[mf][nf][1];
                p.z=acc[mf][nf][2]; p.w=acc[mf][nf][3];
                *(f4*)(cs + 4*(((mf*4+nf))*256 + t)) = p;
            }
    }
    __syncthreads();
    if (kh == 0){
        #pragma unroll
        for (int mf=0; mf<2; mf++)
            #pragma unroll
            for (int nf=0; nf<4; nf++){
                const f4 p = *(const f4*)(cs + 4*(((mf*4+nf))*256 + t));
                acc[mf][nf][0]+=p.x; acc[mf][nf][1]+=p.y;
                acc[mf][nf][2]+=p.z; acc[mf][nf][3]+=p.w;
            }
        const int ecol = l & 15, erow = (l >> 4) * 4;
        #pragma unroll
        for (int mf=0; mf<2; mf++){
            #pragma unroll
            for (int nf=0; nf<4; nf++){
                const int col = col0 + (w&1)*64 + nf*16 + ecol;
                const float bv = bias[col];
                #pragma unroll
                for (int j=0; j<4; j++){
                    const int row = row0 + (w>>1)*32 + mf*16 + erow + j;
                    float v = acc[mf][nf][j] + bv;
                    if (act==1) v = fmaxf(v, 0.f);
                    else if (act==2) v = gelu_f(v);
                    if (hasres) v += res[(size_t)row*N + col];
                    if (outpair) Cp[(size_t)row*N + col] = f32_to_pair(v);
                    else         Cf[(size_t)row*N + col] = v;
                }
            }
        }
    }
    #undef STAGE_A
    #undef STAGE_B
}

// f32 GEMM kept for projectors + locate head
__global__ __launch_bounds__(512) void gemm128k2(
    const float* __restrict__ A, const float* __restrict__ W,
    const float* __restrict__ bias, const float* __restrict__ res,
    float* __restrict__ C, int M, int N, int K, int act, int hasres)
{
    __shared__ float As[2][32][68];
    __shared__ float Ws[2][32][132];
    const int tid = threadIdx.x;
    const int kh = tid >> 8;
    const int t  = tid & 255;
    const int row0 = blockIdx.y*64, col0 = blockIdx.x*128;
    const int ty = t>>4, tx = t&15;
    const int am = t>>2, ak = (t&3)*8;
    const int wk = t>>3, u  = t&7;
    const int K2 = K >> 1;
    const float* Ap = A + (size_t)(row0+am)*K + kh*K2 + ak;
    const float* Wp = W + (size_t)(kh*K2 + wk)*N + col0 + u*16;
    float* Wrow = &Ws[kh][wk][0];

    f4 a0,a1,w0,w1,w2,w3;
    a0 = *(const f4*)(Ap);
    a1 = *(const f4*)(Ap + 4);
    w0 = *(const f4*)(Wp);
    w1 = *(const f4*)(Wp + 4);
    w2 = *(const f4*)(Wp + 8);
    w3 = *(const f4*)(Wp + 12);
    As[kh][ak+0][am]=a0.x; As[kh][ak+1][am]=a0.y; As[kh][ak+2][am]=a0.z; As[kh][ak+3][am]=a0.w;
    As[kh][ak+4][am]=a1.x; As[kh][ak+5][am]=a1.y; As[kh][ak+6][am]=a1.z; As[kh][ak+7][am]=a1.w;
    *(f4*)(Wrow + 8*u)      = w0;
    *(f4*)(Wrow + 8*u + 4)  = w2;
    *(f4*)(Wrow + 64 + 8*u)     = w1;
    *(f4*)(Wrow + 64 + 8*u + 4) = w3;
    __syncthreads();

    float acc[4][8];
    #pragma unroll
    for (int i=0;i<4;i++){
        #pragma unroll
        for (int j=0;j<8;j++) acc[i][j]=0.f;
    }

    int k0 = 0;
    while (true){
        const int kn = k0 + 32;
        const bool more = kn < K2;
        if (more){
            a0 = *(const f4*)(Ap + kn);
            a1 = *(const f4*)(Ap + kn + 4);
            w0 = *(const f4*)(Wp + (size_t)kn*N);
            w1 = *(const f4*)(Wp + (size_t)kn*N + 4);
            w2 = *(const f4*)(Wp + (size_t)kn*N + 8);
            w3 = *(const f4*)(Wp + (size_t)kn*N + 12);
        }
        #pragma unroll
        for (int kk=0;kk<32;kk++){
            f4 a  = *(const f4*)&As[kh][kk][ty*4];
            f4 wA = *(const f4*)&Ws[kh][kk][tx*4];
            f4 wB = *(const f4*)&Ws[kh][kk][64 + tx*4];
            float ar[4] = {a.x,a.y,a.z,a.w};
            #pragma unroll
            for (int i=0;i<4;i++){
                acc[i][0] += ar[i]*wA.x;
                acc[i][1] += ar[i]*wA.y;
                acc[i][2] += ar[i]*wA.z;
                acc[i][3] += ar[i]*wA.w;
                acc[i][4] += ar[i]*wB.x;
                acc[i][5] += ar[i]*wB.y;
                acc[i][6] += ar[i]*wB.z;
                acc[i][7] += ar[i]*wB.w;
            }
        }
        __syncthreads();
        if (!more) break;
        As[kh][ak+0][am]=a0.x; As[kh][ak+1][am]=a0.y; As[kh][ak+2][am]=a0.z; As[kh][ak+3][am]=a0.w;
        As[kh][ak+4][am]=a1.x; As[kh][ak+5][am]=a1.y; As[kh][ak+6][am]=a1.z; As[kh][ak+7][am]=a1.w;
        *(f4*)(Wrow + 8*u)      = w0;
        *(f4*)(Wrow + 8*u + 4)  = w2;
        *(f4*)(Wrow + 64 + 8*u)     = w1;
        *(f4*)(Wrow + 64 + 8*u + 4) = w3;
        __syncthreads();
        k0 = kn;
    }

    float* cs = &Ws[0][0][0];
    if (kh == 1){
        #pragma unroll
        for (int i=0;i<4;i++){
            #pragma unroll
            for (int b=0;b<2;b++){
                f4 p;
                p.x=acc[i][b*4+0]; p.y=acc[i][b*4+1]; p.z=acc[i][b*4+2]; p.w=acc[i][b*4+3];
                *(f4*)(cs + 4*(((i<<1)|b)*256 + t)) = p;
            }
        }
    }
    __syncthreads();
    if (kh == 0){
        #pragma unroll
        for (int i=0;i<4;i++){
            #pragma unroll
            for (int b=0;b<2;b++){
                const f4 p = *(const f4*)(cs + 4*(((i<<1)|b)*256 + t));
                acc[i][b*4+0]+=p.x; acc[i][b*4+1]+=p.y; acc[i][b*4+2]+=p.z; acc[i][b*4+3]+=p.w;
            }
        }
        #pragma unroll
        for (int i=0;i<4;i++){
            const int r = row0 + ty*4 + i;
            #pragma unroll
            for (int half=0; half<2; ++half){
                const int cb = col0 + tx*8 + half*4;
                f4 bv = *(const f4*)(bias + cb);
                float t0 = acc[i][half*4+0] + bv.x;
                float t1 = acc[i][half*4+1] + bv.y;
                float t2 = acc[i][half*4+2] + bv.z;
                float t3 = acc[i][half*4+3] + bv.w;
                if (act==1){ t0=fmaxf(t0,0.f); t1=fmaxf(t1,0.f); t2=fmaxf(t2,0.f); t3=fmaxf(t3,0.f); }
                else if (act==2){ t0=gelu_f(t0); t1=gelu_f(t1); t2=gelu_f(t2); t3=gelu_f(t3); }
                if (hasres){
                    f4 rv = *(const f4*)(res + (size_t)r*N + cb);
                    t0+=rv.x; t1+=rv.y; t2+=rv.z; t3+=rv.w;
                }
                f4 o; o.x=t0; o.y=t1; o.z=t2; o.w=t3;
                *(f4*)(C + (size_t)r*N + cb) = o;
            }
        }
    }
}

__global__ __launch_bounds__(256) void lnrow(
    const float* __restrict__ X, const float* __restrict__ g,
    const float* __restrict__ b, float* __restrict__ out, float eps)
{
    __shared__ float red[4];
    const int row = blockIdx.x, tid = threadIdx.x;
    const float* xp = X + (size_t)row*D_MOD;
    f4 xv = *(const f4*)(xp + tid*4);
    float s = xv.x+xv.y+xv.z+xv.w;
    #pragma unroll
    for (int m=1;m<64;m<<=1) s += __shfl_xor(s, m);
    const int wid = tid>>6, lane = tid&63;
    if (lane==0) red[wid]=s;
    __syncthreads();
    float mean = (red[0]+red[1]+red[2]+red[3]) * (1.0f/1024.0f);
    __syncthreads();
    float d0=xv.x-mean, d1=xv.y-mean, d2=xv.z-mean, d3=xv.w-mean;
    float q = d0*d0+d1*d1+d2*d2+d3*d3;
    #pragma unroll
    for (int m=1;m<64;m<<=1) q += __shfl_xor(q, m);
    if (lane==0) red[wid]=q;
    __syncthreads();
    float var = (red[0]+red[1]+red[2]+red[3]) * (1.0f/1024.0f);
    float inv = rsqrtf(var + eps);
    f4 gv = *(const f4*)(g + tid*4);
    f4 bv = *(const f4*)(b + tid*4);
    f4 o;
    o.x = d0*inv*gv.x + bv.x;
    o.y = d1*inv*gv.y + bv.y;
    o.z = d2*inv*gv.z + bv.z;
    o.w = d3*inv*gv.w + bv.w;
    *(f4*)(out + (size_t)row*D_MOD + tid*4) = o;
}

__global__ __launch_bounds__(256) void lnrow_pair(
    const float* __restrict__ X, const float* __restrict__ g,
    const float* __restrict__ b, unsigned* __restrict__ outp, float eps)
{
    __shared__ float red[4];
    const int row = blockIdx.x, tid = threadIdx.x;
    const float* xp = X + (size_t)row*D_MOD;
    f4 xv = *(const f4*)(xp + tid*4);
    float s = xv.x+xv.y+xv.z+xv.w;
    #pragma unroll
    for (int m=1;m<64;m<<=1) s += __shfl_xor(s, m);
    const int wid = tid>>6, lane = tid&63;
    if (lane==0) red[wid]=s;
    __syncthreads();
    float mean = (red[0]+red[1]+red[2]+red[3]) * (1.0f/1024.0f);
    __syncthreads();
    float d0=xv.x-mean, d1=xv.y-mean, d2=xv.z-mean, d3=xv.w-mean;
    float q = d0*d0+d1*d1+d2*d2+d3*d3;
    #pragma unroll
    for (int m=1;m<64;m<<=1) q += __shfl_xor(q, m);
    if (lane==0) red[wid]=q;
    __syncthreads();
    float var = (red[0]+red[1]+red[2]+red[3]) * (1.0f/1024.0f);
    float inv = rsqrtf(var + eps);
    f4 gv = *(const f4*)(g + tid*4);
    f4 bv = *(const f4*)(b + tid*4);
    uint4 o;
    o.x = f32_to_pair(d0*inv*gv.x + bv.x);
    o.y = f32_to_pair(d1*inv*gv.y + bv.y);
    o.z = f32_to_pair(d2*inv*gv.z + bv.z);
    o.w = f32_to_pair(d3*inv*gv.w + bv.w);
    ((uint4*)(outp + (size_t)row*D_MOD))[tid] = o;
}

// MFMA flash attention, bf16x2 (R12, validated)
__global__ __launch_bounds__(256,1) void attn_mfma(
    const float* __restrict__ Q, const float* __restrict__ Kb,
    const float* __restrict__ Vb,
    float* __restrict__ OA0, float* __restrict__ OA1,
    float* __restrict__ ML0, float* __restrict__ ML1)
{
    __shared__ short QhS[4][8][64][8];
    __shared__ short QlS[4][8][64][8];
    __shared__ short KhS[4][4][64][8];
    __shared__ short KlS[4][4][64][8];
    __shared__ short VhS[2][8][64][8];
    __shared__ short VlS[2][8][64][8];
    short* Ph = &KhS[0][0][0][0];
    short* Pl = &KlS[0][0][0][0];

    const int tid = threadIdx.x;
    const int w = tid >> 6, l = tid & 63;
    const int h  = blockIdx.x & 7;
    const int sh = (blockIdx.x >> 3) & 1;
    const int q0 = (blockIdx.x >> 4) * 128;
    const int sbase = sh * 1024;
    const float qscale = 0.08838834764831845f;

    #pragma unroll
    for (int i=0;i<2;i++){
        const int u = tid + i*256;
        const int qr = u >> 2, dks = u & 3;
        const float* src = Q + (size_t)(q0+qr)*D_MOD + h*128 + dks*32;
        float a[32];
        #pragma unroll
        for (int j=0;j<8;j++) *(f4*)&a[j*4] = ((const f4*)src)[j];
        const int qmf = qr >> 4;
        #pragma unroll
        for (int kg=0;kg<4;kg++){
            bf8v hv, lv;
            #pragma unroll
            for (int e=0;e<8;e++){
                short hi, lo;
                split2(a[kg*8+e]*qscale, hi, lo);
                hv[e]=hi; lv[e]=lo;
            }
            const int lane = (qr & 15) | (kg << 4);
            *(bf8v*)&QhS[dks][qmf][lane][0] = hv;
            *(bf8v*)&QlS[dks][qmf][lane][0] = lv;
        }
    }
    {
        const int sr = tid >> 2, dks = tid & 3;
        const float* src = Kb + (size_t)(sbase+sr)*D_MOD + h*128 + dks*32;
        float a[32];
        #pragma unroll
        for (int j=0;j<8;j++) *(f4*)&a[j*4] = ((const f4*)src)[j];
        const int smf = sr >> 4;
        #pragma unroll
        for (int kg=0;kg<4;kg++){
            bf8v hv, lv;
            #pragma unroll
            for (int e=0;e<8;e++){ short hi,lo; split2(a[kg*8+e],hi,lo); hv[e]=hi; lv[e]=lo; }
            const int lane = (sr & 15) | (kg << 4);
            *(bf8v*)&KhS[dks][smf][lane][0] = hv;
            *(bf8v*)&KlS[dks][smf][lane][0] = lv;
        }
        const int s8 = tid >> 5, d4 = (tid & 31) * 4;
        float b[8][4];
        #pragma unroll
        for (int r=0;r<8;r++)
            *(f4*)&b[r][0] = *(const f4*)(Vb + (size_t)(sbase+s8*8+r)*D_MOD + h*128 + d4);
        const int sks = s8 >> 2, sg = s8 & 3;
        #pragma unroll
        for (int c=0;c<4;c++){
            bf8v hv, lv;
            #pragma unroll
            for (int r=0;r<8;r++){ short hi,lo; split2(b[r][c],hi,lo); hv[r]=hi; lv[r]=lo; }
            const int d = d4 + c;
            const int lane = (d & 15) | (sg << 4);
            *(bf8v*)&VhS[sks][d>>4][lane][0] = hv;
            *(bf8v*)&VlS[sks][d>>4][lane][0] = lv;
        }
    }
    __syncthreads();

    float mstat[8], lstat[8];
    f4v oacc[2][8];
    #pragma unroll
    for (int i=0;i<8;i++){ mstat[i] = -__builtin_inff(); lstat[i] = 0.f; }
    #pragma unroll
    for (int i=0;i<2;i++)
        #pragma unroll
        for (int j=0;j<8;j++) oacc[i][j] = (f4v){0.f,0.f,0.f,0.f};

    for (int t=0; t<16; ++t){
        f4v sacc[2][4];
        #pragma unroll
        for (int i=0;i<2;i++)
            #pragma unroll
            for (int j=0;j<4;j++) sacc[i][j] = (f4v){0.f,0.f,0.f,0.f};
        #pragma unroll
        for (int dks=0; dks<4; dks++){
            const bf8v qh0 = *(const bf8v*)&QhS[dks][2*w+0][l][0];
            const bf8v qh1 = *(const bf8v*)&QhS[dks][2*w+1][l][0];
            const bf8v ql0 = *(const bf8v*)&QlS[dks][2*w+0][l][0];
            const bf8v ql1 = *(const bf8v*)&QlS[dks][2*w+1][l][0];
            #pragma unroll
            for (int sf=0; sf<4; sf++){
                const bf8v kh = *(const bf8v*)&KhS[dks][sf][l][0];
                const bf8v kl = *(const bf8v*)&KlS[dks][sf][l][0];
                sacc[0][sf] = __builtin_amdgcn_mfma_f32_16x16x32_bf16(qh0, kh, sacc[0][sf], 0,0,0);
                sacc[0][sf] = __builtin_amdgcn_mfma_f32_16x16x32_bf16(qh0, kl, sacc[0][sf], 0,0,0);
                sacc[0][sf] = __builtin_amdgcn_mfma_f32_16x16x32_bf16(ql0, kh, sacc[0][sf], 0,0,0);
                sacc[1][sf] = __builtin_amdgcn_mfma_f32_16x16x32_bf16(qh1, kh, sacc[1][sf], 0,0,0);
                sacc[1][sf] = __builtin_amdgcn_mfma_f32_16x16x32_bf16(qh1, kl, sacc[1][sf], 0,0,0);
                sacc[1][sf] = __builtin_amdgcn_mfma_f32_16x16x32_bf16(ql1, kh, sacc[1][sf], 0,0,0);
            }
        }
        __syncthreads();

        float scr[8];
        #pragma unroll
        for (int mfi=0; mfi<2; mfi++){
            #pragma unroll
            for (int j=0; j<4; j++){
                const int si = mfi*4 + j;
                float tm = fmaxf(fmaxf(sacc[mfi][0][j], sacc[mfi][1][j]),
                                 fmaxf(sacc[mfi][2][j], sacc[mfi][3][j]));
                tm = fmaxf(tm, __shfl_xor(tm,1));
                tm = fmaxf(tm, __shfl_xor(tm,2));
                tm = fmaxf(tm, __shfl_xor(tm,4));
                tm = fmaxf(tm, __shfl_xor(tm,8));
                const float mn = fmaxf(mstat[si], tm);
                const float sc = __expf(mstat[si] - mn);
                float rs = 0.f;
                #pragma unroll
                for (int sf=0; sf<4; sf++){
                    const float p = __expf(sacc[mfi][sf][j] - mn);
                    sacc[mfi][sf][j] = p; rs += p;
                }
                rs += __shfl_xor(rs,1); rs += __shfl_xor(rs,2);
                rs += __shfl_xor(rs,4); rs += __shfl_xor(rs,8);
                lstat[si] = lstat[si]*sc + rs;
                mstat[si] = mn;
                scr[si] = sc;
            }
        }
        {
            const int pe = l & 7;
            const int rb4 = (l >> 4) * 4;
            const int sgb = (l & 15) >> 3;
            #pragma unroll
            for (int mfi=0; mfi<2; mfi++){
                const int qmf = 2*w + mfi;
                #pragma unroll
                for (int sf=0; sf<4; sf++){
                    const int sks = sf >> 1;
                    const int sg = (sf & 1)*2 + sgb;
                    #pragma unroll
                    for (int j=0; j<4; j++){
                        const int lane = (rb4 + j) | (sg << 4);
                        short hi, lo;
                        split2(sacc[mfi][sf][j], hi, lo);
                        const int off = ((sks*8 + qmf)*64 + lane)*8 + pe;
                        Ph[off] = hi;
                        Pl[off] = lo;
                    }
                }
            }
        }
        __syncthreads();

        #pragma unroll
        for (int mfi=0; mfi<2; mfi++){
            #pragma unroll
            for (int j=0; j<4; j++){
                const float sc = scr[mfi*4+j];
                #pragma unroll
                for (int dmf=0; dmf<8; dmf++) oacc[mfi][dmf][j] *= sc;
            }
        }
        #pragma unroll
        for (int sks=0; sks<2; sks++){
            const bf8v ph0 = *(const bf8v*)&Ph[((sks*8 + 2*w+0)*64 + l)*8];
            const bf8v ph1 = *(const bf8v*)&Ph[((sks*8 + 2*w+1)*64 + l)*8];
            const bf8v pl0 = *(const bf8v*)&Pl[((sks*8 + 2*w+0)*64 + l)*8];
            const bf8v pl1 = *(const bf8v*)&Pl[((sks*8 + 2*w+1)*64 + l)*8];
            #pragma unroll
            for (int dmf=0; dmf<8; dmf++){
                const bf8v vh = *(const bf8v*)&VhS[sks][dmf][l][0];
                const bf8v vl = *(const bf8v*)&VlS[sks][dmf][l][0];
                oacc[0][dmf] = __builtin_amdgcn_mfma_f32_16x16x32_bf16(ph0, vh, oacc[0][dmf], 0,0,0);
                oacc[0][dmf] = __builtin_amdgcn_mfma_f32_16x16x32_bf16(ph0, vl, oacc[0][dmf], 0,0,0);
                oacc[0][dmf] = __builtin_amdgcn_mfma_f32_16x16x32_bf16(pl0, vh, oacc[0][dmf], 0,0,0);
                oacc[1][dmf] = __builtin_amdgcn_mfma_f32_16x16x32_bf16(ph1, vh, oacc[1][dmf], 0,0,0);
                oacc[1][dmf] = __builtin_amdgcn_mfma_f32_16x16x32_bf16(ph1, vl, oacc[1][dmf], 0,0,0);
                oacc[1][dmf] = __builtin_amdgcn_mfma_f32_16x16x32_bf16(pl1, vh, oacc[1][dmf], 0,0,0);
            }
        }
        __syncthreads();

        if (t < 15){
            const int sb = sbase + (t+1)*64;
            const int sr = tid >> 2, dks = tid & 3;
            const float* src = Kb + (size_t)(sb+sr)*D_MOD + h*128 + dks*32;
            float a[32];
            #pragma unroll
            for (int j=0;j<8;j++) *(f4*)&a[j*4] = ((const f4*)src)[j];
            const int smf = sr >> 4;
            #pragma unroll
            for (int kg=0;kg<4;kg++){
                bf8v hv, lv;
                #pragma unroll
                for (int e=0;e<8;e++){ short hi,lo; split2(a[kg*8+e],hi,lo); hv[e]=hi; lv[e]=lo; }
                const int lane = (sr & 15) | (kg << 4);
                *(bf8v*)&KhS[dks][smf][lane][0] = hv;
                *(bf8v*)&KlS[dks][smf][lane][0] = lv;
            }
            const int s8 = tid >> 5, d4 = (tid & 31) * 4;
            float b[8][4];
            #pragma unroll
            for (int r=0;r<8;r++)
                *(f4*)&b[r][0] = *(const f4*)(Vb + (size_t)(sb+s8*8+r)*D_MOD + h*128 + d4);
            const int sks = s8 >> 2, sg = s8 & 3;
            #pragma unroll
            for (int c=0;c<4;c++){
                bf8v hv, lv;
                #pragma unroll
                for (int r=0;r<8;r++){ short hi,lo; split2(b[r][c],hi,lo); hv[r]=hi; lv[r]=lo; }
                const int d = d4 + c;
                const int lane = (d & 15) | (sg << 4);
                *(bf8v*)&VhS[sks][d>>4][lane][0] = hv;
                *(bf8v*)&VlS[sks][d>>4][lane][0] = lv;
            }
        }
        __syncthreads();
    }

    float* OAp = sh ? OA1 : OA0;
    float* MLp = sh ? ML1 : ML0;
    const int erow = (l >> 4) * 4, ecol = l & 15;
    #pragma unroll
    for (int mfi=0; mfi<2; mfi++){
        #pragma unroll
        for (int dmf=0; dmf<8; dmf++){
            const int col = h*128 + dmf*16 + ecol;
            #pragma unroll
            for (int j=0; j<4; j++){
                const int row = q0 + w*32 + mfi*16 + erow + j;
                OAp[(size_t)row*D_MOD + col] = oacc[mfi][dmf][j];
            }
        }
    }
    if (ecol == 0){
        #pragma unroll
        for (int mfi=0; mfi<2; mfi++){
            #pragma unroll
            for (int j=0; j<4; j++){
                const int row = q0 + w*32 + mfi*16 + erow + j;
                MLp[(size_t)row*16 + h*2 + 0] = mstat[mfi*4+j];
                MLp[(size_t)row*16 + h*2 + 1] = lstat[mfi*4+j];
            }
        }
    }
}

// flash-combine of the two s-halves + bias-KV token; writes bf16-pair output
__global__ __launch_bounds__(256) void attn_combine(
    const float* __restrict__ Q, const float* __restrict__ kbias,
    const float* __restrict__ vbias,
    const float* __restrict__ OA0, const float* __restrict__ OA1,
    const float* __restrict__ ML0, const float* __restrict__ ML1,
    unsigned* __restrict__ OP)
{
    const int row = blockIdx.x, t = threadIdx.x;
    const int h = t >> 5;
    const int cc = t & 31;
    const float qscale = 0.08838834764831845f;
    const f4 qv = *(const f4*)(Q + (size_t)row*D_MOD + h*128 + cc*4);
    const f4 kb = *(const f4*)(kbias + h*128 + cc*4);
    float part = qv.x*kb.x + qv.y*kb.y + qv.z*kb.z + qv.w*kb.w;
    part += __shfl_xor(part,1); part += __shfl_xor(part,2);
    part += __shfl_xor(part,4); part += __shfl_xor(part,8);
    part += __shfl_xor(part,16);
    const float sb = part * qscale;
    const float m0 = ML0[(size_t)row*16 + h*2], l0 = ML0[(size_t)row*16 + h*2 + 1];
    const float m1 = ML1[(size_t)row*16 + h*2], l1 = ML1[(size_t)row*16 + h*2 + 1];
    const float M  = fmaxf(fmaxf(m0, m1), sb);
    const float w0 = __expf(m0 - M), w1 = __expf(m1 - M), wb = __expf(sb - M);
    const float inv = 1.0f / (w0*l0 + w1*l1 + wb);
    const f4 o0 = *(const f4*)(OA0 + (size_t)row*D_MOD + t*4);
    const f4 o1 = *(const f4*)(OA1 + (size_t)row*D_MOD + t*4);
    const f4 vb = *(const f4*)(vbias + h*128 + cc*4);
    uint4 o;
    o.x = f32_to_pair((o0.x*w0 + o1.x*w1 + vb.x*wb) * inv);
    o.y = f32_to_pair((o0.y*w0 + o1.y*w1 + vb.y*wb) * inv);
    o.z = f32_to_pair((o0.z*w0 + o1.z*w1 + vb.z*wb) * inv);
    o.w = f32_to_pair((o0.w*w0 + o1.w*w1 + vb.w*wb) * inv);
    *(uint4*)(OP + (size_t)row*D_MOD + t*4) = o;
}

__global__ __launch_bounds__(64) void locate_head(
    const float* __restrict__ mid, const float* __restrict__ W2,
    const float* __restrict__ b2, float* __restrict__ loc_ws,
    float* __restrict__ loc_out)
{
    const int row = blockIdx.x, lane = threadIdx.x;
    const float* m = mid + (size_t)row*512;
    f4 v0 = *(const f4*)(m + lane*8);
    f4 v1 = *(const f4*)(m + lane*8 + 4);
    f4 w0 = *(const f4*)(W2 + lane*8);
    f4 w1 = *(const f4*)(W2 + lane*8 + 4);
    float s = v0.x*w0.x + v0.y*w0.y + v0.z*w0.z + v0.w*w0.w
            + v1.x*w1.x + v1.y*w1.y + v1.z*w1.z + v1.w*w1.w;
    #pragma unroll
    for (int mm=1; mm<64; mm<<=1) s += __shfl_xor(s, mm);
    if (lane==0){
        float z = s + b2[0];
        float l = 1.0f/(1.0f + expf(-z));
        loc_ws[row] = l;
        loc_out[row] = l;
    }
}

__global__ __launch_bounds__(1024) void segscan(
    const float* __restrict__ located, const float* __restrict__ thrp,
    float* __restrict__ out_segid, float* __restrict__ out_segtype,
    float* __restrict__ out_numseg, int* __restrict__ wsi)
{
    __shared__ int clips[2048];
    __shared__ int segid[2048];
    __shared__ int sstart[2049];
    __shared__ int wsum[16];
    const int tid = threadIdx.x;
    const float thr = *thrp;
    for (int t=tid; t<2048; t+=1024) clips[t] = (located[t] > thr) ? 1 : 0;
    __syncthreads();
    const int t0 = tid*2, t1 = t0+1;
    int f0 = (t0==0) ? 0 : (clips[t0]!=clips[t0-1] ? 1 : 0);
    int f1 = (clips[t1]!=clips[t1-1] ? 1 : 0);
    int e0 = f0, e1 = f0+f1;
    const int lane = tid&63, wid = tid>>6;
    int v = e1;
    #pragma unroll
    for (int off=1; off<64; off<<=1){
        int u = __shfl_up(v, off, 64);
        if (lane>=off) v += u;
    }
    if (lane==63) wsum[wid] = v;
    __syncthreads();
    if (tid < 16){
        int w = wsum[tid];
        #pragma unroll
        for (int off=1; off<16; off<<=1){
            int u = __shfl_up(w, off, 16);
            if (tid>=off) w += u;
        }
        wsum[tid] = w;
    }
    __syncthreads();
    int base = (wid>0 ? wsum[wid-1] : 0) + (v - e1);
    segid[t0] = base + e0;
    segid[t1] = base + e1;
    __syncthreads();
    const int ns = segid[2047] + 1;
    for (int t=tid; t<2048; t+=1024){
        if (t==0 || segid[t]!=segid[t-1]) sstart[segid[t]] = t;
    }
    if (tid==0) sstart[ns] = 2048;
    __syncthreads();
    for (int t=tid; t<2048; t+=1024) out_segid[t] = (float)segid[t];
    for (int s=tid; s<2048; s+=1024)
        out_segtype[s] = (s<ns) ? (float)clips[sstart[s]] : -2147483648.0f;
    if (tid==0){ out_numseg[0] = (float)ns; wsi[0] = ns; }
    for (int s=tid; s<=2048; s+=1024) wsi[2+s] = (s<=ns) ? sstart[s] : 0;
}

__global__ __launch_bounds__(256) void segpool(
    const float* __restrict__ V, const float* __restrict__ A,
    const int* __restrict__ wsi, float* __restrict__ out_vid,
    float* __restrict__ out_aud)
{
    const int s = blockIdx.x;
    const int c = threadIdx.x*4;
    const int ns = wsi[0];
    f4 vv; vv.x=0.f; vv.y=0.f; vv.z=0.f; vv.w=0.f;
    f4 av = vv;
    if (s < ns){
        const int st = wsi[2+s], en = wsi[2+s+1];
        for (int r=st; r<en; ++r){
            f4 x = *(const f4*)(V + (size_t)r*D_MOD + c);
            vv.x+=x.x; vv.y+=x.y; vv.z+=x.z; vv.w+=x.w;
            f4 y = *(const f4*)(A + (size_t)r*D_MOD + c);
            av.x+=y.x; av.y+=y.y; av.z+=y.z; av.w+=y.w;
        }
        const float inv = 1.0f/(float)(en-st);
        vv.x*=inv; vv.y*=inv; vv.z*=inv; vv.w*=inv;
        av.x*=inv; av.y*=inv; av.z*=inv; av.w*=inv;
    }
    *(f4*)(out_vid + (size_t)s*D_MOD + c) = vv;
    *(f4*)(out_aud + (size_t)s*D_MOD + c) = av;
}

extern "C" void kernel_launch(void* const* d_in, const int* in_sizes, int n_in,
                              void* d_out, int out_size, void* d_ws, size_t ws_size,
                              hipStream_t stream) {
    (void)in_sizes; (void)n_in; (void)out_size; (void)ws_size;
    const float* video = (const float*)d_in[0];
    const float* audio = (const float*)d_in[1];
    const float* apW1  = (const float*)d_in[2];
    const float* apb1  = (const float*)d_in[3];
    const float* apW2  = (const float*)d_in[4];
    const float* apb2  = (const float*)d_in[5];
    const float* vpW1  = (const float*)d_in[6];
    const float* vpb1  = (const float*)d_in[7];
    const float* vpW2  = (const float*)d_in[8];
    const float* vpb2  = (const float*)d_in[9];
    const float* preg  = (const float*)d_in[10];
    const float* preb  = (const float*)d_in[11];
    const float* bWq   = (const float*)d_in[12];
    const float* bbq   = (const float*)d_in[13];
    const float* bWk   = (const float*)d_in[14];
    const float* bbk   = (const float*)d_in[15];
    const float* bWv   = (const float*)d_in[16];
    const float* bbv   = (const float*)d_in[17];
    const float* bWo   = (const float*)d_in[18];
    const float* bbo   = (const float*)d_in[19];
    const float* bbiask= (const float*)d_in[20];
    const float* bbiasv= (const float*)d_in[21];
    const float* bg1   = (const float*)d_in[22];
    const float* bb1   = (const float*)d_in[23];
    const float* bg2   = (const float*)d_in[24];
    const float* bb2   = (const float*)d_in[25];
    const float* bmW1  = (const float*)d_in[26];
    const float* bmb1  = (const float*)d_in[27];
    const float* bmW2  = (const float*)d_in[28];
    const float* bmb2  = (const float*)d_in[29];
    const float* lhW1  = (const float*)d_in[30];
    const float* lhb1  = (const float*)d_in[31];
    const float* lhW2  = (const float*)d_in[32];
    const float* lhb2  = (const float*)d_in[33];
    const float* thrp  = (const float*)d_in[34];

    float* ws = (float*)d_ws;
    float* V    = ws + 0;
    float* Abuf = ws + 2097152;
    float* X    = ws + 4194304;
    float* H    = ws + 6291456;
    float* Q    = ws + 8388608;
    float* Kb   = ws + 10485760;
    float* Vb   = ws + 12582912;
    float* Obuf = ws + 14680064;
    unsigned* M4p = (unsigned*)(ws + 8388608);
    float* M512 = ws + 16777216;
    float* LOC  = ws + 17825792;
    int*   WSI  = (int*)(ws + 17827840);
    float* ML0  = ws + 17829952;
    float* ML1  = ws + 17862720;
    unsigned* Vp  = (unsigned*)(ws + 17895488);
    unsigned* OPp = (unsigned*)(ws + 19992640);
    unsigned* Hp  = (unsigned*)H;

    float* out = (float*)d_out;
    float* out_vid     = out + 0;
    float* out_aud     = out + 2097152;
    float* out_loc     = out + 4194304;
    float* out_segid   = out + 4196352;
    float* out_segtype = out + 4198400;
    float* out_numseg  = out + 4200448;

    const dim3 B512(512);
    const dim3 B256(256);
    #define GRID128(M,N) dim3((N)/128,(M)/64)
    #define GRIDM(M,N)   dim3((N)/128,(M)/64)

    // projectors (f32 path, exact for pools)
    gemm128k2<<<GRID128(2048,512), B512, 0, stream>>>(audio, apW1, apb1, nullptr, M512, 2048,512,128, 1,0);
    gemm128k2<<<GRID128(2048,1024),B512, 0, stream>>>(M512, apW2, apb2, nullptr, Abuf, 2048,1024,512, 0,0);
    gemm128k2<<<GRID128(2048,512), B512, 0, stream>>>(video, vpW1, vpb1, nullptr, M512, 2048,512,1024, 1,0);
    gemm128k2<<<GRID128(2048,1024),B512, 0, stream>>>(M512, vpW2, vpb2, nullptr, V,    2048,1024,512, 0,0);
    lnrow<<<2048, B256, 0, stream>>>(Abuf, preg, preb, X, 1e-6f);
    convert1<<<2048, B256, 0, stream>>>(V, Vp, 524288);

    for (int l=0; l<8; ++l){
        const size_t wo = (size_t)l*1024*1024;
        const size_t bo = (size_t)l*1024;
        const size_t mo1 = (size_t)l*1024*4096;
        lnrow_pair<<<2048, B256, 0, stream>>>(X, bg1+bo, bb1+bo, Hp, 1e-5f);
        gemm_mfma2<<<GRIDM(2048,1024), B512, 0, stream>>>(Hp, bWq+wo, bbq+bo, nullptr, Q,  nullptr, 2048,1024,1024, 0,0,0);
        gemm_mfma2<<<GRIDM(2048,1024), B512, 0, stream>>>(Vp, bWk+wo, bbk+bo, nullptr, Kb, nullptr, 2048,1024,1024, 0,0,0);
        gemm_mfma2<<<GRIDM(2048,1024), B512, 0, stream>>>(Vp, bWv+wo, bbv+bo, nullptr, Vb, nullptr, 2048,1024,1024, 0,0,0);
        attn_mfma<<<256, B256, 0, stream>>>(Q, Kb, Vb, Obuf, H, ML0, ML1);
        attn_combine<<<2048, B256, 0, stream>>>(Q, bbiask+bo, bbiasv+bo, Obuf, H, ML0, ML1, OPp);
        gemm_mfma2<<<GRIDM(2048,1024), B512, 0, stream>>>(OPp, bWo+wo, bbo+bo, X, X, nullptr, 2048,1024,1024, 0,1,0);
        lnrow_pair<<<2048, B256, 0, stream>>>(X, bg2+bo, bb2+bo, Hp, 1e-5f);
        gemm_mfma<<<GRIDM(2048,4096), B256, 0, stream>>>(Hp, bmW1+mo1, bmb1+(size_t)l*4096, nullptr, nullptr, M4p, 2048,4096,1024, 2,0,1);
        gemm_mfma2<<<GRIDM(2048,1024), B512, 0, stream>>>(M4p, bmW2+mo1, bmb2+bo, X, X, nullptr, 2048,1024,4096, 0,1,0);
    }

    gemm128k2<<<GRID128(2048,512), B512, 0, stream>>>(X, lhW1, lhb1, nullptr, M512, 2048,512,1024, 1,0);
    locate_head<<<2048, dim3(64), 0, stream>>>(M512, lhW2, lhb2, LOC, out_loc);
    segscan<<<1, dim3(1024), 0, stream>>>(LOC, thrp, out_segid, out_segtype, out_numseg, WSI);
    segpool<<<2048, B256, 0, stream>>>(V, Abuf, WSI, out_vid, out_aud);
}

// Round 18
// 4101.133 us; speedup vs baseline: 1.1264x; 1.0535x over previous
//
#include <hip/hip_runtime.h>
#include <math.h>

typedef float4 f4;
typedef __attribute__((ext_vector_type(8))) short bf8v;
typedef __attribute__((ext_vector_type(4))) float f4v;

#define T_SEQ 2048
#define D_MOD 1024

__device__ __forceinline__ float gelu_f(float x){
    float u = 0.7978845608028654f*(x + 0.044715f*x*x*x);
    return 0.5f*x*(1.0f + tanhf(u));
}

// pack f32 -> (hi bf16 rounded, lo bf16) ; x ~= hi + lo
__device__ __forceinline__ unsigned f32_to_pair(float x){
    unsigned u = __float_as_uint(x);
    unsigned hi = (u + 0x7FFFu + ((u >> 16) & 1u)) >> 16;
    float hif = __uint_as_float(hi << 16);
    float lof = x - hif;
    unsigned v = __float_as_uint(lof);
    unsigned lo = (v + 0x7FFFu + ((v >> 16) & 1u)) >> 16;
    return hi | (lo << 16);
}

// truncating split: hi = trunc-bf16(x), lo = trunc-bf16(x-hi)
__device__ __forceinline__ void split2(float x, short& hi, short& lo){
    unsigned u = __float_as_uint(x);
    hi = (short)(u >> 16);
    float rem = x - __uint_as_float(u & 0xFFFF0000u);
    lo = (short)(__float_as_uint(rem) >> 16);
}

__global__ __launch_bounds__(256) void convert1(
    const float* __restrict__ s, unsigned* __restrict__ d, int n4)
{
    const int i = blockIdx.x*256 + threadIdx.x;
    if (i < n4){
        f4 v = ((const f4*)s)[i];
        uint4 o;
        o.x = f32_to_pair(v.x); o.y = f32_to_pair(v.y);
        o.z = f32_to_pair(v.z); o.w = f32_to_pair(v.w);
        ((uint4*)d)[i] = o;
    }
}

__global__ __launch_bounds__(256) void convert6(
    const float* __restrict__ s0, const float* __restrict__ s1,
    const float* __restrict__ s2, const float* __restrict__ s3,
    const float* __restrict__ s4, const float* __restrict__ s5,
    unsigned* __restrict__ d0, unsigned* __restrict__ d1,
    unsigned* __restrict__ d2, unsigned* __restrict__ d3,
    unsigned* __restrict__ d4, unsigned* __restrict__ d5)
{
    const int stride = gridDim.x * 256;
    for (int idx = blockIdx.x*256 + threadIdx.x; idx < 3145728; idx += stride){
        const float* s; unsigned* d; int off;
        if (idx < 1048576){
            const int r = idx >> 18; off = idx & 262143;
            s = (r==0)?s0:(r==1)?s1:(r==2)?s2:s3;
            d = (r==0)?d0:(r==1)?d1:(r==2)?d2:d3;
        } else if (idx < 2097152){ s = s4; d = d4; off = idx - 1048576; }
        else                     { s = s5; d = d5; off = idx - 2097152; }
        f4 v = ((const f4*)s)[off];
        uint4 o;
        o.x = f32_to_pair(v.x); o.y = f32_to_pair(v.y);
        o.z = f32_to_pair(v.z); o.w = f32_to_pair(v.w);
        ((uint4*)d)[off] = o;
    }
}

// bf16x2 MFMA GEMM, 256 threads, 3 blocks/CU — for LARGE grids (mW1).
__global__ __launch_bounds__(256) void gemm_mfma(
    const unsigned* __restrict__ Apr, const unsigned* __restrict__ Wpr,
    const float* __restrict__ bias, const float* __restrict__ res,
    float* __restrict__ Cf, unsigned* __restrict__ Cp,
    int M, int N, int K, int act, int hasres, int outpair)
{
    __shared__ short Ah[2][4][64][8];
    __shared__ short Al[2][4][64][8];
    __shared__ short Bh[2][8][64][8];
    __shared__ short Bl[2][8][64][8];
    const int tid = threadIdx.x;
    const int w = tid >> 6, l = tid & 63;
    const int row0 = blockIdx.y * 64, col0 = blockIdx.x * 128;
    const int mb = (w >> 1) * 2;
    const int nb = (w & 1) * 4;

    f4v acc[2][4];
    #pragma unroll
    for (int i=0;i<2;i++)
        #pragma unroll
        for (int j=0;j<4;j++) acc[i][j] = (f4v){0.f,0.f,0.f,0.f};

    const int b_c4 = (tid & 31) * 4;
    const int b_kg = tid >> 5;

    for (int k0 = 0; k0 < K; k0 += 64){
        if (k0) __syncthreads();
        #pragma unroll
        for (int i=0;i<2;i++){
            const int u = tid + i*256;
            const int ar = u >> 3, kg = u & 7;
            const unsigned* src = Apr + (size_t)(row0 + ar)*K + k0 + kg*8;
            const uint4 p0 = *(const uint4*)src;
            const uint4 p1 = *(const uint4*)(src + 4);
            bf8v hv, lv;
            hv[0]=(short)(p0.x); lv[0]=(short)(p0.x>>16);
            hv[1]=(short)(p0.y); lv[1]=(short)(p0.y>>16);
            hv[2]=(short)(p0.z); lv[2]=(short)(p0.z>>16);
            hv[3]=(short)(p0.w); lv[3]=(short)(p0.w>>16);
            hv[4]=(short)(p1.x); lv[4]=(short)(p1.x>>16);
            hv[5]=(short)(p1.y); lv[5]=(short)(p1.y>>16);
            hv[6]=(short)(p1.z); lv[6]=(short)(p1.z>>16);
            hv[7]=(short)(p1.w); lv[7]=(short)(p1.w>>16);
            const int lane = (ar & 15) | ((kg & 3) << 4);
            const int ks = kg >> 2, mf = ar >> 4;
            *(bf8v*)&Ah[ks][mf][lane][0] = hv;
            *(bf8v*)&Al[ks][mf][lane][0] = lv;
        }
        {
            uint4 r[8];
            #pragma unroll
            for (int j=0;j<8;j++)
                r[j] = *(const uint4*)(Wpr + (size_t)(k0 + b_kg*8 + j)*N + col0 + b_c4);
            #pragma unroll
            for (int c=0;c<4;c++){
                bf8v hv, lv;
                #pragma unroll
                for (int j=0;j<8;j++){
                    const unsigned e = ((const unsigned*)&r[j])[c];
                    hv[j] = (short)e; lv[j] = (short)(e >> 16);
                }
                const int col = b_c4 + c;
                const int lane = (col & 15) | ((b_kg & 3) << 4);
                const int ks = b_kg >> 2, nf = col >> 4;
                *(bf8v*)&Bh[ks][nf][lane][0] = hv;
                *(bf8v*)&Bl[ks][nf][lane][0] = lv;
            }
        }
        __syncthreads();
        #pragma unroll
        for (int ks=0; ks<2; ks++){
            const bf8v ah0 = *(const bf8v*)&Ah[ks][mb+0][l][0];
            const bf8v ah1 = *(const bf8v*)&Ah[ks][mb+1][l][0];
            const bf8v al0 = *(const bf8v*)&Al[ks][mb+0][l][0];
            const bf8v al1 = *(const bf8v*)&Al[ks][mb+1][l][0];
            #pragma unroll
            for (int nf=0; nf<4; nf++){
                const bf8v bh = *(const bf8v*)&Bh[ks][nb+nf][l][0];
                const bf8v bl = *(const bf8v*)&Bl[ks][nb+nf][l][0];
                acc[0][nf] = __builtin_amdgcn_mfma_f32_16x16x32_bf16(ah0, bh, acc[0][nf], 0,0,0);
                acc[0][nf] = __builtin_amdgcn_mfma_f32_16x16x32_bf16(ah0, bl, acc[0][nf], 0,0,0);
                acc[0][nf] = __builtin_amdgcn_mfma_f32_16x16x32_bf16(al0, bh, acc[0][nf], 0,0,0);
                acc[1][nf] = __builtin_amdgcn_mfma_f32_16x16x32_bf16(ah1, bh, acc[1][nf], 0,0,0);
                acc[1][nf] = __builtin_amdgcn_mfma_f32_16x16x32_bf16(ah1, bl, acc[1][nf], 0,0,0);
                acc[1][nf] = __builtin_amdgcn_mfma_f32_16x16x32_bf16(al1, bh, acc[1][nf], 0,0,0);
            }
        }
    }

    const int ecol = l & 15, erow = (l >> 4) * 4;
    #pragma unroll
    for (int mf=0; mf<2; mf++){
        #pragma unroll
        for (int nf=0; nf<4; nf++){
            const int col = col0 + (w&1)*64 + nf*16 + ecol;
            const float bv = bias[col];
            #pragma unroll
            for (int j=0; j<4; j++){
                const int row = row0 + (w>>1)*32 + mf*16 + erow + j;
                float v = acc[mf][nf][j] + bv;
                if (act==1) v = fmaxf(v, 0.f);
                else if (act==2) v = gelu_f(v);
                if (hasres) v += res[(size_t)row*N + col];
                if (outpair) Cp[(size_t)row*N + col] = f32_to_pair(v);
                else         Cf[(size_t)row*N + col] = v;
            }
        }
    }
}

// bf16x2 MFMA GEMM, 512 threads: intra-block split-K x2 + depth-1 register
// prefetch + XCD-aware block swizzle (bijective) for (8,32) grids: all 8
// column-blocks of a row-panel share flat%8 -> same XCD L2 -> A panels
// become L2-resident (was 8x duplicated across XCDs).
__global__ __launch_bounds__(512) void gemm_mfma2(
    const unsigned* __restrict__ Apr, const unsigned* __restrict__ Wpr,
    const float* __restrict__ bias, const float* __restrict__ res,
    float* __restrict__ Cf, unsigned* __restrict__ Cp,
    int M, int N, int K, int act, int hasres, int outpair)
{
    __shared__ short Ah[2][2][4][64][8];   // [kh][ks][mf][lane][e]  16KB
    __shared__ short Al[2][2][4][64][8];   // 16KB
    __shared__ short Bh[2][2][8][64][8];   // 32KB
    __shared__ short Bl[2][2][8][64][8];   // 32KB
    const int tid = threadIdx.x;
    const int kh = tid >> 8;               // K-half
    const int t  = tid & 255;
    const int w = t >> 6, l = t & 63;
    int bx = blockIdx.x, by = blockIdx.y;
    if (gridDim.x == 8 && gridDim.y == 32){
        const int flat = by*8 + bx;
        by = (flat & 7)*4 + ((flat >> 3) & 3);
        bx = flat >> 5;
    }
    const int row0 = by * 64, col0 = bx * 128;
    const int mb = (w >> 1) * 2;
    const int nb = (w & 1) * 4;
    const int K2 = K >> 1;
    const int kbase = kh * K2;
    const int b_c4 = (t & 31) * 4;
    const int b_kg = t >> 5;
    const int a_r0 = t >> 3,       a_kg0 = t & 7;
    const int a_r1 = (t+256) >> 3, a_kg1 = (t+256) & 7;

    f4v acc[2][4];
    #pragma unroll
    for (int i=0;i<2;i++)
        #pragma unroll
        for (int j=0;j<4;j++) acc[i][j] = (f4v){0.f,0.f,0.f,0.f};

    uint4 pa0[2], pa1[2], pb[8];

    // load tile 0 into regs
    {
        const unsigned* s0 = Apr + (size_t)(row0 + a_r0)*K + kbase + a_kg0*8;
        const unsigned* s1 = Apr + (size_t)(row0 + a_r1)*K + kbase + a_kg1*8;
        pa0[0] = *(const uint4*)s0; pa0[1] = *(const uint4*)(s0+4);
        pa1[0] = *(const uint4*)s1; pa1[1] = *(const uint4*)(s1+4);
        #pragma unroll
        for (int j=0;j<8;j++)
            pb[j] = *(const uint4*)(Wpr + (size_t)(kbase + b_kg*8 + j)*N + col0 + b_c4);
    }

    #define STAGE_A(pr, ar, kg) { \
        bf8v hv, lv; \
        hv[0]=(short)(pr[0].x); lv[0]=(short)(pr[0].x>>16); \
        hv[1]=(short)(pr[0].y); lv[1]=(short)(pr[0].y>>16); \
        hv[2]=(short)(pr[0].z); lv[2]=(short)(pr[0].z>>16); \
        hv[3]=(short)(pr[0].w); lv[3]=(short)(pr[0].w>>16); \
        hv[4]=(short)(pr[1].x); lv[4]=(short)(pr[1].x>>16); \
        hv[5]=(short)(pr[1].y); lv[5]=(short)(pr[1].y>>16); \
        hv[6]=(short)(pr[1].z); lv[6]=(short)(pr[1].z>>16); \
        hv[7]=(short)(pr[1].w); lv[7]=(short)(pr[1].w>>16); \
        const int lane_ = ((ar) & 15) | (((kg) & 3) << 4); \
        *(bf8v*)&Ah[kh][(kg)>>2][(ar)>>4][lane_][0] = hv; \
        *(bf8v*)&Al[kh][(kg)>>2][(ar)>>4][lane_][0] = lv; }

    #define STAGE_B() { \
        _Pragma("unroll") \
        for (int c=0;c<4;c++){ \
            bf8v hv, lv; \
            _Pragma("unroll") \
            for (int j=0;j<8;j++){ \
                const unsigned e = ((const unsigned*)&pb[j])[c]; \
                hv[j] = (short)e; lv[j] = (short)(e >> 16); \
            } \
            const int col_ = b_c4 + c; \
            const int lane_ = (col_ & 15) | ((b_kg & 3) << 4); \
            *(bf8v*)&Bh[kh][b_kg>>2][col_>>4][lane_][0] = hv; \
            *(bf8v*)&Bl[kh][b_kg>>2][col_>>4][lane_][0] = lv; } }

    // stage tile 0
    STAGE_A(pa0, a_r0, a_kg0)
    STAGE_A(pa1, a_r1, a_kg1)
    STAGE_B()
    __syncthreads();

    int k0 = 0;
    while (true){
        const int kn = k0 + 64;
        const bool more = kn < K2;
        if (more){
            const unsigned* s0 = Apr + (size_t)(row0 + a_r0)*K + kbase + kn + a_kg0*8;
            const unsigned* s1 = Apr + (size_t)(row0 + a_r1)*K + kbase + kn + a_kg1*8;
            pa0[0] = *(const uint4*)s0; pa0[1] = *(const uint4*)(s0+4);
            pa1[0] = *(const uint4*)s1; pa1[1] = *(const uint4*)(s1+4);
            #pragma unroll
            for (int j=0;j<8;j++)
                pb[j] = *(const uint4*)(Wpr + (size_t)(kbase + kn + b_kg*8 + j)*N + col0 + b_c4);
        }
        #pragma unroll
        for (int ks=0; ks<2; ks++){
            const bf8v ah0 = *(const bf8v*)&Ah[kh][ks][mb+0][l][0];
            const bf8v ah1 = *(const bf8v*)&Ah[kh][ks][mb+1][l][0];
            const bf8v al0 = *(const bf8v*)&Al[kh][ks][mb+0][l][0];
            const bf8v al1 = *(const bf8v*)&Al[kh][ks][mb+1][l][0];
            #pragma unroll
            for (int nf=0; nf<4; nf++){
                const bf8v bh = *(const bf8v*)&Bh[kh][ks][nb+nf][l][0];
                const bf8v bl = *(const bf8v*)&Bl[kh][ks][nb+nf][l][0];
                acc[0][nf] = __builtin_amdgcn_mfma_f32_16x16x32_bf16(ah0, bh, acc[0][nf], 0,0,0);
                acc[0][nf] = __builtin_amdgcn_mfma_f32_16x16x32_bf16(ah0, bl, acc[0][nf], 0,0,0);
                acc[0][nf] = __builtin_amdgcn_mfma_f32_16x16x32_bf16(al0, bh, acc[0][nf], 0,0,0);
                acc[1][nf] = __builtin_amdgcn_mfma_f32_16x16x32_bf16(ah1, bh, acc[1][nf], 0,0,0);
                acc[1][nf] = __builtin_amdgcn_mfma_f32_16x16x32_bf16(ah1, bl, acc[1][nf], 0,0,0);
                acc[1][nf] = __builtin_amdgcn_mfma_f32_16x16x32_bf16(al1, bh, acc[1][nf], 0,0,0);
            }
        }
        __syncthreads();        // both halves done reading this tile
        if (!more) break;
        STAGE_A(pa0, a_r0, a_kg0)
        STAGE_A(pa1, a_r1, a_kg1)
        STAGE_B()
        __syncthreads();        // next tile staged
        k0 = kn;
    }

    // deterministic half-combine via LDS (kh1 -> kh0)
    float* cs = (float*)&Ah[0][0][0][0][0];
    if (kh == 1){
        #pragma unroll
        for (int mf=0; mf<2; mf++)
            #pragma unroll
            for (int nf=0; nf<4; nf++){
                f4 p;
                p.x=acc[mf][nf][0]; p.y=acc[mf][nf][1];
                p.z=acc[mf][nf][2]; p.w=acc[mf][nf][3];
                *(f4*)(cs + 4*(((mf*4+nf))*256 + t)) = p;
            }
    }
    __syncthreads();
    if (kh == 0){
        #pragma unroll
        for (int mf=0; mf<2; mf++)
            #pragma unroll
            for (int nf=0; nf<4; nf++){
                const f4 p = *(const f4*)(cs + 4*(((mf*4+nf))*256 + t));
                acc[mf][nf][0]+=p.x; acc[mf][nf][1]+=p.y;
                acc[mf][nf][2]+=p.z; acc[mf][nf][3]+=p.w;
            }
        const int ecol = l & 15, erow = (l >> 4) * 4;
        #pragma unroll
        for (int mf=0; mf<2; mf++){
            #pragma unroll
            for (int nf=0; nf<4; nf++){
                const int col = col0 + (w&1)*64 + nf*16 + ecol;
                const float bv = bias[col];
                #pragma unroll
                for (int j=0; j<4; j++){
                    const int row = row0 + (w>>1)*32 + mf*16 + erow + j;
                    float v = acc[mf][nf][j] + bv;
                    if (act==1) v = fmaxf(v, 0.f);
                    else if (act==2) v = gelu_f(v);
                    if (hasres) v += res[(size_t)row*N + col];
                    if (outpair) Cp[(size_t)row*N + col] = f32_to_pair(v);
                    else         Cf[(size_t)row*N + col] = v;
                }
            }
        }
    }
    #undef STAGE_A
    #undef STAGE_B
}

// f32 GEMM kept for projectors + locate head
__global__ __launch_bounds__(512) void gemm128k2(
    const float* __restrict__ A, const float* __restrict__ W,
    const float* __restrict__ bias, const float* __restrict__ res,
    float* __restrict__ C, int M, int N, int K, int act, int hasres)
{
    __shared__ float As[2][32][68];
    __shared__ float Ws[2][32][132];
    const int tid = threadIdx.x;
    const int kh = tid >> 8;
    const int t  = tid & 255;
    const int row0 = blockIdx.y*64, col0 = blockIdx.x*128;
    const int ty = t>>4, tx = t&15;
    const int am = t>>2, ak = (t&3)*8;
    const int wk = t>>3, u  = t&7;
    const int K2 = K >> 1;
    const float* Ap = A + (size_t)(row0+am)*K + kh*K2 + ak;
    const float* Wp = W + (size_t)(kh*K2 + wk)*N + col0 + u*16;
    float* Wrow = &Ws[kh][wk][0];

    f4 a0,a1,w0,w1,w2,w3;
    a0 = *(const f4*)(Ap);
    a1 = *(const f4*)(Ap + 4);
    w0 = *(const f4*)(Wp);
    w1 = *(const f4*)(Wp + 4);
    w2 = *(const f4*)(Wp + 8);
    w3 = *(const f4*)(Wp + 12);
    As[kh][ak+0][am]=a0.x; As[kh][ak+1][am]=a0.y; As[kh][ak+2][am]=a0.z; As[kh][ak+3][am]=a0.w;
    As[kh][ak+4][am]=a1.x; As[kh][ak+5][am]=a1.y; As[kh][ak+6][am]=a1.z; As[kh][ak+7][am]=a1.w;
    *(f4*)(Wrow + 8*u)      = w0;
    *(f4*)(Wrow + 8*u + 4)  = w2;
    *(f4*)(Wrow + 64 + 8*u)     = w1;
    *(f4*)(Wrow + 64 + 8*u + 4) = w3;
    __syncthreads();

    float acc[4][8];
    #pragma unroll
    for (int i=0;i<4;i++){
        #pragma unroll
        for (int j=0;j<8;j++) acc[i][j]=0.f;
    }

    int k0 = 0;
    while (true){
        const int kn = k0 + 32;
        const bool more = kn < K2;
        if (more){
            a0 = *(const f4*)(Ap + kn);
            a1 = *(const f4*)(Ap + kn + 4);
            w0 = *(const f4*)(Wp + (size_t)kn*N);
            w1 = *(const f4*)(Wp + (size_t)kn*N + 4);
            w2 = *(const f4*)(Wp + (size_t)kn*N + 8);
            w3 = *(const f4*)(Wp + (size_t)kn*N + 12);
        }
        #pragma unroll
        for (int kk=0;kk<32;kk++){
            f4 a  = *(const f4*)&As[kh][kk][ty*4];
            f4 wA = *(const f4*)&Ws[kh][kk][tx*4];
            f4 wB = *(const f4*)&Ws[kh][kk][64 + tx*4];
            float ar[4] = {a.x,a.y,a.z,a.w};
            #pragma unroll
            for (int i=0;i<4;i++){
                acc[i][0] += ar[i]*wA.x;
                acc[i][1] += ar[i]*wA.y;
                acc[i][2] += ar[i]*wA.z;
                acc[i][3] += ar[i]*wA.w;
                acc[i][4] += ar[i]*wB.x;
                acc[i][5] += ar[i]*wB.y;
                acc[i][6] += ar[i]*wB.z;
                acc[i][7] += ar[i]*wB.w;
            }
        }
        __syncthreads();
        if (!more) break;
        As[kh][ak+0][am]=a0.x; As[kh][ak+1][am]=a0.y; As[kh][ak+2][am]=a0.z; As[kh][ak+3][am]=a0.w;
        As[kh][ak+4][am]=a1.x; As[kh][ak+5][am]=a1.y; As[kh][ak+6][am]=a1.z; As[kh][ak+7][am]=a1.w;
        *(f4*)(Wrow + 8*u)      = w0;
        *(f4*)(Wrow + 8*u + 4)  = w2;
        *(f4*)(Wrow + 64 + 8*u)     = w1;
        *(f4*)(Wrow + 64 + 8*u + 4) = w3;
        __syncthreads();
        k0 = kn;
    }

    float* cs = &Ws[0][0][0];
    if (kh == 1){
        #pragma unroll
        for (int i=0;i<4;i++){
            #pragma unroll
            for (int b=0;b<2;b++){
                f4 p;
                p.x=acc[i][b*4+0]; p.y=acc[i][b*4+1]; p.z=acc[i][b*4+2]; p.w=acc[i][b*4+3];
                *(f4*)(cs + 4*(((i<<1)|b)*256 + t)) = p;
            }
        }
    }
    __syncthreads();
    if (kh == 0){
        #pragma unroll
        for (int i=0;i<4;i++){
            #pragma unroll
            for (int b=0;b<2;b++){
                const f4 p = *(const f4*)(cs + 4*(((i<<1)|b)*256 + t));
                acc[i][b*4+0]+=p.x; acc[i][b*4+1]+=p.y; acc[i][b*4+2]+=p.z; acc[i][b*4+3]+=p.w;
            }
        }
        #pragma unroll
        for (int i=0;i<4;i++){
            const int r = row0 + ty*4 + i;
            #pragma unroll
            for (int half=0; half<2; ++half){
                const int cb = col0 + tx*8 + half*4;
                f4 bv = *(const f4*)(bias + cb);
                float t0 = acc[i][half*4+0] + bv.x;
                float t1 = acc[i][half*4+1] + bv.y;
                float t2 = acc[i][half*4+2] + bv.z;
                float t3 = acc[i][half*4+3] + bv.w;
                if (act==1){ t0=fmaxf(t0,0.f); t1=fmaxf(t1,0.f); t2=fmaxf(t2,0.f); t3=fmaxf(t3,0.f); }
                else if (act==2){ t0=gelu_f(t0); t1=gelu_f(t1); t2=gelu_f(t2); t3=gelu_f(t3); }
                if (hasres){
                    f4 rv = *(const f4*)(res + (size_t)r*N + cb);
                    t0+=rv.x; t1+=rv.y; t2+=rv.z; t3+=rv.w;
                }
                f4 o; o.x=t0; o.y=t1; o.z=t2; o.w=t3;
                *(f4*)(C + (size_t)r*N + cb) = o;
            }
        }
    }
}

__global__ __launch_bounds__(256) void lnrow(
    const float* __restrict__ X, const float* __restrict__ g,
    const float* __restrict__ b, float* __restrict__ out, float eps)
{
    __shared__ float red[4];
    const int row = blockIdx.x, tid = threadIdx.x;
    const float* xp = X + (size_t)row*D_MOD;
    f4 xv = *(const f4*)(xp + tid*4);
    float s = xv.x+xv.y+xv.z+xv.w;
    #pragma unroll
    for (int m=1;m<64;m<<=1) s += __shfl_xor(s, m);
    const int wid = tid>>6, lane = tid&63;
    if (lane==0) red[wid]=s;
    __syncthreads();
    float mean = (red[0]+red[1]+red[2]+red[3]) * (1.0f/1024.0f);
    __syncthreads();
    float d0=xv.x-mean, d1=xv.y-mean, d2=xv.z-mean, d3=xv.w-mean;
    float q = d0*d0+d1*d1+d2*d2+d3*d3;
    #pragma unroll
    for (int m=1;m<64;m<<=1) q += __shfl_xor(q, m);
    if (lane==0) red[wid]=q;
    __syncthreads();
    float var = (red[0]+red[1]+red[2]+red[3]) * (1.0f/1024.0f);
    float inv = rsqrtf(var + eps);
    f4 gv = *(const f4*)(g + tid*4);
    f4 bv = *(const f4*)(b + tid*4);
    f4 o;
    o.x = d0*inv*gv.x + bv.x;
    o.y = d1*inv*gv.y + bv.y;
    o.z = d2*inv*gv.z + bv.z;
    o.w = d3*inv*gv.w + bv.w;
    *(f4*)(out + (size_t)row*D_MOD + tid*4) = o;
}

__global__ __launch_bounds__(256) void lnrow_pair(
    const float* __restrict__ X, const float* __restrict__ g,
    const float* __restrict__ b, unsigned* __restrict__ outp, float eps)
{
    __shared__ float red[4];
    const int row = blockIdx.x, tid = threadIdx.x;
    const float* xp = X + (size_t)row*D_MOD;
    f4 xv = *(const f4*)(xp + tid*4);
    float s = xv.x+xv.y+xv.z+xv.w;
    #pragma unroll
    for (int m=1;m<64;m<<=1) s += __shfl_xor(s, m);
    const int wid = tid>>6, lane = tid&63;
    if (lane==0) red[wid]=s;
    __syncthreads();
    float mean = (red[0]+red[1]+red[2]+red[3]) * (1.0f/1024.0f);
    __syncthreads();
    float d0=xv.x-mean, d1=xv.y-mean, d2=xv.z-mean, d3=xv.w-mean;
    float q = d0*d0+d1*d1+d2*d2+d3*d3;
    #pragma unroll
    for (int m=1;m<64;m<<=1) q += __shfl_xor(q, m);
    if (lane==0) red[wid]=q;
    __syncthreads();
    float var = (red[0]+red[1]+red[2]+red[3]) * (1.0f/1024.0f);
    float inv = rsqrtf(var + eps);
    f4 gv = *(const f4*)(g + tid*4);
    f4 bv = *(const f4*)(b + tid*4);
    uint4 o;
    o.x = f32_to_pair(d0*inv*gv.x + bv.x);
    o.y = f32_to_pair(d1*inv*gv.y + bv.y);
    o.z = f32_to_pair(d2*inv*gv.z + bv.z);
    o.w = f32_to_pair(d3*inv*gv.w + bv.w);
    ((uint4*)(outp + (size_t)row*D_MOD))[tid] = o;
}

// MFMA flash attention, bf16x2 (R12, validated)
__global__ __launch_bounds__(256,1) void attn_mfma(
    const float* __restrict__ Q, const float* __restrict__ Kb,
    const float* __restrict__ Vb,
    float* __restrict__ OA0, float* __restrict__ OA1,
    float* __restrict__ ML0, float* __restrict__ ML1)
{
    __shared__ short QhS[4][8][64][8];
    __shared__ short QlS[4][8][64][8];
    __shared__ short KhS[4][4][64][8];
    __shared__ short KlS[4][4][64][8];
    __shared__ short VhS[2][8][64][8];
    __shared__ short VlS[2][8][64][8];
    short* Ph = &KhS[0][0][0][0];
    short* Pl = &KlS[0][0][0][0];

    const int tid = threadIdx.x;
    const int w = tid >> 6, l = tid & 63;
    const int h  = blockIdx.x & 7;
    const int sh = (blockIdx.x >> 3) & 1;
    const int q0 = (blockIdx.x >> 4) * 128;
    const int sbase = sh * 1024;
    const float qscale = 0.08838834764831845f;

    #pragma unroll
    for (int i=0;i<2;i++){
        const int u = tid + i*256;
        const int qr = u >> 2, dks = u & 3;
        const float* src = Q + (size_t)(q0+qr)*D_MOD + h*128 + dks*32;
        float a[32];
        #pragma unroll
        for (int j=0;j<8;j++) *(f4*)&a[j*4] = ((const f4*)src)[j];
        const int qmf = qr >> 4;
        #pragma unroll
        for (int kg=0;kg<4;kg++){
            bf8v hv, lv;
            #pragma unroll
            for (int e=0;e<8;e++){
                short hi, lo;
                split2(a[kg*8+e]*qscale, hi, lo);
                hv[e]=hi; lv[e]=lo;
            }
            const int lane = (qr & 15) | (kg << 4);
            *(bf8v*)&QhS[dks][qmf][lane][0] = hv;
            *(bf8v*)&QlS[dks][qmf][lane][0] = lv;
        }
    }
    {
        const int sr = tid >> 2, dks = tid & 3;
        const float* src = Kb + (size_t)(sbase+sr)*D_MOD + h*128 + dks*32;
        float a[32];
        #pragma unroll
        for (int j=0;j<8;j++) *(f4*)&a[j*4] = ((const f4*)src)[j];
        const int smf = sr >> 4;
        #pragma unroll
        for (int kg=0;kg<4;kg++){
            bf8v hv, lv;
            #pragma unroll
            for (int e=0;e<8;e++){ short hi,lo; split2(a[kg*8+e],hi,lo); hv[e]=hi; lv[e]=lo; }
            const int lane = (sr & 15) | (kg << 4);
            *(bf8v*)&KhS[dks][smf][lane][0] = hv;
            *(bf8v*)&KlS[dks][smf][lane][0] = lv;
        }
        const int s8 = tid >> 5, d4 = (tid & 31) * 4;
        float b[8][4];
        #pragma unroll
        for (int r=0;r<8;r++)
            *(f4*)&b[r][0] = *(const f4*)(Vb + (size_t)(sbase+s8*8+r)*D_MOD + h*128 + d4);
        const int sks = s8 >> 2, sg = s8 & 3;
        #pragma unroll
        for (int c=0;c<4;c++){
            bf8v hv, lv;
            #pragma unroll
            for (int r=0;r<8;r++){ short hi,lo; split2(b[r][c],hi,lo); hv[r]=hi; lv[r]=lo; }
            const int d = d4 + c;
            const int lane = (d & 15) | (sg << 4);
            *(bf8v*)&VhS[sks][d>>4][lane][0] = hv;
            *(bf8v*)&VlS[sks][d>>4][lane][0] = lv;
        }
    }
    __syncthreads();

    float mstat[8], lstat[8];
    f4v oacc[2][8];
    #pragma unroll
    for (int i=0;i<8;i++){ mstat[i] = -__builtin_inff(); lstat[i] = 0.f; }
    #pragma unroll
    for (int i=0;i<2;i++)
        #pragma unroll
        for (int j=0;j<8;j++) oacc[i][j] = (f4v){0.f,0.f,0.f,0.f};

    for (int t=0; t<16; ++t){
        f4v sacc[2][4];
        #pragma unroll
        for (int i=0;i<2;i++)
            #pragma unroll
            for (int j=0;j<4;j++) sacc[i][j] = (f4v){0.f,0.f,0.f,0.f};
        #pragma unroll
        for (int dks=0; dks<4; dks++){
            const bf8v qh0 = *(const bf8v*)&QhS[dks][2*w+0][l][0];
            const bf8v qh1 = *(const bf8v*)&QhS[dks][2*w+1][l][0];
            const bf8v ql0 = *(const bf8v*)&QlS[dks][2*w+0][l][0];
            const bf8v ql1 = *(const bf8v*)&QlS[dks][2*w+1][l][0];
            #pragma unroll
            for (int sf=0; sf<4; sf++){
                const bf8v kh = *(const bf8v*)&KhS[dks][sf][l][0];
                const bf8v kl = *(const bf8v*)&KlS[dks][sf][l][0];
                sacc[0][sf] = __builtin_amdgcn_mfma_f32_16x16x32_bf16(qh0, kh, sacc[0][sf], 0,0,0);
                sacc[0][sf] = __builtin_amdgcn_mfma_f32_16x16x32_bf16(qh0, kl, sacc[0][sf], 0,0,0);
                sacc[0][sf] = __builtin_amdgcn_mfma_f32_16x16x32_bf16(ql0, kh, sacc[0][sf], 0,0,0);
                sacc[1][sf] = __builtin_amdgcn_mfma_f32_16x16x32_bf16(qh1, kh, sacc[1][sf], 0,0,0);
                sacc[1][sf] = __builtin_amdgcn_mfma_f32_16x16x32_bf16(qh1, kl, sacc[1][sf], 0,0,0);
                sacc[1][sf] = __builtin_amdgcn_mfma_f32_16x16x32_bf16(ql1, kh, sacc[1][sf], 0,0,0);
            }
        }
        __syncthreads();

        float scr[8];
        #pragma unroll
        for (int mfi=0; mfi<2; mfi++){
            #pragma unroll
            for (int j=0; j<4; j++){
                const int si = mfi*4 + j;
                float tm = fmaxf(fmaxf(sacc[mfi][0][j], sacc[mfi][1][j]),
                                 fmaxf(sacc[mfi][2][j], sacc[mfi][3][j]));
                tm = fmaxf(tm, __shfl_xor(tm,1));
                tm = fmaxf(tm, __shfl_xor(tm,2));
                tm = fmaxf(tm, __shfl_xor(tm,4));
                tm = fmaxf(tm, __shfl_xor(tm,8));
                const float mn = fmaxf(mstat[si], tm);
                const float sc = __expf(mstat[si] - mn);
                float rs = 0.f;
                #pragma unroll
                for (int sf=0; sf<4; sf++){
                    const float p = __expf(sacc[mfi][sf][j] - mn);
                    sacc[mfi][sf][j] = p; rs += p;
                }
                rs += __shfl_xor(rs,1); rs += __shfl_xor(rs,2);
                rs += __shfl_xor(rs,4); rs += __shfl_xor(rs,8);
                lstat[si] = lstat[si]*sc + rs;
                mstat[si] = mn;
                scr[si] = sc;
            }
        }
        {
            const int pe = l & 7;
            const int rb4 = (l >> 4) * 4;
            const int sgb = (l & 15) >> 3;
            #pragma unroll
            for (int mfi=0; mfi<2; mfi++){
                const int qmf = 2*w + mfi;
                #pragma unroll
                for (int sf=0; sf<4; sf++){
                    const int sks = sf >> 1;
                    const int sg = (sf & 1)*2 + sgb;
                    #pragma unroll
                    for (int j=0; j<4; j++){
                        const int lane = (rb4 + j) | (sg << 4);
                        short hi, lo;
                        split2(sacc[mfi][sf][j], hi, lo);
                        const int off = ((sks*8 + qmf)*64 + lane)*8 + pe;
                        Ph[off] = hi;
                        Pl[off] = lo;
                    }
                }
            }
        }
        __syncthreads();

        #pragma unroll
        for (int mfi=0; mfi<2; mfi++){
            #pragma unroll
            for (int j=0; j<4; j++){
                const float sc = scr[mfi*4+j];
                #pragma unroll
                for (int dmf=0; dmf<8; dmf++) oacc[mfi][dmf][j] *= sc;
            }
        }
        #pragma unroll
        for (int sks=0; sks<2; sks++){
            const bf8v ph0 = *(const bf8v*)&Ph[((sks*8 + 2*w+0)*64 + l)*8];
            const bf8v ph1 = *(const bf8v*)&Ph[((sks*8 + 2*w+1)*64 + l)*8];
            const bf8v pl0 = *(const bf8v*)&Pl[((sks*8 + 2*w+0)*64 + l)*8];
            const bf8v pl1 = *(const bf8v*)&Pl[((sks*8 + 2*w+1)*64 + l)*8];
            #pragma unroll
            for (int dmf=0; dmf<8; dmf++){
                const bf8v vh = *(const bf8v*)&VhS[sks][dmf][l][0];
                const bf8v vl = *(const bf8v*)&VlS[sks][dmf][l][0];
                oacc[0][dmf] = __builtin_amdgcn_mfma_f32_16x16x32_bf16(ph0, vh, oacc[0][dmf], 0,0,0);
                oacc[0][dmf] = __builtin_amdgcn_mfma_f32_16x16x32_bf16(ph0, vl, oacc[0][dmf], 0,0,0);
                oacc[0][dmf] = __builtin_amdgcn_mfma_f32_16x16x32_bf16(pl0, vh, oacc[0][dmf], 0,0,0);
                oacc[1][dmf] = __builtin_amdgcn_mfma_f32_16x16x32_bf16(ph1, vh, oacc[1][dmf], 0,0,0);
                oacc[1][dmf] = __builtin_amdgcn_mfma_f32_16x16x32_bf16(ph1, vl, oacc[1][dmf], 0,0,0);
                oacc[1][dmf] = __builtin_amdgcn_mfma_f32_16x16x32_bf16(pl1, vh, oacc[1][dmf], 0,0,0);
            }
        }
        __syncthreads();

        if (t < 15){
            const int sb = sbase + (t+1)*64;
            const int sr = tid >> 2, dks = tid & 3;
            const float* src = Kb + (size_t)(sb+sr)*D_MOD + h*128 + dks*32;
            float a[32];
            #pragma unroll
            for (int j=0;j<8;j++) *(f4*)&a[j*4] = ((const f4*)src)[j];
            const int smf = sr >> 4;
            #pragma unroll
            for (int kg=0;kg<4;kg++){
                bf8v hv, lv;
                #pragma unroll
                for (int e=0;e<8;e++){ short hi,lo; split2(a[kg*8+e],hi,lo); hv[e]=hi; lv[e]=lo; }
                const int lane = (sr & 15) | (kg << 4);
                *(bf8v*)&KhS[dks][smf][lane][0] = hv;
                *(bf8v*)&KlS[dks][smf][lane][0] = lv;
            }
            const int s8 = tid >> 5, d4 = (tid & 31) * 4;
            float b[8][4];
            #pragma unroll
            for (int r=0;r<8;r++)
                *(f4*)&b[r][0] = *(const f4*)(Vb + (size_t)(sb+s8*8+r)*D_MOD + h*128 + d4);
            const int sks = s8 >> 2, sg = s8 & 3;
            #pragma unroll
            for (int c=0;c<4;c++){
                bf8v hv, lv;
                #pragma unroll
                for (int r=0;r<8;r++){ short hi,lo; split2(b[r][c],hi,lo); hv[r]=hi; lv[r]=lo; }
                const int d = d4 + c;
                const int lane = (d & 15) | (sg << 4);
                *(bf8v*)&VhS[sks][d>>4][lane][0] = hv;
                *(bf8v*)&VlS[sks][d>>4][lane][0] = lv;
            }
        }
        __syncthreads();
    }

    float* OAp = sh ? OA1 : OA0;
    float* MLp = sh ? ML1 : ML0;
    const int erow = (l >> 4) * 4, ecol = l & 15;
    #pragma unroll
    for (int mfi=0; mfi<2; mfi++){
        #pragma unroll
        for (int dmf=0; dmf<8; dmf++){
            const int col = h*128 + dmf*16 + ecol;
            #pragma unroll
            for (int j=0; j<4; j++){
                const int row = q0 + w*32 + mfi*16 + erow + j;
                OAp[(size_t)row*D_MOD + col] = oacc[mfi][dmf][j];
            }
        }
    }
    if (ecol == 0){
        #pragma unroll
        for (int mfi=0; mfi<2; mfi++){
            #pragma unroll
            for (int j=0; j<4; j++){
                const int row = q0 + w*32 + mfi*16 + erow + j;
                MLp[(size_t)row*16 + h*2 + 0] = mstat[mfi*4+j];
                MLp[(size_t)row*16 + h*2 + 1] = lstat[mfi*4+j];
            }
        }
    }
}

// flash-combine of the two s-halves + bias-KV token; writes bf16-pair output
__global__ __launch_bounds__(256) void attn_combine(
    const float* __restrict__ Q, const float* __restrict__ kbias,
    const float* __restrict__ vbias,
    const float* __restrict__ OA0, const float* __restrict__ OA1,
    const float* __restrict__ ML0, const float* __restrict__ ML1,
    unsigned* __restrict__ OP)
{
    const int row = blockIdx.x, t = threadIdx.x;
    const int h = t >> 5;
    const int cc = t & 31;
    const float qscale = 0.08838834764831845f;
    const f4 qv = *(const f4*)(Q + (size_t)row*D_MOD + h*128 + cc*4);
    const f4 kb = *(const f4*)(kbias + h*128 + cc*4);
    float part = qv.x*kb.x + qv.y*kb.y + qv.z*kb.z + qv.w*kb.w;
    part += __shfl_xor(part,1); part += __shfl_xor(part,2);
    part += __shfl_xor(part,4); part += __shfl_xor(part,8);
    part += __shfl_xor(part,16);
    const float sb = part * qscale;
    const float m0 = ML0[(size_t)row*16 + h*2], l0 = ML0[(size_t)row*16 + h*2 + 1];
    const float m1 = ML1[(size_t)row*16 + h*2], l1 = ML1[(size_t)row*16 + h*2 + 1];
    const float M  = fmaxf(fmaxf(m0, m1), sb);
    const float w0 = __expf(m0 - M), w1 = __expf(m1 - M), wb = __expf(sb - M);
    const float inv = 1.0f / (w0*l0 + w1*l1 + wb);
    const f4 o0 = *(const f4*)(OA0 + (size_t)row*D_MOD + t*4);
    const f4 o1 = *(const f4*)(OA1 + (size_t)row*D_MOD + t*4);
    const f4 vb = *(const f4*)(vbias + h*128 + cc*4);
    uint4 o;
    o.x = f32_to_pair((o0.x*w0 + o1.x*w1 + vb.x*wb) * inv);
    o.y = f32_to_pair((o0.y*w0 + o1.y*w1 + vb.y*wb) * inv);
    o.z = f32_to_pair((o0.z*w0 + o1.z*w1 + vb.z*wb) * inv);
    o.w = f32_to_pair((o0.w*w0 + o1.w*w1 + vb.w*wb) * inv);
    *(uint4*)(OP + (size_t)row*D_MOD + t*4) = o;
}

__global__ __launch_bounds__(64) void locate_head(
    const float* __restrict__ mid, const float* __restrict__ W2,
    const float* __restrict__ b2, float* __restrict__ loc_ws,
    float* __restrict__ loc_out)
{
    const int row = blockIdx.x, lane = threadIdx.x;
    const float* m = mid + (size_t)row*512;
    f4 v0 = *(const f4*)(m + lane*8);
    f4 v1 = *(const f4*)(m + lane*8 + 4);
    f4 w0 = *(const f4*)(W2 + lane*8);
    f4 w1 = *(const f4*)(W2 + lane*8 + 4);
    float s = v0.x*w0.x + v0.y*w0.y + v0.z*w0.z + v0.w*w0.w
            + v1.x*w1.x + v1.y*w1.y + v1.z*w1.z + v1.w*w1.w;
    #pragma unroll
    for (int mm=1; mm<64; mm<<=1) s += __shfl_xor(s, mm);
    if (lane==0){
        float z = s + b2[0];
        float l = 1.0f/(1.0f + expf(-z));
        loc_ws[row] = l;
        loc_out[row] = l;
    }
}

__global__ __launch_bounds__(1024) void segscan(
    const float* __restrict__ located, const float* __restrict__ thrp,
    float* __restrict__ out_segid, float* __restrict__ out_segtype,
    float* __restrict__ out_numseg, int* __restrict__ wsi)
{
    __shared__ int clips[2048];
    __shared__ int segid[2048];
    __shared__ int sstart[2049];
    __shared__ int wsum[16];
    const int tid = threadIdx.x;
    const float thr = *thrp;
    for (int t=tid; t<2048; t+=1024) clips[t] = (located[t] > thr) ? 1 : 0;
    __syncthreads();
    const int t0 = tid*2, t1 = t0+1;
    int f0 = (t0==0) ? 0 : (clips[t0]!=clips[t0-1] ? 1 : 0);
    int f1 = (clips[t1]!=clips[t1-1] ? 1 : 0);
    int e0 = f0, e1 = f0+f1;
    const int lane = tid&63, wid = tid>>6;
    int v = e1;
    #pragma unroll
    for (int off=1; off<64; off<<=1){
        int u = __shfl_up(v, off, 64);
        if (lane>=off) v += u;
    }
    if (lane==63) wsum[wid] = v;
    __syncthreads();
    if (tid < 16){
        int w = wsum[tid];
        #pragma unroll
        for (int off=1; off<16; off<<=1){
            int u = __shfl_up(w, off, 16);
            if (tid>=off) w += u;
        }
        wsum[tid] = w;
    }
    __syncthreads();
    int base = (wid>0 ? wsum[wid-1] : 0) + (v - e1);
    segid[t0] = base + e0;
    segid[t1] = base + e1;
    __syncthreads();
    const int ns = segid[2047] + 1;
    for (int t=tid; t<2048; t+=1024){
        if (t==0 || segid[t]!=segid[t-1]) sstart[segid[t]] = t;
    }
    if (tid==0) sstart[ns] = 2048;
    __syncthreads();
    for (int t=tid; t<2048; t+=1024) out_segid[t] = (float)segid[t];
    for (int s=tid; s<2048; s+=1024)
        out_segtype[s] = (s<ns) ? (float)clips[sstart[s]] : -2147483648.0f;
    if (tid==0){ out_numseg[0] = (float)ns; wsi[0] = ns; }
    for (int s=tid; s<=2048; s+=1024) wsi[2+s] = (s<=ns) ? sstart[s] : 0;
}

__global__ __launch_bounds__(256) void segpool(
    const float* __restrict__ V, const float* __restrict__ A,
    const int* __restrict__ wsi, float* __restrict__ out_vid,
    float* __restrict__ out_aud)
{
    const int s = blockIdx.x;
    const int c = threadIdx.x*4;
    const int ns = wsi[0];
    f4 vv; vv.x=0.f; vv.y=0.f; vv.z=0.f; vv.w=0.f;
    f4 av = vv;
    if (s < ns){
        const int st = wsi[2+s], en = wsi[2+s+1];
        for (int r=st; r<en; ++r){
            f4 x = *(const f4*)(V + (size_t)r*D_MOD + c);
            vv.x+=x.x; vv.y+=x.y; vv.z+=x.z; vv.w+=x.w;
            f4 y = *(const f4*)(A + (size_t)r*D_MOD + c);
            av.x+=y.x; av.y+=y.y; av.z+=y.z; av.w+=y.w;
        }
        const float inv = 1.0f/(float)(en-st);
        vv.x*=inv; vv.y*=inv; vv.z*=inv; vv.w*=inv;
        av.x*=inv; av.y*=inv; av.z*=inv; av.w*=inv;
    }
    *(f4*)(out_vid + (size_t)s*D_MOD + c) = vv;
    *(f4*)(out_aud + (size_t)s*D_MOD + c) = av;
}

extern "C" void kernel_launch(void* const* d_in, const int* in_sizes, int n_in,
                              void* d_out, int out_size, void* d_ws, size_t ws_size,
                              hipStream_t stream) {
    (void)in_sizes; (void)n_in; (void)out_size; (void)ws_size;
    const float* video = (const float*)d_in[0];
    const float* audio = (const float*)d_in[1];
    const float* apW1  = (const float*)d_in[2];
    const float* apb1  = (const float*)d_in[3];
    const float* apW2  = (const float*)d_in[4];
    const float* apb2  = (const float*)d_in[5];
    const float* vpW1  = (const float*)d_in[6];
    const float* vpb1  = (const float*)d_in[7];
    const float* vpW2  = (const float*)d_in[8];
    const float* vpb2  = (const float*)d_in[9];
    const float* preg  = (const float*)d_in[10];
    const float* preb  = (const float*)d_in[11];
    const float* bWq   = (const float*)d_in[12];
    const float* bbq   = (const float*)d_in[13];
    const float* bWk   = (const float*)d_in[14];
    const float* bbk   = (const float*)d_in[15];
    const float* bWv   = (const float*)d_in[16];
    const float* bbv   = (const float*)d_in[17];
    const float* bWo   = (const float*)d_in[18];
    const float* bbo   = (const float*)d_in[19];
    const float* bbiask= (const float*)d_in[20];
    const float* bbiasv= (const float*)d_in[21];
    const float* bg1   = (const float*)d_in[22];
    const float* bb1   = (const float*)d_in[23];
    const float* bg2   = (const float*)d_in[24];
    const float* bb2   = (const float*)d_in[25];
    const float* bmW1  = (const float*)d_in[26];
    const float* bmb1  = (const float*)d_in[27];
    const float* bmW2  = (const float*)d_in[28];
    const float* bmb2  = (const float*)d_in[29];
    const float* lhW1  = (const float*)d_in[30];
    const float* lhb1  = (const float*)d_in[31];
    const float* lhW2  = (const float*)d_in[32];
    const float* lhb2  = (const float*)d_in[33];
    const float* thrp  = (const float*)d_in[34];

    float* ws = (float*)d_ws;
    float* V    = ws + 0;
    float* Abuf = ws + 2097152;
    float* X    = ws + 4194304;
    float* H    = ws + 6291456;
    float* Q    = ws + 8388608;
    float* Kb   = ws + 10485760;
    float* Vb   = ws + 12582912;
    float* Obuf = ws + 14680064;
    unsigned* M4p = (unsigned*)(ws + 8388608);
    float* M512 = ws + 16777216;
    float* LOC  = ws + 17825792;
    int*   WSI  = (int*)(ws + 17827840);
    float* ML0  = ws + 17829952;
    float* ML1  = ws + 17862720;
    unsigned* Vp  = (unsigned*)(ws + 17895488);
    unsigned* OPp = (unsigned*)(ws + 19992640);
    unsigned* WQp = (unsigned*)(ws + 22089792);
    unsigned* WKp = (unsigned*)(ws + 23138368);
    unsigned* WVp = (unsigned*)(ws + 24186944);
    unsigned* WOp = (unsigned*)(ws + 25235520);
    unsigned* W1p = (unsigned*)(ws + 26284096);
    unsigned* W2p = (unsigned*)(ws + 30478400);
    unsigned* Hp  = (unsigned*)H;

    float* out = (float*)d_out;
    float* out_vid     = out + 0;
    float* out_aud     = out + 2097152;
    float* out_loc     = out + 4194304;
    float* out_segid   = out + 4196352;
    float* out_segtype = out + 4198400;
    float* out_numseg  = out + 4200448;

    const dim3 B512(512);
    const dim3 B256(256);
    #define GRID128(M,N) dim3((N)/128,(M)/64)
    #define GRIDM(M,N)   dim3((N)/128,(M)/64)

    // projectors (f32 path, exact for pools)
    gemm128k2<<<GRID128(2048,512), B512, 0, stream>>>(audio, apW1, apb1, nullptr, M512, 2048,512,128, 1,0);
    gemm128k2<<<GRID128(2048,1024),B512, 0, stream>>>(M512, apW2, apb2, nullptr, Abuf, 2048,1024,512, 0,0);
    gemm128k2<<<GRID128(2048,512), B512, 0, stream>>>(video, vpW1, vpb1, nullptr, M512, 2048,512,1024, 1,0);
    gemm128k2<<<GRID128(2048,1024),B512, 0, stream>>>(M512, vpW2, vpb2, nullptr, V,    2048,1024,512, 0,0);
    lnrow<<<2048, B256, 0, stream>>>(Abuf, preg, preb, X, 1e-6f);
    convert1<<<2048, B256, 0, stream>>>(V, Vp, 524288);

    for (int l=0; l<8; ++l){
        const size_t wo = (size_t)l*1024*1024;
        const size_t bo = (size_t)l*1024;
        const size_t mo1 = (size_t)l*1024*4096;
        convert6<<<1536, B256, 0, stream>>>(bWq+wo, bWk+wo, bWv+wo, bWo+wo,
                                            bmW1+mo1, bmW2+mo1,
                                            WQp, WKp, WVp, WOp, W1p, W2p);
        lnrow_pair<<<2048, B256, 0, stream>>>(X, bg1+bo, bb1+bo, Hp, 1e-5f);
        gemm_mfma2<<<GRIDM(2048,1024), B512, 0, stream>>>(Hp, WQp, bbq+bo, nullptr, Q,  nullptr, 2048,1024,1024, 0,0,0);
        gemm_mfma2<<<GRIDM(2048,1024), B512, 0, stream>>>(Vp, WKp, bbk+bo, nullptr, Kb, nullptr, 2048,1024,1024, 0,0,0);
        gemm_mfma2<<<GRIDM(2048,1024), B512, 0, stream>>>(Vp, WVp, bbv+bo, nullptr, Vb, nullptr, 2048,1024,1024, 0,0,0);
        attn_mfma<<<256, B256, 0, stream>>>(Q, Kb, Vb, Obuf, H, ML0, ML1);
        attn_combine<<<2048, B256, 0, stream>>>(Q, bbiask+bo, bbiasv+bo, Obuf, H, ML0, ML1, OPp);
        gemm_mfma2<<<GRIDM(2048,1024), B512, 0, stream>>>(OPp, WOp, bbo+bo, X, X, nullptr, 2048,1024,1024, 0,1,0);
        lnrow_pair<<<2048, B256, 0, stream>>>(X, bg2+bo, bb2+bo, Hp, 1e-5f);
        gemm_mfma<<<GRIDM(2048,4096), B256, 0, stream>>>(Hp, W1p, bmb1+(size_t)l*4096, nullptr, nullptr, M4p, 2048,4096,1024, 2,0,1);
        gemm_mfma2<<<GRIDM(2048,1024), B512, 0, stream>>>(M4p, W2p, bmb2+bo, X, X, nullptr, 2048,1024,4096, 0,1,0);
    }

    gemm128k2<<<GRID128(2048,512), B512, 0, stream>>>(X, lhW1, lhb1, nullptr, M512, 2048,512,1024, 1,0);
    locate_head<<<2048, dim3(64), 0, stream>>>(M512, lhW2, lhb2, LOC, out_loc);
    segscan<<<1, dim3(1024), 0, stream>>>(LOC, thrp, out_segid, out_segtype, out_numseg, WSI);
    segpool<<<2048, B256, 0, stream>>>(V, Abuf, WSI, out_vid, out_aud);
}

// Round 19
// 4072.457 us; speedup vs baseline: 1.1343x; 1.0070x over previous
//
#include <hip/hip_runtime.h>
#include <math.h>

typedef float4 f4;
typedef __attribute__((ext_vector_type(8))) short bf8v;
typedef __attribute__((ext_vector_type(4))) float f4v;

#define T_SEQ 2048
#define D_MOD 1024

__device__ __forceinline__ float gelu_f(float x){
    float u = 0.7978845608028654f*(x + 0.044715f*x*x*x);
    return 0.5f*x*(1.0f + tanhf(u));
}

// pack f32 -> (hi bf16 rounded, lo bf16) ; x ~= hi + lo
__device__ __forceinline__ unsigned f32_to_pair(float x){
    unsigned u = __float_as_uint(x);
    unsigned hi = (u + 0x7FFFu + ((u >> 16) & 1u)) >> 16;
    float hif = __uint_as_float(hi << 16);
    float lof = x - hif;
    unsigned v = __float_as_uint(lof);
    unsigned lo = (v + 0x7FFFu + ((v >> 16) & 1u)) >> 16;
    return hi | (lo << 16);
}

// truncating split: hi = trunc-bf16(x), lo = trunc-bf16(x-hi)
__device__ __forceinline__ void split2(float x, short& hi, short& lo){
    unsigned u = __float_as_uint(x);
    hi = (short)(u >> 16);
    float rem = x - __uint_as_float(u & 0xFFFF0000u);
    lo = (short)(__float_as_uint(rem) >> 16);
}

__global__ __launch_bounds__(256) void convert1(
    const float* __restrict__ s, unsigned* __restrict__ d, int n4)
{
    const int i = blockIdx.x*256 + threadIdx.x;
    if (i < n4){
        f4 v = ((const f4*)s)[i];
        uint4 o;
        o.x = f32_to_pair(v.x); o.y = f32_to_pair(v.y);
        o.z = f32_to_pair(v.z); o.w = f32_to_pair(v.w);
        ((uint4*)d)[i] = o;
    }
}

__global__ __launch_bounds__(256) void convert6(
    const float* __restrict__ s0, const float* __restrict__ s1,
    const float* __restrict__ s2, const float* __restrict__ s3,
    const float* __restrict__ s4, const float* __restrict__ s5,
    unsigned* __restrict__ d0, unsigned* __restrict__ d1,
    unsigned* __restrict__ d2, unsigned* __restrict__ d3,
    unsigned* __restrict__ d4, unsigned* __restrict__ d5)
{
    const int stride = gridDim.x * 256;
    for (int idx = blockIdx.x*256 + threadIdx.x; idx < 3145728; idx += stride){
        const float* s; unsigned* d; int off;
        if (idx < 1048576){
            const int r = idx >> 18; off = idx & 262143;
            s = (r==0)?s0:(r==1)?s1:(r==2)?s2:s3;
            d = (r==0)?d0:(r==1)?d1:(r==2)?d2:d3;
        } else if (idx < 2097152){ s = s4; d = d4; off = idx - 1048576; }
        else                     { s = s5; d = d5; off = idx - 2097152; }
        f4 v = ((const f4*)s)[off];
        uint4 o;
        o.x = f32_to_pair(v.x); o.y = f32_to_pair(v.y);
        o.z = f32_to_pair(v.z); o.w = f32_to_pair(v.w);
        ((uint4*)d)[off] = o;
    }
}

// bf16x2 MFMA GEMM, 256 threads, 3 blocks/CU — for LARGE grids (mW1).
__global__ __launch_bounds__(256) void gemm_mfma(
    const unsigned* __restrict__ Apr, const unsigned* __restrict__ Wpr,
    const float* __restrict__ bias, const float* __restrict__ res,
    float* __restrict__ Cf, unsigned* __restrict__ Cp,
    int M, int N, int K, int act, int hasres, int outpair)
{
    __shared__ short Ah[2][4][64][8];
    __shared__ short Al[2][4][64][8];
    __shared__ short Bh[2][8][64][8];
    __shared__ short Bl[2][8][64][8];
    const int tid = threadIdx.x;
    const int w = tid >> 6, l = tid & 63;
    const int row0 = blockIdx.y * 64, col0 = blockIdx.x * 128;
    const int mb = (w >> 1) * 2;
    const int nb = (w & 1) * 4;

    f4v acc[2][4];
    #pragma unroll
    for (int i=0;i<2;i++)
        #pragma unroll
        for (int j=0;j<4;j++) acc[i][j] = (f4v){0.f,0.f,0.f,0.f};

    const int b_c4 = (tid & 31) * 4;
    const int b_kg = tid >> 5;

    for (int k0 = 0; k0 < K; k0 += 64){
        if (k0) __syncthreads();
        #pragma unroll
        for (int i=0;i<2;i++){
            const int u = tid + i*256;
            const int ar = u >> 3, kg = u & 7;
            const unsigned* src = Apr + (size_t)(row0 + ar)*K + k0 + kg*8;
            const uint4 p0 = *(const uint4*)src;
            const uint4 p1 = *(const uint4*)(src + 4);
            bf8v hv, lv;
            hv[0]=(short)(p0.x); lv[0]=(short)(p0.x>>16);
            hv[1]=(short)(p0.y); lv[1]=(short)(p0.y>>16);
            hv[2]=(short)(p0.z); lv[2]=(short)(p0.z>>16);
            hv[3]=(short)(p0.w); lv[3]=(short)(p0.w>>16);
            hv[4]=(short)(p1.x); lv[4]=(short)(p1.x>>16);
            hv[5]=(short)(p1.y); lv[5]=(short)(p1.y>>16);
            hv[6]=(short)(p1.z); lv[6]=(short)(p1.z>>16);
            hv[7]=(short)(p1.w); lv[7]=(short)(p1.w>>16);
            const int lane = (ar & 15) | ((kg & 3) << 4);
            const int ks = kg >> 2, mf = ar >> 4;
            *(bf8v*)&Ah[ks][mf][lane][0] = hv;
            *(bf8v*)&Al[ks][mf][lane][0] = lv;
        }
        {
            uint4 r[8];
            #pragma unroll
            for (int j=0;j<8;j++)
                r[j] = *(const uint4*)(Wpr + (size_t)(k0 + b_kg*8 + j)*N + col0 + b_c4);
            #pragma unroll
            for (int c=0;c<4;c++){
                bf8v hv, lv;
                #pragma unroll
                for (int j=0;j<8;j++){
                    const unsigned e = ((const unsigned*)&r[j])[c];
                    hv[j] = (short)e; lv[j] = (short)(e >> 16);
                }
                const int col = b_c4 + c;
                const int lane = (col & 15) | ((b_kg & 3) << 4);
                const int ks = b_kg >> 2, nf = col >> 4;
                *(bf8v*)&Bh[ks][nf][lane][0] = hv;
                *(bf8v*)&Bl[ks][nf][lane][0] = lv;
            }
        }
        __syncthreads();
        #pragma unroll
        for (int ks=0; ks<2; ks++){
            const bf8v ah0 = *(const bf8v*)&Ah[ks][mb+0][l][0];
            const bf8v ah1 = *(const bf8v*)&Ah[ks][mb+1][l][0];
            const bf8v al0 = *(const bf8v*)&Al[ks][mb+0][l][0];
            const bf8v al1 = *(const bf8v*)&Al[ks][mb+1][l][0];
            #pragma unroll
            for (int nf=0; nf<4; nf++){
                const bf8v bh = *(const bf8v*)&Bh[ks][nb+nf][l][0];
                const bf8v bl = *(const bf8v*)&Bl[ks][nb+nf][l][0];
                acc[0][nf] = __builtin_amdgcn_mfma_f32_16x16x32_bf16(ah0, bh, acc[0][nf], 0,0,0);
                acc[0][nf] = __builtin_amdgcn_mfma_f32_16x16x32_bf16(ah0, bl, acc[0][nf], 0,0,0);
                acc[0][nf] = __builtin_amdgcn_mfma_f32_16x16x32_bf16(al0, bh, acc[0][nf], 0,0,0);
                acc[1][nf] = __builtin_amdgcn_mfma_f32_16x16x32_bf16(ah1, bh, acc[1][nf], 0,0,0);
                acc[1][nf] = __builtin_amdgcn_mfma_f32_16x16x32_bf16(ah1, bl, acc[1][nf], 0,0,0);
                acc[1][nf] = __builtin_amdgcn_mfma_f32_16x16x32_bf16(al1, bh, acc[1][nf], 0,0,0);
            }
        }
    }

    const int ecol = l & 15, erow = (l >> 4) * 4;
    #pragma unroll
    for (int mf=0; mf<2; mf++){
        #pragma unroll
        for (int nf=0; nf<4; nf++){
            const int col = col0 + (w&1)*64 + nf*16 + ecol;
            const float bv = bias[col];
            #pragma unroll
            for (int j=0; j<4; j++){
                const int row = row0 + (w>>1)*32 + mf*16 + erow + j;
                float v = acc[mf][nf][j] + bv;
                if (act==1) v = fmaxf(v, 0.f);
                else if (act==2) v = gelu_f(v);
                if (hasres) v += res[(size_t)row*N + col];
                if (outpair) Cp[(size_t)row*N + col] = f32_to_pair(v);
                else         Cf[(size_t)row*N + col] = v;
            }
        }
    }
}

// bf16x2 MFMA GEMM, 512 threads: split-K x2 + depth-1 prefetch + XCD swizzle
// for (8,32) grids (QKVO). 96KB LDS, 1 block/CU.
__global__ __launch_bounds__(512) void gemm_mfma2(
    const unsigned* __restrict__ Apr, const unsigned* __restrict__ Wpr,
    const float* __restrict__ bias, const float* __restrict__ res,
    float* __restrict__ Cf, unsigned* __restrict__ Cp,
    int M, int N, int K, int act, int hasres, int outpair)
{
    __shared__ short Ah[2][2][4][64][8];
    __shared__ short Al[2][2][4][64][8];
    __shared__ short Bh[2][2][8][64][8];
    __shared__ short Bl[2][2][8][64][8];
    const int tid = threadIdx.x;
    const int kh = tid >> 8;
    const int t  = tid & 255;
    const int w = t >> 6, l = t & 63;
    int bx = blockIdx.x, by = blockIdx.y;
    if (gridDim.x == 8 && gridDim.y == 32){
        const int flat = by*8 + bx;
        by = (flat & 7)*4 + ((flat >> 3) & 3);
        bx = flat >> 5;
    }
    const int row0 = by * 64, col0 = bx * 128;
    const int mb = (w >> 1) * 2;
    const int nb = (w & 1) * 4;
    const int K2 = K >> 1;
    const int kbase = kh * K2;
    const int b_c4 = (t & 31) * 4;
    const int b_kg = t >> 5;
    const int a_r0 = t >> 3,       a_kg0 = t & 7;
    const int a_r1 = (t+256) >> 3, a_kg1 = (t+256) & 7;

    f4v acc[2][4];
    #pragma unroll
    for (int i=0;i<2;i++)
        #pragma unroll
        for (int j=0;j<4;j++) acc[i][j] = (f4v){0.f,0.f,0.f,0.f};

    uint4 pa0[2], pa1[2], pb[8];

    {
        const unsigned* s0 = Apr + (size_t)(row0 + a_r0)*K + kbase + a_kg0*8;
        const unsigned* s1 = Apr + (size_t)(row0 + a_r1)*K + kbase + a_kg1*8;
        pa0[0] = *(const uint4*)s0; pa0[1] = *(const uint4*)(s0+4);
        pa1[0] = *(const uint4*)s1; pa1[1] = *(const uint4*)(s1+4);
        #pragma unroll
        for (int j=0;j<8;j++)
            pb[j] = *(const uint4*)(Wpr + (size_t)(kbase + b_kg*8 + j)*N + col0 + b_c4);
    }

    #define STAGE_A(pr, ar, kg) { \
        bf8v hv, lv; \
        hv[0]=(short)(pr[0].x); lv[0]=(short)(pr[0].x>>16); \
        hv[1]=(short)(pr[0].y); lv[1]=(short)(pr[0].y>>16); \
        hv[2]=(short)(pr[0].z); lv[2]=(short)(pr[0].z>>16); \
        hv[3]=(short)(pr[0].w); lv[3]=(short)(pr[0].w>>16); \
        hv[4]=(short)(pr[1].x); lv[4]=(short)(pr[1].x>>16); \
        hv[5]=(short)(pr[1].y); lv[5]=(short)(pr[1].y>>16); \
        hv[6]=(short)(pr[1].z); lv[6]=(short)(pr[1].z>>16); \
        hv[7]=(short)(pr[1].w); lv[7]=(short)(pr[1].w>>16); \
        const int lane_ = ((ar) & 15) | (((kg) & 3) << 4); \
        *(bf8v*)&Ah[kh][(kg)>>2][(ar)>>4][lane_][0] = hv; \
        *(bf8v*)&Al[kh][(kg)>>2][(ar)>>4][lane_][0] = lv; }

    #define STAGE_B() { \
        _Pragma("unroll") \
        for (int c=0;c<4;c++){ \
            bf8v hv, lv; \
            _Pragma("unroll") \
            for (int j=0;j<8;j++){ \
                const unsigned e = ((const unsigned*)&pb[j])[c]; \
                hv[j] = (short)e; lv[j] = (short)(e >> 16); \
            } \
            const int col_ = b_c4 + c; \
            const int lane_ = (col_ & 15) | ((b_kg & 3) << 4); \
            *(bf8v*)&Bh[kh][b_kg>>2][col_>>4][lane_][0] = hv; \
            *(bf8v*)&Bl[kh][b_kg>>2][col_>>4][lane_][0] = lv; } }

    STAGE_A(pa0, a_r0, a_kg0)
    STAGE_A(pa1, a_r1, a_kg1)
    STAGE_B()
    __syncthreads();

    int k0 = 0;
    while (true){
        const int kn = k0 + 64;
        const bool more = kn < K2;
        if (more){
            const unsigned* s0 = Apr + (size_t)(row0 + a_r0)*K + kbase + kn + a_kg0*8;
            const unsigned* s1 = Apr + (size_t)(row0 + a_r1)*K + kbase + kn + a_kg1*8;
            pa0[0] = *(const uint4*)s0; pa0[1] = *(const uint4*)(s0+4);
            pa1[0] = *(const uint4*)s1; pa1[1] = *(const uint4*)(s1+4);
            #pragma unroll
            for (int j=0;j<8;j++)
                pb[j] = *(const uint4*)(Wpr + (size_t)(kbase + kn + b_kg*8 + j)*N + col0 + b_c4);
        }
        #pragma unroll
        for (int ks=0; ks<2; ks++){
            const bf8v ah0 = *(const bf8v*)&Ah[kh][ks][mb+0][l][0];
            const bf8v ah1 = *(const bf8v*)&Ah[kh][ks][mb+1][l][0];
            const bf8v al0 = *(const bf8v*)&Al[kh][ks][mb+0][l][0];
            const bf8v al1 = *(const bf8v*)&Al[kh][ks][mb+1][l][0];
            #pragma unroll
            for (int nf=0; nf<4; nf++){
                const bf8v bh = *(const bf8v*)&Bh[kh][ks][nb+nf][l][0];
                const bf8v bl = *(const bf8v*)&Bl[kh][ks][nb+nf][l][0];
                acc[0][nf] = __builtin_amdgcn_mfma_f32_16x16x32_bf16(ah0, bh, acc[0][nf], 0,0,0);
                acc[0][nf] = __builtin_amdgcn_mfma_f32_16x16x32_bf16(ah0, bl, acc[0][nf], 0,0,0);
                acc[0][nf] = __builtin_amdgcn_mfma_f32_16x16x32_bf16(al0, bh, acc[0][nf], 0,0,0);
                acc[1][nf] = __builtin_amdgcn_mfma_f32_16x16x32_bf16(ah1, bh, acc[1][nf], 0,0,0);
                acc[1][nf] = __builtin_amdgcn_mfma_f32_16x16x32_bf16(ah1, bl, acc[1][nf], 0,0,0);
                acc[1][nf] = __builtin_amdgcn_mfma_f32_16x16x32_bf16(al1, bh, acc[1][nf], 0,0,0);
            }
        }
        __syncthreads();
        if (!more) break;
        STAGE_A(pa0, a_r0, a_kg0)
        STAGE_A(pa1, a_r1, a_kg1)
        STAGE_B()
        __syncthreads();
        k0 = kn;
    }

    float* cs = (float*)&Ah[0][0][0][0][0];
    if (kh == 1){
        #pragma unroll
        for (int mf=0; mf<2; mf++)
            #pragma unroll
            for (int nf=0; nf<4; nf++){
                f4 p;
                p.x=acc[mf][nf][0]; p.y=acc[mf][nf][1];
                p.z=acc[mf][nf][2]; p.w=acc[mf][nf][3];
                *(f4*)(cs + 4*(((mf*4+nf))*256 + t)) = p;
            }
    }
    __syncthreads();
    if (kh == 0){
        #pragma unroll
        for (int mf=0; mf<2; mf++)
            #pragma unroll
            for (int nf=0; nf<4; nf++){
                const f4 p = *(const f4*)(cs + 4*(((mf*4+nf))*256 + t));
                acc[mf][nf][0]+=p.x; acc[mf][nf][1]+=p.y;
                acc[mf][nf][2]+=p.z; acc[mf][nf][3]+=p.w;
            }
        const int ecol = l & 15, erow = (l >> 4) * 4;
        #pragma unroll
        for (int mf=0; mf<2; mf++){
            #pragma unroll
            for (int nf=0; nf<4; nf++){
                const int col = col0 + (w&1)*64 + nf*16 + ecol;
                const float bv = bias[col];
                #pragma unroll
                for (int j=0; j<4; j++){
                    const int row = row0 + (w>>1)*32 + mf*16 + erow + j;
                    float v = acc[mf][nf][j] + bv;
                    if (act==1) v = fmaxf(v, 0.f);
                    else if (act==2) v = gelu_f(v);
                    if (hasres) v += res[(size_t)row*N + col];
                    if (outpair) Cp[(size_t)row*N + col] = f32_to_pair(v);
                    else         Cf[(size_t)row*N + col] = v;
                }
            }
        }
    }
    #undef STAGE_A
    #undef STAGE_B
}

// bf16x2 MFMA GEMM, 64x64 tile, split-K x2, 512 threads, 64KB LDS ->
// 2 blocks/CU. For mW2 (grid (16,32) = 512 blocks): doubles per-CU memory
// concurrency on the fetch-latency-bound path. XCD swizzle: each XCD owns
// 4 row-panels (A 4MB L2-resident) x all 16 col-blocks.
__global__ __launch_bounds__(512) void gemm_mfma3(
    const unsigned* __restrict__ Apr, const unsigned* __restrict__ Wpr,
    const float* __restrict__ bias, const float* __restrict__ res,
    float* __restrict__ Cf, unsigned* __restrict__ Cp,
    int M, int N, int K, int act, int hasres, int outpair)
{
    __shared__ short Ah[2][2][4][64][8];   // 16KB
    __shared__ short Al[2][2][4][64][8];   // 16KB
    __shared__ short Bh[2][2][4][64][8];   // 16KB
    __shared__ short Bl[2][2][4][64][8];   // 16KB
    const int tid = threadIdx.x;
    const int kh = tid >> 8;
    const int t  = tid & 255;
    const int w = t >> 6, l = t & 63;
    int bx = blockIdx.x, by = blockIdx.y;
    if (gridDim.x == 16 && gridDim.y == 32){
        const int flat = by*16 + bx;
        by = (flat & 7)*4 + ((flat >> 3) & 3);
        bx = flat >> 5;
    }
    const int row0 = by * 64, col0 = bx * 64;
    const int mb = (w >> 1) * 2;
    const int nb = (w & 1) * 2;
    const int K2 = K >> 1;
    const int kbase = kh * K2;
    const int b_c2 = (t & 31) * 2;
    const int b_kg = t >> 5;
    const int a_r0 = t >> 3,       a_kg0 = t & 7;
    const int a_r1 = (t+256) >> 3, a_kg1 = (t+256) & 7;

    f4v acc[2][2];
    #pragma unroll
    for (int i=0;i<2;i++)
        #pragma unroll
        for (int j=0;j<2;j++) acc[i][j] = (f4v){0.f,0.f,0.f,0.f};

    uint4 pa0[2], pa1[2];
    uint2 pb[8];

    {
        const unsigned* s0 = Apr + (size_t)(row0 + a_r0)*K + kbase + a_kg0*8;
        const unsigned* s1 = Apr + (size_t)(row0 + a_r1)*K + kbase + a_kg1*8;
        pa0[0] = *(const uint4*)s0; pa0[1] = *(const uint4*)(s0+4);
        pa1[0] = *(const uint4*)s1; pa1[1] = *(const uint4*)(s1+4);
        #pragma unroll
        for (int j=0;j<8;j++)
            pb[j] = *(const uint2*)(Wpr + (size_t)(kbase + b_kg*8 + j)*N + col0 + b_c2);
    }

    #define STAGE_A3(pr, ar, kg) { \
        bf8v hv, lv; \
        hv[0]=(short)(pr[0].x); lv[0]=(short)(pr[0].x>>16); \
        hv[1]=(short)(pr[0].y); lv[1]=(short)(pr[0].y>>16); \
        hv[2]=(short)(pr[0].z); lv[2]=(short)(pr[0].z>>16); \
        hv[3]=(short)(pr[0].w); lv[3]=(short)(pr[0].w>>16); \
        hv[4]=(short)(pr[1].x); lv[4]=(short)(pr[1].x>>16); \
        hv[5]=(short)(pr[1].y); lv[5]=(short)(pr[1].y>>16); \
        hv[6]=(short)(pr[1].z); lv[6]=(short)(pr[1].z>>16); \
        hv[7]=(short)(pr[1].w); lv[7]=(short)(pr[1].w>>16); \
        const int lane_ = ((ar) & 15) | (((kg) & 3) << 4); \
        *(bf8v*)&Ah[kh][(kg)>>2][(ar)>>4][lane_][0] = hv; \
        *(bf8v*)&Al[kh][(kg)>>2][(ar)>>4][lane_][0] = lv; }

    #define STAGE_B3() { \
        _Pragma("unroll") \
        for (int c=0;c<2;c++){ \
            bf8v hv, lv; \
            _Pragma("unroll") \
            for (int j=0;j<8;j++){ \
                const unsigned e = ((const unsigned*)&pb[j])[c]; \
                hv[j] = (short)e; lv[j] = (short)(e >> 16); \
            } \
            const int col_ = b_c2 + c; \
            const int lane_ = (col_ & 15) | ((b_kg & 3) << 4); \
            *(bf8v*)&Bh[kh][b_kg>>2][col_>>4][lane_][0] = hv; \
            *(bf8v*)&Bl[kh][b_kg>>2][col_>>4][lane_][0] = lv; } }

    STAGE_A3(pa0, a_r0, a_kg0)
    STAGE_A3(pa1, a_r1, a_kg1)
    STAGE_B3()
    __syncthreads();

    int k0 = 0;
    while (true){
        const int kn = k0 + 64;
        const bool more = kn < K2;
        if (more){
            const unsigned* s0 = Apr + (size_t)(row0 + a_r0)*K + kbase + kn + a_kg0*8;
            const unsigned* s1 = Apr + (size_t)(row0 + a_r1)*K + kbase + kn + a_kg1*8;
            pa0[0] = *(const uint4*)s0; pa0[1] = *(const uint4*)(s0+4);
            pa1[0] = *(const uint4*)s1; pa1[1] = *(const uint4*)(s1+4);
            #pragma unroll
            for (int j=0;j<8;j++)
                pb[j] = *(const uint2*)(Wpr + (size_t)(kbase + kn + b_kg*8 + j)*N + col0 + b_c2);
        }
        #pragma unroll
        for (int ks=0; ks<2; ks++){
            const bf8v ah0 = *(const bf8v*)&Ah[kh][ks][mb+0][l][0];
            const bf8v ah1 = *(const bf8v*)&Ah[kh][ks][mb+1][l][0];
            const bf8v al0 = *(const bf8v*)&Al[kh][ks][mb+0][l][0];
            const bf8v al1 = *(const bf8v*)&Al[kh][ks][mb+1][l][0];
            #pragma unroll
            for (int nf=0; nf<2; nf++){
                const bf8v bh = *(const bf8v*)&Bh[kh][ks][nb+nf][l][0];
                const bf8v bl = *(const bf8v*)&Bl[kh][ks][nb+nf][l][0];
                acc[0][nf] = __builtin_amdgcn_mfma_f32_16x16x32_bf16(ah0, bh, acc[0][nf], 0,0,0);
                acc[0][nf] = __builtin_amdgcn_mfma_f32_16x16x32_bf16(ah0, bl, acc[0][nf], 0,0,0);
                acc[0][nf] = __builtin_amdgcn_mfma_f32_16x16x32_bf16(al0, bh, acc[0][nf], 0,0,0);
                acc[1][nf] = __builtin_amdgcn_mfma_f32_16x16x32_bf16(ah1, bh, acc[1][nf], 0,0,0);
                acc[1][nf] = __builtin_amdgcn_mfma_f32_16x16x32_bf16(ah1, bl, acc[1][nf], 0,0,0);
                acc[1][nf] = __builtin_amdgcn_mfma_f32_16x16x32_bf16(al1, bh, acc[1][nf], 0,0,0);
            }
        }
        __syncthreads();
        if (!more) break;
        STAGE_A3(pa0, a_r0, a_kg0)
        STAGE_A3(pa1, a_r1, a_kg1)
        STAGE_B3()
        __syncthreads();
        k0 = kn;
    }

    // deterministic half-combine via LDS (kh1 -> kh0); 4KB region
    float* cs = (float*)&Ah[0][0][0][0][0];
    if (kh == 1){
        #pragma unroll
        for (int mf=0; mf<2; mf++)
            #pragma unroll
            for (int nf=0; nf<2; nf++){
                f4 p;
                p.x=acc[mf][nf][0]; p.y=acc[mf][nf][1];
                p.z=acc[mf][nf][2]; p.w=acc[mf][nf][3];
                *(f4*)(cs + 4*(((mf*2+nf))*256 + t)) = p;
            }
    }
    __syncthreads();
    if (kh == 0){
        #pragma unroll
        for (int mf=0; mf<2; mf++)
            #pragma unroll
            for (int nf=0; nf<2; nf++){
                const f4 p = *(const f4*)(cs + 4*(((mf*2+nf))*256 + t));
                acc[mf][nf][0]+=p.x; acc[mf][nf][1]+=p.y;
                acc[mf][nf][2]+=p.z; acc[mf][nf][3]+=p.w;
            }
        const int ecol = l & 15, erow = (l >> 4) * 4;
        #pragma unroll
        for (int mf=0; mf<2; mf++){
            #pragma unroll
            for (int nf=0; nf<2; nf++){
                const int col = col0 + (w&1)*32 + nf*16 + ecol;
                const float bv = bias[col];
                #pragma unroll
                for (int j=0; j<4; j++){
                    const int row = row0 + (w>>1)*32 + mf*16 + erow + j;
                    float v = acc[mf][nf][j] + bv;
                    if (act==1) v = fmaxf(v, 0.f);
                    else if (act==2) v = gelu_f(v);
                    if (hasres) v += res[(size_t)row*N + col];
                    if (outpair) Cp[(size_t)row*N + col] = f32_to_pair(v);
                    else         Cf[(size_t)row*N + col] = v;
                }
            }
        }
    }
    #undef STAGE_A3
    #undef STAGE_B3
}

// f32 GEMM kept for projectors + locate head
__global__ __launch_bounds__(512) void gemm128k2(
    const float* __restrict__ A, const float* __restrict__ W,
    const float* __restrict__ bias, const float* __restrict__ res,
    float* __restrict__ C, int M, int N, int K, int act, int hasres)
{
    __shared__ float As[2][32][68];
    __shared__ float Ws[2][32][132];
    const int tid = threadIdx.x;
    const int kh = tid >> 8;
    const int t  = tid & 255;
    const int row0 = blockIdx.y*64, col0 = blockIdx.x*128;
    const int ty = t>>4, tx = t&15;
    const int am = t>>2, ak = (t&3)*8;
    const int wk = t>>3, u  = t&7;
    const int K2 = K >> 1;
    const float* Ap = A + (size_t)(row0+am)*K + kh*K2 + ak;
    const float* Wp = W + (size_t)(kh*K2 + wk)*N + col0 + u*16;
    float* Wrow = &Ws[kh][wk][0];

    f4 a0,a1,w0,w1,w2,w3;
    a0 = *(const f4*)(Ap);
    a1 = *(const f4*)(Ap + 4);
    w0 = *(const f4*)(Wp);
    w1 = *(const f4*)(Wp + 4);
    w2 = *(const f4*)(Wp + 8);
    w3 = *(const f4*)(Wp + 12);
    As[kh][ak+0][am]=a0.x; As[kh][ak+1][am]=a0.y; As[kh][ak+2][am]=a0.z; As[kh][ak+3][am]=a0.w;
    As[kh][ak+4][am]=a1.x; As[kh][ak+5][am]=a1.y; As[kh][ak+6][am]=a1.z; As[kh][ak+7][am]=a1.w;
    *(f4*)(Wrow + 8*u)      = w0;
    *(f4*)(Wrow + 8*u + 4)  = w2;
    *(f4*)(Wrow + 64 + 8*u)     = w1;
    *(f4*)(Wrow + 64 + 8*u + 4) = w3;
    __syncthreads();

    float acc[4][8];
    #pragma unroll
    for (int i=0;i<4;i++){
        #pragma unroll
        for (int j=0;j<8;j++) acc[i][j]=0.f;
    }

    int k0 = 0;
    while (true){
        const int kn = k0 + 32;
        const bool more = kn < K2;
        if (more){
            a0 = *(const f4*)(Ap + kn);
            a1 = *(const f4*)(Ap + kn + 4);
            w0 = *(const f4*)(Wp + (size_t)kn*N);
            w1 = *(const f4*)(Wp + (size_t)kn*N + 4);
            w2 = *(const f4*)(Wp + (size_t)kn*N + 8);
            w3 = *(const f4*)(Wp + (size_t)kn*N + 12);
        }
        #pragma unroll
        for (int kk=0;kk<32;kk++){
            f4 a  = *(const f4*)&As[kh][kk][ty*4];
            f4 wA = *(const f4*)&Ws[kh][kk][tx*4];
            f4 wB = *(const f4*)&Ws[kh][kk][64 + tx*4];
            float ar[4] = {a.x,a.y,a.z,a.w};
            #pragma unroll
            for (int i=0;i<4;i++){
                acc[i][0] += ar[i]*wA.x;
                acc[i][1] += ar[i]*wA.y;
                acc[i][2] += ar[i]*wA.z;
                acc[i][3] += ar[i]*wA.w;
                acc[i][4] += ar[i]*wB.x;
                acc[i][5] += ar[i]*wB.y;
                acc[i][6] += ar[i]*wB.z;
                acc[i][7] += ar[i]*wB.w;
            }
        }
        __syncthreads();
        if (!more) break;
        As[kh][ak+0][am]=a0.x; As[kh][ak+1][am]=a0.y; As[kh][ak+2][am]=a0.z; As[kh][ak+3][am]=a0.w;
        As[kh][ak+4][am]=a1.x; As[kh][ak+5][am]=a1.y; As[kh][ak+6][am]=a1.z; As[kh][ak+7][am]=a1.w;
        *(f4*)(Wrow + 8*u)      = w0;
        *(f4*)(Wrow + 8*u + 4)  = w2;
        *(f4*)(Wrow + 64 + 8*u)     = w1;
        *(f4*)(Wrow + 64 + 8*u + 4) = w3;
        __syncthreads();
        k0 = kn;
    }

    float* cs = &Ws[0][0][0];
    if (kh == 1){
        #pragma unroll
        for (int i=0;i<4;i++){
            #pragma unroll
            for (int b=0;b<2;b++){
                f4 p;
                p.x=acc[i][b*4+0]; p.y=acc[i][b*4+1]; p.z=acc[i][b*4+2]; p.w=acc[i][b*4+3];
                *(f4*)(cs + 4*(((i<<1)|b)*256 + t)) = p;
            }
        }
    }
    __syncthreads();
    if (kh == 0){
        #pragma unroll
        for (int i=0;i<4;i++){
            #pragma unroll
            for (int b=0;b<2;b++){
                const f4 p = *(const f4*)(cs + 4*(((i<<1)|b)*256 + t));
                acc[i][b*4+0]+=p.x; acc[i][b*4+1]+=p.y; acc[i][b*4+2]+=p.z; acc[i][b*4+3]+=p.w;
            }
        }
        #pragma unroll
        for (int i=0;i<4;i++){
            const int r = row0 + ty*4 + i;
            #pragma unroll
            for (int half=0; half<2; ++half){
                const int cb = col0 + tx*8 + half*4;
                f4 bv = *(const f4*)(bias + cb);
                float t0 = acc[i][half*4+0] + bv.x;
                float t1 = acc[i][half*4+1] + bv.y;
                float t2 = acc[i][half*4+2] + bv.z;
                float t3 = acc[i][half*4+3] + bv.w;
                if (act==1){ t0=fmaxf(t0,0.f); t1=fmaxf(t1,0.f); t2=fmaxf(t2,0.f); t3=fmaxf(t3,0.f); }
                else if (act==2){ t0=gelu_f(t0); t1=gelu_f(t1); t2=gelu_f(t2); t3=gelu_f(t3); }
                if (hasres){
                    f4 rv = *(const f4*)(res + (size_t)r*N + cb);
                    t0+=rv.x; t1+=rv.y; t2+=rv.z; t3+=rv.w;
                }
                f4 o; o.x=t0; o.y=t1; o.z=t2; o.w=t3;
                *(f4*)(C + (size_t)r*N + cb) = o;
            }
        }
    }
}

__global__ __launch_bounds__(256) void lnrow(
    const float* __restrict__ X, const float* __restrict__ g,
    const float* __restrict__ b, float* __restrict__ out, float eps)
{
    __shared__ float red[4];
    const int row = blockIdx.x, tid = threadIdx.x;
    const float* xp = X + (size_t)row*D_MOD;
    f4 xv = *(const f4*)(xp + tid*4);
    float s = xv.x+xv.y+xv.z+xv.w;
    #pragma unroll
    for (int m=1;m<64;m<<=1) s += __shfl_xor(s, m);
    const int wid = tid>>6, lane = tid&63;
    if (lane==0) red[wid]=s;
    __syncthreads();
    float mean = (red[0]+red[1]+red[2]+red[3]) * (1.0f/1024.0f);
    __syncthreads();
    float d0=xv.x-mean, d1=xv.y-mean, d2=xv.z-mean, d3=xv.w-mean;
    float q = d0*d0+d1*d1+d2*d2+d3*d3;
    #pragma unroll
    for (int m=1;m<64;m<<=1) q += __shfl_xor(q, m);
    if (lane==0) red[wid]=q;
    __syncthreads();
    float var = (red[0]+red[1]+red[2]+red[3]) * (1.0f/1024.0f);
    float inv = rsqrtf(var + eps);
    f4 gv = *(const f4*)(g + tid*4);
    f4 bv = *(const f4*)(b + tid*4);
    f4 o;
    o.x = d0*inv*gv.x + bv.x;
    o.y = d1*inv*gv.y + bv.y;
    o.z = d2*inv*gv.z + bv.z;
    o.w = d3*inv*gv.w + bv.w;
    *(f4*)(out + (size_t)row*D_MOD + tid*4) = o;
}

__global__ __launch_bounds__(256) void lnrow_pair(
    const float* __restrict__ X, const float* __restrict__ g,
    const float* __restrict__ b, unsigned* __restrict__ outp, float eps)
{
    __shared__ float red[4];
    const int row = blockIdx.x, tid = threadIdx.x;
    const float* xp = X + (size_t)row*D_MOD;
    f4 xv = *(const f4*)(xp + tid*4);
    float s = xv.x+xv.y+xv.z+xv.w;
    #pragma unroll
    for (int m=1;m<64;m<<=1) s += __shfl_xor(s, m);
    const int wid = tid>>6, lane = tid&63;
    if (lane==0) red[wid]=s;
    __syncthreads();
    float mean = (red[0]+red[1]+red[2]+red[3]) * (1.0f/1024.0f);
    __syncthreads();
    float d0=xv.x-mean, d1=xv.y-mean, d2=xv.z-mean, d3=xv.w-mean;
    float q = d0*d0+d1*d1+d2*d2+d3*d3;
    #pragma unroll
    for (int m=1;m<64;m<<=1) q += __shfl_xor(q, m);
    if (lane==0) red[wid]=q;
    __syncthreads();
    float var = (red[0]+red[1]+red[2]+red[3]) * (1.0f/1024.0f);
    float inv = rsqrtf(var + eps);
    f4 gv = *(const f4*)(g + tid*4);
    f4 bv = *(const f4*)(b + tid*4);
    uint4 o;
    o.x = f32_to_pair(d0*inv*gv.x + bv.x);
    o.y = f32_to_pair(d1*inv*gv.y + bv.y);
    o.z = f32_to_pair(d2*inv*gv.z + bv.z);
    o.w = f32_to_pair(d3*inv*gv.w + bv.w);
    ((uint4*)(outp + (size_t)row*D_MOD))[tid] = o;
}

// MFMA flash attention, bf16x2 (R12, validated)
__global__ __launch_bounds__(256,1) void attn_mfma(
    const float* __restrict__ Q, const float* __restrict__ Kb,
    const float* __restrict__ Vb,
    float* __restrict__ OA0, float* __restrict__ OA1,
    float* __restrict__ ML0, float* __restrict__ ML1)
{
    __shared__ short QhS[4][8][64][8];
    __shared__ short QlS[4][8][64][8];
    __shared__ short KhS[4][4][64][8];
    __shared__ short KlS[4][4][64][8];
    __shared__ short VhS[2][8][64][8];
    __shared__ short VlS[2][8][64][8];
    short* Ph = &KhS[0][0][0][0];
    short* Pl = &KlS[0][0][0][0];

    const int tid = threadIdx.x;
    const int w = tid >> 6, l = tid & 63;
    const int h  = blockIdx.x & 7;
    const int sh = (blockIdx.x >> 3) & 1;
    const int q0 = (blockIdx.x >> 4) * 128;
    const int sbase = sh * 1024;
    const float qscale = 0.08838834764831845f;

    #pragma unroll
    for (int i=0;i<2;i++){
        const int u = tid + i*256;
        const int qr = u >> 2, dks = u & 3;
        const float* src = Q + (size_t)(q0+qr)*D_MOD + h*128 + dks*32;
        float a[32];
        #pragma unroll
        for (int j=0;j<8;j++) *(f4*)&a[j*4] = ((const f4*)src)[j];
        const int qmf = qr >> 4;
        #pragma unroll
        for (int kg=0;kg<4;kg++){
            bf8v hv, lv;
            #pragma unroll
            for (int e=0;e<8;e++){
                short hi, lo;
                split2(a[kg*8+e]*qscale, hi, lo);
                hv[e]=hi; lv[e]=lo;
            }
            const int lane = (qr & 15) | (kg << 4);
            *(bf8v*)&QhS[dks][qmf][lane][0] = hv;
            *(bf8v*)&QlS[dks][qmf][lane][0] = lv;
        }
    }
    {
        const int sr = tid >> 2, dks = tid & 3;
        const float* src = Kb + (size_t)(sbase+sr)*D_MOD + h*128 + dks*32;
        float a[32];
        #pragma unroll
        for (int j=0;j<8;j++) *(f4*)&a[j*4] = ((const f4*)src)[j];
        const int smf = sr >> 4;
        #pragma unroll
        for (int kg=0;kg<4;kg++){
            bf8v hv, lv;
            #pragma unroll
            for (int e=0;e<8;e++){ short hi,lo; split2(a[kg*8+e],hi,lo); hv[e]=hi; lv[e]=lo; }
            const int lane = (sr & 15) | (kg << 4);
            *(bf8v*)&KhS[dks][smf][lane][0] = hv;
            *(bf8v*)&KlS[dks][smf][lane][0] = lv;
        }
        const int s8 = tid >> 5, d4 = (tid & 31) * 4;
        float b[8][4];
        #pragma unroll
        for (int r=0;r<8;r++)
            *(f4*)&b[r][0] = *(const f4*)(Vb + (size_t)(sbase+s8*8+r)*D_MOD + h*128 + d4);
        const int sks = s8 >> 2, sg = s8 & 3;
        #pragma unroll
        for (int c=0;c<4;c++){
            bf8v hv, lv;
            #pragma unroll
            for (int r=0;r<8;r++){ short hi,lo; split2(b[r][c],hi,lo); hv[r]=hi; lv[r]=lo; }
            const int d = d4 + c;
            const int lane = (d & 15) | (sg << 4);
            *(bf8v*)&VhS[sks][d>>4][lane][0] = hv;
            *(bf8v*)&VlS[sks][d>>4][lane][0] = lv;
        }
    }
    __syncthreads();

    float mstat[8], lstat[8];
    f4v oacc[2][8];
    #pragma unroll
    for (int i=0;i<8;i++){ mstat[i] = -__builtin_inff(); lstat[i] = 0.f; }
    #pragma unroll
    for (int i=0;i<2;i++)
        #pragma unroll
        for (int j=0;j<8;j++) oacc[i][j] = (f4v){0.f,0.f,0.f,0.f};

    for (int t=0; t<16; ++t){
        f4v sacc[2][4];
        #pragma unroll
        for (int i=0;i<2;i++)
            #pragma unroll
            for (int j=0;j<4;j++) sacc[i][j] = (f4v){0.f,0.f,0.f,0.f};
        #pragma unroll
        for (int dks=0; dks<4; dks++){
            const bf8v qh0 = *(const bf8v*)&QhS[dks][2*w+0][l][0];
            const bf8v qh1 = *(const bf8v*)&QhS[dks][2*w+1][l][0];
            const bf8v ql0 = *(const bf8v*)&QlS[dks][2*w+0][l][0];
            const bf8v ql1 = *(const bf8v*)&QlS[dks][2*w+1][l][0];
            #pragma unroll
            for (int sf=0; sf<4; sf++){
                const bf8v kh = *(const bf8v*)&KhS[dks][sf][l][0];
                const bf8v kl = *(const bf8v*)&KlS[dks][sf][l][0];
                sacc[0][sf] = __builtin_amdgcn_mfma_f32_16x16x32_bf16(qh0, kh, sacc[0][sf], 0,0,0);
                sacc[0][sf] = __builtin_amdgcn_mfma_f32_16x16x32_bf16(qh0, kl, sacc[0][sf], 0,0,0);
                sacc[0][sf] = __builtin_amdgcn_mfma_f32_16x16x32_bf16(ql0, kh, sacc[0][sf], 0,0,0);
                sacc[1][sf] = __builtin_amdgcn_mfma_f32_16x16x32_bf16(qh1, kh, sacc[1][sf], 0,0,0);
                sacc[1][sf] = __builtin_amdgcn_mfma_f32_16x16x32_bf16(qh1, kl, sacc[1][sf], 0,0,0);
                sacc[1][sf] = __builtin_amdgcn_mfma_f32_16x16x32_bf16(ql1, kh, sacc[1][sf], 0,0,0);
            }
        }
        __syncthreads();

        float scr[8];
        #pragma unroll
        for (int mfi=0; mfi<2; mfi++){
            #pragma unroll
            for (int j=0; j<4; j++){
                const int si = mfi*4 + j;
                float tm = fmaxf(fmaxf(sacc[mfi][0][j], sacc[mfi][1][j]),
                                 fmaxf(sacc[mfi][2][j], sacc[mfi][3][j]));
                tm = fmaxf(tm, __shfl_xor(tm,1));
                tm = fmaxf(tm, __shfl_xor(tm,2));
                tm = fmaxf(tm, __shfl_xor(tm,4));
                tm = fmaxf(tm, __shfl_xor(tm,8));
                const float mn = fmaxf(mstat[si], tm);
                const float sc = __expf(mstat[si] - mn);
                float rs = 0.f;
                #pragma unroll
                for (int sf=0; sf<4; sf++){
                    const float p = __expf(sacc[mfi][sf][j] - mn);
                    sacc[mfi][sf][j] = p; rs += p;
                }
                rs += __shfl_xor(rs,1); rs += __shfl_xor(rs,2);
                rs += __shfl_xor(rs,4); rs += __shfl_xor(rs,8);
                lstat[si] = lstat[si]*sc + rs;
                mstat[si] = mn;
                scr[si] = sc;
            }
        }
        {
            const int pe = l & 7;
            const int rb4 = (l >> 4) * 4;
            const int sgb = (l & 15) >> 3;
            #pragma unroll
            for (int mfi=0; mfi<2; mfi++){
                const int qmf = 2*w + mfi;
                #pragma unroll
                for (int sf=0; sf<4; sf++){
                    const int sks = sf >> 1;
                    const int sg = (sf & 1)*2 + sgb;
                    #pragma unroll
                    for (int j=0; j<4; j++){
                        const int lane = (rb4 + j) | (sg << 4);
                        short hi, lo;
                        split2(sacc[mfi][sf][j], hi, lo);
                        const int off = ((sks*8 + qmf)*64 + lane)*8 + pe;
                        Ph[off] = hi;
                        Pl[off] = lo;
                    }
                }
            }
        }
        __syncthreads();

        #pragma unroll
        for (int mfi=0; mfi<2; mfi++){
            #pragma unroll
            for (int j=0; j<4; j++){
                const float sc = scr[mfi*4+j];
                #pragma unroll
                for (int dmf=0; dmf<8; dmf++) oacc[mfi][dmf][j] *= sc;
            }
        }
        #pragma unroll
        for (int sks=0; sks<2; sks++){
            const bf8v ph0 = *(const bf8v*)&Ph[((sks*8 + 2*w+0)*64 + l)*8];
            const bf8v ph1 = *(const bf8v*)&Ph[((sks*8 + 2*w+1)*64 + l)*8];
            const bf8v pl0 = *(const bf8v*)&Pl[((sks*8 + 2*w+0)*64 + l)*8];
            const bf8v pl1 = *(const bf8v*)&Pl[((sks*8 + 2*w+1)*64 + l)*8];
            #pragma unroll
            for (int dmf=0; dmf<8; dmf++){
                const bf8v vh = *(const bf8v*)&VhS[sks][dmf][l][0];
                const bf8v vl = *(const bf8v*)&VlS[sks][dmf][l][0];
                oacc[0][dmf] = __builtin_amdgcn_mfma_f32_16x16x32_bf16(ph0, vh, oacc[0][dmf], 0,0,0);
                oacc[0][dmf] = __builtin_amdgcn_mfma_f32_16x16x32_bf16(ph0, vl, oacc[0][dmf], 0,0,0);
                oacc[0][dmf] = __builtin_amdgcn_mfma_f32_16x16x32_bf16(pl0, vh, oacc[0][dmf], 0,0,0);
                oacc[1][dmf] = __builtin_amdgcn_mfma_f32_16x16x32_bf16(ph1, vh, oacc[1][dmf], 0,0,0);
                oacc[1][dmf] = __builtin_amdgcn_mfma_f32_16x16x32_bf16(ph1, vl, oacc[1][dmf], 0,0,0);
                oacc[1][dmf] = __builtin_amdgcn_mfma_f32_16x16x32_bf16(pl1, vh, oacc[1][dmf], 0,0,0);
            }
        }
        __syncthreads();

        if (t < 15){
            const int sb = sbase + (t+1)*64;
            const int sr = tid >> 2, dks = tid & 3;
            const float* src = Kb + (size_t)(sb+sr)*D_MOD + h*128 + dks*32;
            float a[32];
            #pragma unroll
            for (int j=0;j<8;j++) *(f4*)&a[j*4] = ((const f4*)src)[j];
            const int smf = sr >> 4;
            #pragma unroll
            for (int kg=0;kg<4;kg++){
                bf8v hv, lv;
                #pragma unroll
                for (int e=0;e<8;e++){ short hi,lo; split2(a[kg*8+e],hi,lo); hv[e]=hi; lv[e]=lo; }
                const int lane = (sr & 15) | (kg << 4);
                *(bf8v*)&KhS[dks][smf][lane][0] = hv;
                *(bf8v*)&KlS[dks][smf][lane][0] = lv;
            }
            const int s8 = tid >> 5, d4 = (tid & 31) * 4;
            float b[8][4];
            #pragma unroll
            for (int r=0;r<8;r++)
                *(f4*)&b[r][0] = *(const f4*)(Vb + (size_t)(sb+s8*8+r)*D_MOD + h*128 + d4);
            const int sks = s8 >> 2, sg = s8 & 3;
            #pragma unroll
            for (int c=0;c<4;c++){
                bf8v hv, lv;
                #pragma unroll
                for (int r=0;r<8;r++){ short hi,lo; split2(b[r][c],hi,lo); hv[r]=hi; lv[r]=lo; }
                const int d = d4 + c;
                const int lane = (d & 15) | (sg << 4);
                *(bf8v*)&VhS[sks][d>>4][lane][0] = hv;
                *(bf8v*)&VlS[sks][d>>4][lane][0] = lv;
            }
        }
        __syncthreads();
    }

    float* OAp = sh ? OA1 : OA0;
    float* MLp = sh ? ML1 : ML0;
    const int erow = (l >> 4) * 4, ecol = l & 15;
    #pragma unroll
    for (int mfi=0; mfi<2; mfi++){
        #pragma unroll
        for (int dmf=0; dmf<8; dmf++){
            const int col = h*128 + dmf*16 + ecol;
            #pragma unroll
            for (int j=0; j<4; j++){
                const int row = q0 + w*32 + mfi*16 + erow + j;
                OAp[(size_t)row*D_MOD + col] = oacc[mfi][dmf][j];
            }
        }
    }
    if (ecol == 0){
        #pragma unroll
        for (int mfi=0; mfi<2; mfi++){
            #pragma unroll
            for (int j=0; j<4; j++){
                const int row = q0 + w*32 + mfi*16 + erow + j;
                MLp[(size_t)row*16 + h*2 + 0] = mstat[mfi*4+j];
                MLp[(size_t)row*16 + h*2 + 1] = lstat[mfi*4+j];
            }
        }
    }
}

// flash-combine of the two s-halves + bias-KV token; writes bf16-pair output
__global__ __launch_bounds__(256) void attn_combine(
    const float* __restrict__ Q, const float* __restrict__ kbias,
    const float* __restrict__ vbias,
    const float* __restrict__ OA0, const float* __restrict__ OA1,
    const float* __restrict__ ML0, const float* __restrict__ ML1,
    unsigned* __restrict__ OP)
{
    const int row = blockIdx.x, t = threadIdx.x;
    const int h = t >> 5;
    const int cc = t & 31;
    const float qscale = 0.08838834764831845f;
    const f4 qv = *(const f4*)(Q + (size_t)row*D_MOD + h*128 + cc*4);
    const f4 kb = *(const f4*)(kbias + h*128 + cc*4);
    float part = qv.x*kb.x + qv.y*kb.y + qv.z*kb.z + qv.w*kb.w;
    part += __shfl_xor(part,1); part += __shfl_xor(part,2);
    part += __shfl_xor(part,4); part += __shfl_xor(part,8);
    part += __shfl_xor(part,16);
    const float sb = part * qscale;
    const float m0 = ML0[(size_t)row*16 + h*2], l0 = ML0[(size_t)row*16 + h*2 + 1];
    const float m1 = ML1[(size_t)row*16 + h*2], l1 = ML1[(size_t)row*16 + h*2 + 1];
    const float M  = fmaxf(fmaxf(m0, m1), sb);
    const float w0 = __expf(m0 - M), w1 = __expf(m1 - M), wb = __expf(sb - M);
    const float inv = 1.0f / (w0*l0 + w1*l1 + wb);
    const f4 o0 = *(const f4*)(OA0 + (size_t)row*D_MOD + t*4);
    const f4 o1 = *(const f4*)(OA1 + (size_t)row*D_MOD + t*4);
    const f4 vb = *(const f4*)(vbias + h*128 + cc*4);
    uint4 o;
    o.x = f32_to_pair((o0.x*w0 + o1.x*w1 + vb.x*wb) * inv);
    o.y = f32_to_pair((o0.y*w0 + o1.y*w1 + vb.y*wb) * inv);
    o.z = f32_to_pair((o0.z*w0 + o1.z*w1 + vb.z*wb) * inv);
    o.w = f32_to_pair((o0.w*w0 + o1.w*w1 + vb.w*wb) * inv);
    *(uint4*)(OP + (size_t)row*D_MOD + t*4) = o;
}

__global__ __launch_bounds__(64) void locate_head(
    const float* __restrict__ mid, const float* __restrict__ W2,
    const float* __restrict__ b2, float* __restrict__ loc_ws,
    float* __restrict__ loc_out)
{
    const int row = blockIdx.x, lane = threadIdx.x;
    const float* m = mid + (size_t)row*512;
    f4 v0 = *(const f4*)(m + lane*8);
    f4 v1 = *(const f4*)(m + lane*8 + 4);
    f4 w0 = *(const f4*)(W2 + lane*8);
    f4 w1 = *(const f4*)(W2 + lane*8 + 4);
    float s = v0.x*w0.x + v0.y*w0.y + v0.z*w0.z + v0.w*w0.w
            + v1.x*w1.x + v1.y*w1.y + v1.z*w1.z + v1.w*w1.w;
    #pragma unroll
    for (int mm=1; mm<64; mm<<=1) s += __shfl_xor(s, mm);
    if (lane==0){
        float z = s + b2[0];
        float l = 1.0f/(1.0f + expf(-z));
        loc_ws[row] = l;
        loc_out[row] = l;
    }
}

__global__ __launch_bounds__(1024) void segscan(
    const float* __restrict__ located, const float* __restrict__ thrp,
    float* __restrict__ out_segid, float* __restrict__ out_segtype,
    float* __restrict__ out_numseg, int* __restrict__ wsi)
{
    __shared__ int clips[2048];
    __shared__ int segid[2048];
    __shared__ int sstart[2049];
    __shared__ int wsum[16];
    const int tid = threadIdx.x;
    const float thr = *thrp;
    for (int t=tid; t<2048; t+=1024) clips[t] = (located[t] > thr) ? 1 : 0;
    __syncthreads();
    const int t0 = tid*2, t1 = t0+1;
    int f0 = (t0==0) ? 0 : (clips[t0]!=clips[t0-1] ? 1 : 0);
    int f1 = (clips[t1]!=clips[t1-1] ? 1 : 0);
    int e0 = f0, e1 = f0+f1;
    const int lane = tid&63, wid = tid>>6;
    int v = e1;
    #pragma unroll
    for (int off=1; off<64; off<<=1){
        int u = __shfl_up(v, off, 64);
        if (lane>=off) v += u;
    }
    if (lane==63) wsum[wid] = v;
    __syncthreads();
    if (tid < 16){
        int w = wsum[tid];
        #pragma unroll
        for (int off=1; off<16; off<<=1){
            int u = __shfl_up(w, off, 16);
            if (tid>=off) w += u;
        }
        wsum[tid] = w;
    }
    __syncthreads();
    int base = (wid>0 ? wsum[wid-1] : 0) + (v - e1);
    segid[t0] = base + e0;
    segid[t1] = base + e1;
    __syncthreads();
    const int ns = segid[2047] + 1;
    for (int t=tid; t<2048; t+=1024){
        if (t==0 || segid[t]!=segid[t-1]) sstart[segid[t]] = t;
    }
    if (tid==0) sstart[ns] = 2048;
    __syncthreads();
    for (int t=tid; t<2048; t+=1024) out_segid[t] = (float)segid[t];
    for (int s=tid; s<2048; s+=1024)
        out_segtype[s] = (s<ns) ? (float)clips[sstart[s]] : -2147483648.0f;
    if (tid==0){ out_numseg[0] = (float)ns; wsi[0] = ns; }
    for (int s=tid; s<=2048; s+=1024) wsi[2+s] = (s<=ns) ? sstart[s] : 0;
}

__global__ __launch_bounds__(256) void segpool(
    const float* __restrict__ V, const float* __restrict__ A,
    const int* __restrict__ wsi, float* __restrict__ out_vid,
    float* __restrict__ out_aud)
{
    const int s = blockIdx.x;
    const int c = threadIdx.x*4;
    const int ns = wsi[0];
    f4 vv; vv.x=0.f; vv.y=0.f; vv.z=0.f; vv.w=0.f;
    f4 av = vv;
    if (s < ns){
        const int st = wsi[2+s], en = wsi[2+s+1];
        for (int r=st; r<en; ++r){
            f4 x = *(const f4*)(V + (size_t)r*D_MOD + c);
            vv.x+=x.x; vv.y+=x.y; vv.z+=x.z; vv.w+=x.w;
            f4 y = *(const f4*)(A + (size_t)r*D_MOD + c);
            av.x+=y.x; av.y+=y.y; av.z+=y.z; av.w+=y.w;
        }
        const float inv = 1.0f/(float)(en-st);
        vv.x*=inv; vv.y*=inv; vv.z*=inv; vv.w*=inv;
        av.x*=inv; av.y*=inv; av.z*=inv; av.w*=inv;
    }
    *(f4*)(out_vid + (size_t)s*D_MOD + c) = vv;
    *(f4*)(out_aud + (size_t)s*D_MOD + c) = av;
}

extern "C" void kernel_launch(void* const* d_in, const int* in_sizes, int n_in,
                              void* d_out, int out_size, void* d_ws, size_t ws_size,
                              hipStream_t stream) {
    (void)in_sizes; (void)n_in; (void)out_size; (void)ws_size;
    const float* video = (const float*)d_in[0];
    const float* audio = (const float*)d_in[1];
    const float* apW1  = (const float*)d_in[2];
    const float* apb1  = (const float*)d_in[3];
    const float* apW2  = (const float*)d_in[4];
    const float* apb2  = (const float*)d_in[5];
    const float* vpW1  = (const float*)d_in[6];
    const float* vpb1  = (const float*)d_in[7];
    const float* vpW2  = (const float*)d_in[8];
    const float* vpb2  = (const float*)d_in[9];
    const float* preg  = (const float*)d_in[10];
    const float* preb  = (const float*)d_in[11];
    const float* bWq   = (const float*)d_in[12];
    const float* bbq   = (const float*)d_in[13];
    const float* bWk   = (const float*)d_in[14];
    const float* bbk   = (const float*)d_in[15];
    const float* bWv   = (const float*)d_in[16];
    const float* bbv   = (const float*)d_in[17];
    const float* bWo   = (const float*)d_in[18];
    const float* bbo   = (const float*)d_in[19];
    const float* bbiask= (const float*)d_in[20];
    const float* bbiasv= (const float*)d_in[21];
    const float* bg1   = (const float*)d_in[22];
    const float* bb1   = (const float*)d_in[23];
    const float* bg2   = (const float*)d_in[24];
    const float* bb2   = (const float*)d_in[25];
    const float* bmW1  = (const float*)d_in[26];
    const float* bmb1  = (const float*)d_in[27];
    const float* bmW2  = (const float*)d_in[28];
    const float* bmb2  = (const float*)d_in[29];
    const float* lhW1  = (const float*)d_in[30];
    const float* lhb1  = (const float*)d_in[31];
    const float* lhW2  = (const float*)d_in[32];
    const float* lhb2  = (const float*)d_in[33];
    const float* thrp  = (const float*)d_in[34];

    float* ws = (float*)d_ws;
    float* V    = ws + 0;
    float* Abuf = ws + 2097152;
    float* X    = ws + 4194304;
    float* H    = ws + 6291456;
    float* Q    = ws + 8388608;
    float* Kb   = ws + 10485760;
    float* Vb   = ws + 12582912;
    float* Obuf = ws + 14680064;
    unsigned* M4p = (unsigned*)(ws + 8388608);
    float* M512 = ws + 16777216;
    float* LOC  = ws + 17825792;
    int*   WSI  = (int*)(ws + 17827840);
    float* ML0  = ws + 17829952;
    float* ML1  = ws + 17862720;
    unsigned* Vp  = (unsigned*)(ws + 17895488);
    unsigned* OPp = (unsigned*)(ws + 19992640);
    unsigned* WQp = (unsigned*)(ws + 22089792);
    unsigned* WKp = (unsigned*)(ws + 23138368);
    unsigned* WVp = (unsigned*)(ws + 24186944);
    unsigned* WOp = (unsigned*)(ws + 25235520);
    unsigned* W1p = (unsigned*)(ws + 26284096);
    unsigned* W2p = (unsigned*)(ws + 30478400);
    unsigned* Hp  = (unsigned*)H;

    float* out = (float*)d_out;
    float* out_vid     = out + 0;
    float* out_aud     = out + 2097152;
    float* out_loc     = out + 4194304;
    float* out_segid   = out + 4196352;
    float* out_segtype = out + 4198400;
    float* out_numseg  = out + 4200448;

    const dim3 B512(512);
    const dim3 B256(256);
    #define GRID128(M,N) dim3((N)/128,(M)/64)
    #define GRIDM(M,N)   dim3((N)/128,(M)/64)
    #define GRID64(M,N)  dim3((N)/64,(M)/64)

    // projectors (f32 path, exact for pools)
    gemm128k2<<<GRID128(2048,512), B512, 0, stream>>>(audio, apW1, apb1, nullptr, M512, 2048,512,128, 1,0);
    gemm128k2<<<GRID128(2048,1024),B512, 0, stream>>>(M512, apW2, apb2, nullptr, Abuf, 2048,1024,512, 0,0);
    gemm128k2<<<GRID128(2048,512), B512, 0, stream>>>(video, vpW1, vpb1, nullptr, M512, 2048,512,1024, 1,0);
    gemm128k2<<<GRID128(2048,1024),B512, 0, stream>>>(M512, vpW2, vpb2, nullptr, V,    2048,1024,512, 0,0);
    lnrow<<<2048, B256, 0, stream>>>(Abuf, preg, preb, X, 1e-6f);
    convert1<<<2048, B256, 0, stream>>>(V, Vp, 524288);

    for (int l=0; l<8; ++l){
        const size_t wo = (size_t)l*1024*1024;
        const size_t bo = (size_t)l*1024;
        const size_t mo1 = (size_t)l*1024*4096;
        convert6<<<1536, B256, 0, stream>>>(bWq+wo, bWk+wo, bWv+wo, bWo+wo,
                                            bmW1+mo1, bmW2+mo1,
                                            WQp, WKp, WVp, WOp, W1p, W2p);
        lnrow_pair<<<2048, B256, 0, stream>>>(X, bg1+bo, bb1+bo, Hp, 1e-5f);
        gemm_mfma2<<<GRIDM(2048,1024), B512, 0, stream>>>(Hp, WQp, bbq+bo, nullptr, Q,  nullptr, 2048,1024,1024, 0,0,0);
        gemm_mfma2<<<GRIDM(2048,1024), B512, 0, stream>>>(Vp, WKp, bbk+bo, nullptr, Kb, nullptr, 2048,1024,1024, 0,0,0);
        gemm_mfma2<<<GRIDM(2048,1024), B512, 0, stream>>>(Vp, WVp, bbv+bo, nullptr, Vb, nullptr, 2048,1024,1024, 0,0,0);
        attn_mfma<<<256, B256, 0, stream>>>(Q, Kb, Vb, Obuf, H, ML0, ML1);
        attn_combine<<<2048, B256, 0, stream>>>(Q, bbiask+bo, bbiasv+bo, Obuf, H, ML0, ML1, OPp);
        gemm_mfma2<<<GRIDM(2048,1024), B512, 0, stream>>>(OPp, WOp, bbo+bo, X, X, nullptr, 2048,1024,1024, 0,1,0);
        lnrow_pair<<<2048, B256, 0, stream>>>(X, bg2+bo, bb2+bo, Hp, 1e-5f);
        gemm_mfma<<<GRIDM(2048,4096), B256, 0, stream>>>(Hp, W1p, bmb1+(size_t)l*4096, nullptr, nullptr, M4p, 2048,4096,1024, 2,0,1);
        gemm_mfma3<<<GRID64(2048,1024), B512, 0, stream>>>(M4p, W2p, bmb2+bo, X, X, nullptr, 2048,1024,4096, 0,1,0);
    }

    gemm128k2<<<GRID128(2048,512), B512, 0, stream>>>(X, lhW1, lhb1, nullptr, M512, 2048,512,1024, 1,0);
    locate_head<<<2048, dim3(64), 0, stream>>>(M512, lhW2, lhb2, LOC, out_loc);
    segscan<<<1, dim3(1024), 0, stream>>>(LOC, thrp, out_segid, out_segtype, out_numseg, WSI);
    segpool<<<2048, B256, 0, stream>>>(V, Abuf, WSI, out_vid, out_aud);
}